// Round 1
// baseline (1577.205 us; speedup 1.0000x reference)
//
#include <hip/hip_runtime.h>
#include <math.h>

#define TSEQ 2048
#define NB   2
#define NH   16
#define NE   8
#define DHD  64
#define MDIM 1024
#define MBT  4096   // NB*TSEQ

// ---------------- generic fp32-in GEMM: C[M,N] = A[M,K] * B[N,K]^T ----------------
// grid = (N/64, M/64), block = 256. ACC selects accumulator precision.
template <typename ACC>
__global__ __launch_bounds__(256)
void gemm_nt(const float* __restrict__ A, int lda,
             const float* __restrict__ B, int ldb,
             float* __restrict__ C, int ldc, int Kc)
{
    __shared__ float As[64][17];
    __shared__ float Bs[64][17];
    const int tid = threadIdx.x;
    const int tx = tid & 15, ty = tid >> 4;
    const int m0 = blockIdx.y * 64, n0 = blockIdx.x * 64;
    const int lr = tid >> 2;          // 0..63
    const int lc = (tid & 3) << 2;    // 0,4,8,12
    ACC acc[4][4] = {};
    for (int k0 = 0; k0 < Kc; k0 += 16) {
        __syncthreads();
        float4 av = *(const float4*)(A + (size_t)(m0 + lr) * lda + k0 + lc);
        As[lr][lc] = av.x; As[lr][lc+1] = av.y; As[lr][lc+2] = av.z; As[lr][lc+3] = av.w;
        float4 bv = *(const float4*)(B + (size_t)(n0 + lr) * ldb + k0 + lc);
        Bs[lr][lc] = bv.x; Bs[lr][lc+1] = bv.y; Bs[lr][lc+2] = bv.z; Bs[lr][lc+3] = bv.w;
        __syncthreads();
        #pragma unroll
        for (int kk = 0; kk < 16; ++kk) {
            float a[4], b[4];
            #pragma unroll
            for (int i = 0; i < 4; ++i) a[i] = As[ty*4+i][kk];
            #pragma unroll
            for (int j = 0; j < 4; ++j) b[j] = Bs[tx*4+j][kk];
            #pragma unroll
            for (int i = 0; i < 4; ++i)
                #pragma unroll
                for (int j = 0; j < 4; ++j)
                    acc[i][j] += (ACC)a[i] * (ACC)b[j];
        }
    }
    #pragma unroll
    for (int i = 0; i < 4; ++i) {
        float4 o = make_float4((float)acc[i][0], (float)acc[i][1],
                               (float)acc[i][2], (float)acc[i][3]);
        *(float4*)(C + (size_t)(m0 + ty*4 + i) * ldc + n0 + tx*4) = o;
    }
}

// ---------------- Wo repack: WoT[f][e*64+d] = Wo[e][f][d] ----------------
__global__ __launch_bounds__(256)
void repack_wo(const float* __restrict__ Wo, float* __restrict__ WoT)
{
    int idx = blockIdx.x * 256 + threadIdx.x;    // < 1024*512
    int f = idx >> 9, ed = idx & 511, e = ed >> 6, d = ed & 63;
    WoT[idx] = Wo[(size_t)e * (MDIM * DHD) + (size_t)f * DHD + d];
}

// ---------------- top-2 gates (V: sigmoid weights, O: mask) ----------------
__global__ __launch_bounds__(256)
void gate_topk(const float* __restrict__ Gv, const float* __restrict__ Go,
               float2* __restrict__ wv, unsigned* __restrict__ sel)
{
    int item = blockIdx.x * 256 + threadIdx.x;   // < 65536 = MBT*NH
    int bt = item >> 4, h = item & 15;
    const float* g = Gv + (size_t)bt * (NH * NE) + h * NE;
    float b1 = -1e30f, b2 = -1e30f; int e1 = 0, e2 = 0;
    #pragma unroll
    for (int e = 0; e < NE; ++e) {
        float v = g[e];
        if (v > b1)      { b2 = b1; e2 = e1; b1 = v; e1 = e; }
        else if (v > b2) { b2 = v;  e2 = e; }
    }
    float w1 = 1.f / (1.f + __expf(-b1));
    float w2 = 1.f / (1.f + __expf(-b2));
    wv[item] = make_float2(w1, w2);
    const float* go = Go + (size_t)bt * (NH * NE) + h * NE;
    float o1 = -1e30f, o2 = -1e30f; int f1 = 0, f2 = 0;
    #pragma unroll
    for (int e = 0; e < NE; ++e) {
        float v = go[e];
        if (v > o1)      { o2 = o1; f2 = f1; o1 = v; f1 = e; }
        else if (v > o2) { o2 = v;  f2 = e; }
    }
    unsigned mask = (1u << f1) | (1u << f2);
    sel[item] = (unsigned)e1 | ((unsigned)e2 << 4) | (mask << 8);
}

// ---------------- V mix: Vm[bt][h*64+d] = w1*Pv[bt][e1*64+d] + w2*Pv[bt][e2*64+d] ----------------
__global__ __launch_bounds__(256)
void mix_v(const float* __restrict__ Pv, const float2* __restrict__ wv,
           const unsigned* __restrict__ sel, float* __restrict__ Vm)
{
    int idx = blockIdx.x * 256 + threadIdx.x;    // < MBT*1024
    int bt = idx >> 10, hd = idx & 1023, h = hd >> 6, d = hd & 63;
    unsigned s = sel[bt * 16 + h];
    float2 w = wv[bt * 16 + h];
    int e1 = s & 15, e2 = (s >> 4) & 15;
    const float* pv = Pv + (size_t)bt * (NE * DHD);
    Vm[idx] = w.x * pv[e1 * DHD + d] + w.y * pv[e2 * DHD + d];
}

// ---------------- flash attention, fp32: 64 q-rows per WG, key tiles of 64 ----------------
#define SROW 76
__global__ __launch_bounds__(256)
void attn_fa(const float* __restrict__ Q, const float* __restrict__ Kp,
             const float* __restrict__ Vm, float* __restrict__ At)
{
    __shared__ __align__(16) float Qs[64][SROW];
    __shared__ __align__(16) float Ks[64][SROW];   // reused as P after scores
    __shared__ __align__(16) float Vs[64][SROW];
    const int tid = threadIdx.x;
    const int tx = tid & 15, ty = tid >> 4;
    const int q0 = blockIdx.x * 64;
    const int h  = blockIdx.y;
    const int b  = blockIdx.z;
    const int lr = tid >> 4;          // 0..15
    const int lc = (tid & 15) << 2;   // 0..60
    const size_t base = (size_t)b * TSEQ * MDIM + (size_t)h * DHD;

    #pragma unroll
    for (int rep = 0; rep < 4; ++rep) {
        int row = lr + rep * 16;
        float4 v = *(const float4*)(Q + base + (size_t)(q0 + row) * MDIM + lc);
        *(float4*)&Qs[row][lc] = v;
    }

    float m_r[4], l_r[4], acc[4][4];
    #pragma unroll
    for (int i = 0; i < 4; ++i) {
        m_r[i] = -1e30f; l_r[i] = 0.f;
        #pragma unroll
        for (int j = 0; j < 4; ++j) acc[i][j] = 0.f;
    }
    const float scale = 0.125f;   // 64^-0.5

    for (int kb = 0; kb < TSEQ / 64; ++kb) {
        __syncthreads();  // prior iteration done reading Ks(P)/Vs
        #pragma unroll
        for (int rep = 0; rep < 4; ++rep) {
            int row = lr + rep * 16;
            const size_t g = base + (size_t)(kb * 64 + row) * MDIM + lc;
            *(float4*)&Ks[row][lc] = *(const float4*)(Kp + g);
            *(float4*)&Vs[row][lc] = *(const float4*)(Vm + g);
        }
        __syncthreads();
        // scores
        float s[4][4] = {};
        #pragma unroll
        for (int d4 = 0; d4 < DHD; d4 += 4) {
            float4 qa[4], kB[4];
            #pragma unroll
            for (int i = 0; i < 4; ++i) qa[i] = *(const float4*)&Qs[ty*4+i][d4];
            #pragma unroll
            for (int j = 0; j < 4; ++j) kB[j] = *(const float4*)&Ks[tx*4+j][d4];
            #pragma unroll
            for (int i = 0; i < 4; ++i)
                #pragma unroll
                for (int j = 0; j < 4; ++j) {
                    s[i][j] = fmaf(qa[i].x, kB[j].x, s[i][j]);
                    s[i][j] = fmaf(qa[i].y, kB[j].y, s[i][j]);
                    s[i][j] = fmaf(qa[i].z, kB[j].z, s[i][j]);
                    s[i][j] = fmaf(qa[i].w, kB[j].w, s[i][j]);
                }
        }
        __syncthreads();  // everyone done reading Ks; safe to overwrite with P
        #pragma unroll
        for (int i = 0; i < 4; ++i) {
            #pragma unroll
            for (int j = 0; j < 4; ++j) s[i][j] *= scale;
            float rm = fmaxf(fmaxf(s[i][0], s[i][1]), fmaxf(s[i][2], s[i][3]));
            #pragma unroll
            for (int off = 1; off < 16; off <<= 1)
                rm = fmaxf(rm, __shfl_xor(rm, off));
            float mnew = fmaxf(m_r[i], rm);
            float c = __expf(m_r[i] - mnew);
            m_r[i] = mnew;
            float rs = 0.f;
            #pragma unroll
            for (int j = 0; j < 4; ++j) {
                s[i][j] = __expf(s[i][j] - mnew);
                rs += s[i][j];
            }
            #pragma unroll
            for (int off = 1; off < 16; off <<= 1)
                rs += __shfl_xor(rs, off);
            l_r[i] = l_r[i] * c + rs;
            #pragma unroll
            for (int j = 0; j < 4; ++j) acc[i][j] *= c;
            *(float4*)&Ks[ty*4+i][tx*4] = make_float4(s[i][0], s[i][1], s[i][2], s[i][3]);
        }
        __syncthreads();  // P visible
        // PV
        #pragma unroll
        for (int k4 = 0; k4 < 64; k4 += 4) {
            float4 p4[4], vv[4];
            #pragma unroll
            for (int i = 0; i < 4; ++i)  p4[i] = *(const float4*)&Ks[ty*4+i][k4];
            #pragma unroll
            for (int jj = 0; jj < 4; ++jj) vv[jj] = *(const float4*)&Vs[k4+jj][tx*4];
            #pragma unroll
            for (int i = 0; i < 4; ++i) {
                acc[i][0] = fmaf(p4[i].x, vv[0].x, acc[i][0]);
                acc[i][0] = fmaf(p4[i].y, vv[1].x, acc[i][0]);
                acc[i][0] = fmaf(p4[i].z, vv[2].x, acc[i][0]);
                acc[i][0] = fmaf(p4[i].w, vv[3].x, acc[i][0]);
                acc[i][1] = fmaf(p4[i].x, vv[0].y, acc[i][1]);
                acc[i][1] = fmaf(p4[i].y, vv[1].y, acc[i][1]);
                acc[i][1] = fmaf(p4[i].z, vv[2].y, acc[i][1]);
                acc[i][1] = fmaf(p4[i].w, vv[3].y, acc[i][1]);
                acc[i][2] = fmaf(p4[i].x, vv[0].z, acc[i][2]);
                acc[i][2] = fmaf(p4[i].y, vv[1].z, acc[i][2]);
                acc[i][2] = fmaf(p4[i].z, vv[2].z, acc[i][2]);
                acc[i][2] = fmaf(p4[i].w, vv[3].z, acc[i][2]);
                acc[i][3] = fmaf(p4[i].x, vv[0].w, acc[i][3]);
                acc[i][3] = fmaf(p4[i].y, vv[1].w, acc[i][3]);
                acc[i][3] = fmaf(p4[i].z, vv[2].w, acc[i][3]);
                acc[i][3] = fmaf(p4[i].w, vv[3].w, acc[i][3]);
            }
        }
    }
    #pragma unroll
    for (int i = 0; i < 4; ++i) {
        float inv = 1.f / l_r[i];
        float4 o = make_float4(acc[i][0]*inv, acc[i][1]*inv, acc[i][2]*inv, acc[i][3]*inv);
        *(float4*)(At + base + (size_t)(q0 + ty*4 + i) * MDIM + tx*4) = o;
    }
}

// ---------------- U[bt][e*64+d] = sum_h mask_o(bt,h,e) * At[bt][h*64+d] ----------------
__global__ __launch_bounds__(256)
void compute_U(const float* __restrict__ At, const unsigned* __restrict__ sel,
               float* __restrict__ U)
{
    int idx = blockIdx.x * 256 + threadIdx.x;    // < MBT*512
    int bt = idx >> 9, ed = idx & 511, e = ed >> 6, d = ed & 63;
    float sum = 0.f;
    const float* a = At + (size_t)bt * MDIM + d;
    const unsigned* sp = sel + bt * 16;
    #pragma unroll
    for (int h = 0; h < NH; ++h)
        if (sp[h] & (1u << (8 + e))) sum += a[h * DHD];
    U[idx] = sum;
}

extern "C" void kernel_launch(void* const* d_in, const int* in_sizes, int n_in,
                              void* d_out, int out_size, void* d_ws, size_t ws_size,
                              hipStream_t stream)
{
    const float* x  = (const float*)d_in[0];
    const float* Wq = (const float*)d_in[1];
    const float* Wk = (const float*)d_in[2];
    const float* Wv = (const float*)d_in[3];
    const float* Ws = (const float*)d_in[4];
    const float* Wd = (const float*)d_in[5];
    const float* Wo = (const float*)d_in[6];
    float* out = (float*)d_out;
    float* ws = (float*)d_ws;

    float* Q   = ws;                     // 4096*1024
    float* Kp  = Q   + 4194304;          // 4096*1024
    float* Vm  = Kp  + 4194304;          // 4096*1024
    float* At  = Vm  + 4194304;          // 4096*1024
    float* Pv  = At  + 4194304;          // 4096*512
    float* U   = Pv  + 2097152;          // 4096*512
    float* Gv  = U   + 2097152;          // 4096*128
    float* Go  = Gv  + 524288;           // 4096*128
    float* WoT = Go  + 524288;           // 1024*512
    float2*   wvp  = (float2*)(WoT + 524288);    // 65536 float2
    unsigned* selp = (unsigned*)(wvp + 65536);   // 65536 u32

    dim3 blk(256);
    // projections
    gemm_nt<float ><<<dim3(16, 64), blk, 0, stream>>>(x, MDIM, Wq, MDIM, Q,  MDIM, MDIM);
    gemm_nt<float ><<<dim3(16, 64), blk, 0, stream>>>(x, MDIM, Wk, MDIM, Kp, MDIM, MDIM);
    gemm_nt<float ><<<dim3( 8, 64), blk, 0, stream>>>(x, MDIM, Wv, MDIM, Pv, 512,  MDIM);
    // gates in fp64 accumulation (pin top-k ranking against reference)
    gemm_nt<double><<<dim3( 2, 64), blk, 0, stream>>>(x, MDIM, Ws, MDIM, Gv, 128,  MDIM);
    gemm_nt<double><<<dim3( 2, 64), blk, 0, stream>>>(x, MDIM, Wd, MDIM, Go, 128,  MDIM);
    repack_wo<<<2048, blk, 0, stream>>>(Wo, WoT);
    gate_topk<<<256, blk, 0, stream>>>(Gv, Go, wvp, selp);
    mix_v<<<16384, blk, 0, stream>>>(Pv, wvp, selp, Vm);
    attn_fa<<<dim3(TSEQ / 64, NH, NB), blk, 0, stream>>>(Q, Kp, Vm, At);
    compute_U<<<8192, blk, 0, stream>>>(At, selp, U);
    gemm_nt<float ><<<dim3(16, 64), blk, 0, stream>>>(U, 512, WoT, 512, out, MDIM, 512);
}

// Round 2
// 561.548 us; speedup vs baseline: 2.8087x; 2.8087x over previous
//
#include <hip/hip_runtime.h>
#include <math.h>

#define TSEQ 2048
#define NB   2
#define NH   16
#define NE   8
#define DHD  64
#define MDIM 1024
#define MBT  4096   // NB*TSEQ

typedef __attribute__((ext_vector_type(8))) short bf16x8;
typedef __attribute__((ext_vector_type(4))) float f32x4;

__device__ inline unsigned short f2bf(float f) {
    union { float f; unsigned u; } v; v.f = f;
    unsigned r = v.u + 0x7fff + ((v.u >> 16) & 1);
    return (unsigned short)(r >> 16);
}
__device__ inline float bf2f(unsigned short h) {
    union { unsigned u; float f; } v; v.u = ((unsigned)h) << 16;
    return v.f;
}

// ---------------- fp32 -> bf16 cast (8 elems/thread) ----------------
__global__ __launch_bounds__(256)
void cast_bf16(const float* __restrict__ in, unsigned short* __restrict__ out, int n8)
{
    int i = blockIdx.x * 256 + threadIdx.x;
    if (i >= n8) return;
    const float4* p = (const float4*)(in + (size_t)i * 8);
    float4 a = p[0], b = p[1];
    unsigned short o[8] = { f2bf(a.x), f2bf(a.y), f2bf(a.z), f2bf(a.w),
                            f2bf(b.x), f2bf(b.y), f2bf(b.z), f2bf(b.w) };
    *(uint4*)(out + (size_t)i * 8) = *(const uint4*)o;
}

// ---------------- bf16 MFMA GEMM: C[M,N]=A[M,K]*B[N,K]^T, bf16 out ----------------
// grid=(N/128, M/128), 256 threads (4 waves, 2x2 of 64x64)
__global__ __launch_bounds__(256)
void mfma_gemm(const unsigned short* __restrict__ A,
               const unsigned short* __restrict__ B,
               unsigned short* __restrict__ C, int N, int K)
{
    __shared__ __align__(16) unsigned short As[128 * 40];
    __shared__ __align__(16) unsigned short Bs[128 * 40];
    const int tid = threadIdx.x;
    const int lane = tid & 63, wave = tid >> 6;
    const int m0 = blockIdx.y * 128, n0 = blockIdx.x * 128;
    const int wm = (wave >> 1) * 64, wn = (wave & 1) * 64;
    const int sr = tid >> 2, sc = (tid & 3) * 8;
    const int fr = lane & 15, fg = lane >> 4;

    f32x4 acc[4][4];
    #pragma unroll
    for (int i = 0; i < 4; ++i)
        #pragma unroll
        for (int j = 0; j < 4; ++j) acc[i][j] = (f32x4)0.f;

    for (int k0 = 0; k0 < K; k0 += 32) {
        __syncthreads();
        uint4 a0 = *(const uint4*)(A + (size_t)(m0 + sr) * K + k0 + sc);
        uint4 a1 = *(const uint4*)(A + (size_t)(m0 + 64 + sr) * K + k0 + sc);
        uint4 b0 = *(const uint4*)(B + (size_t)(n0 + sr) * K + k0 + sc);
        uint4 b1 = *(const uint4*)(B + (size_t)(n0 + 64 + sr) * K + k0 + sc);
        *(uint4*)(As + sr * 40 + sc)        = a0;
        *(uint4*)(As + (64 + sr) * 40 + sc) = a1;
        *(uint4*)(Bs + sr * 40 + sc)        = b0;
        *(uint4*)(Bs + (64 + sr) * 40 + sc) = b1;
        __syncthreads();
        bf16x8 af[4], bfr[4];
        #pragma unroll
        for (int t = 0; t < 4; ++t) {
            af[t]  = *(const bf16x8*)(As + (wm + t * 16 + fr) * 40 + fg * 8);
            bfr[t] = *(const bf16x8*)(Bs + (wn + t * 16 + fr) * 40 + fg * 8);
        }
        #pragma unroll
        for (int i = 0; i < 4; ++i)
            #pragma unroll
            for (int j = 0; j < 4; ++j)
                acc[i][j] = __builtin_amdgcn_mfma_f32_16x16x32_bf16(af[i], bfr[j], acc[i][j], 0, 0, 0);
    }
    #pragma unroll
    for (int i = 0; i < 4; ++i)
        #pragma unroll
        for (int j = 0; j < 4; ++j)
            #pragma unroll
            for (int rr = 0; rr < 4; ++rr) {
                int row = m0 + wm + i * 16 + fg * 4 + rr;
                int col = n0 + wn + j * 16 + fr;
                C[(size_t)row * N + col] = f2bf(acc[i][j][rr]);
            }
}

// ---------------- fp32-in GEMM (kept for gates fp64-acc + final fp32) ----------------
template <typename ACC>
__global__ __launch_bounds__(256)
void gemm_nt(const float* __restrict__ A, int lda,
             const float* __restrict__ B, int ldb,
             float* __restrict__ C, int ldc, int Kc)
{
    __shared__ float As[64][17];
    __shared__ float Bs[64][17];
    const int tid = threadIdx.x;
    const int tx = tid & 15, ty = tid >> 4;
    const int m0 = blockIdx.y * 64, n0 = blockIdx.x * 64;
    const int lr = tid >> 2;
    const int lc = (tid & 3) << 2;
    ACC acc[4][4] = {};
    for (int k0 = 0; k0 < Kc; k0 += 16) {
        __syncthreads();
        float4 av = *(const float4*)(A + (size_t)(m0 + lr) * lda + k0 + lc);
        As[lr][lc] = av.x; As[lr][lc+1] = av.y; As[lr][lc+2] = av.z; As[lr][lc+3] = av.w;
        float4 bv = *(const float4*)(B + (size_t)(n0 + lr) * ldb + k0 + lc);
        Bs[lr][lc] = bv.x; Bs[lr][lc+1] = bv.y; Bs[lr][lc+2] = bv.z; Bs[lr][lc+3] = bv.w;
        __syncthreads();
        #pragma unroll
        for (int kk = 0; kk < 16; ++kk) {
            float a[4], b[4];
            #pragma unroll
            for (int i = 0; i < 4; ++i) a[i] = As[ty*4+i][kk];
            #pragma unroll
            for (int j = 0; j < 4; ++j) b[j] = Bs[tx*4+j][kk];
            #pragma unroll
            for (int i = 0; i < 4; ++i)
                #pragma unroll
                for (int j = 0; j < 4; ++j)
                    acc[i][j] += (ACC)a[i] * (ACC)b[j];
        }
    }
    #pragma unroll
    for (int i = 0; i < 4; ++i) {
        float4 o = make_float4((float)acc[i][0], (float)acc[i][1],
                               (float)acc[i][2], (float)acc[i][3]);
        *(float4*)(C + (size_t)(m0 + ty*4 + i) * ldc + n0 + tx*4) = o;
    }
}

// ---------------- Wo repack ----------------
__global__ __launch_bounds__(256)
void repack_wo(const float* __restrict__ Wo, float* __restrict__ WoT)
{
    int idx = blockIdx.x * 256 + threadIdx.x;
    int f = idx >> 9, ed = idx & 511, e = ed >> 6, d = ed & 63;
    WoT[idx] = Wo[(size_t)e * (MDIM * DHD) + (size_t)f * DHD + d];
}

// ---------------- top-2 gates ----------------
__global__ __launch_bounds__(256)
void gate_topk(const float* __restrict__ Gv, const float* __restrict__ Go,
               float2* __restrict__ wv, unsigned* __restrict__ sel)
{
    int item = blockIdx.x * 256 + threadIdx.x;
    int bt = item >> 4, h = item & 15;
    const float* g = Gv + (size_t)bt * (NH * NE) + h * NE;
    float b1 = -1e30f, b2 = -1e30f; int e1 = 0, e2 = 0;
    #pragma unroll
    for (int e = 0; e < NE; ++e) {
        float v = g[e];
        if (v > b1)      { b2 = b1; e2 = e1; b1 = v; e1 = e; }
        else if (v > b2) { b2 = v;  e2 = e; }
    }
    float w1 = 1.f / (1.f + __expf(-b1));
    float w2 = 1.f / (1.f + __expf(-b2));
    wv[item] = make_float2(w1, w2);
    const float* go = Go + (size_t)bt * (NH * NE) + h * NE;
    float o1 = -1e30f, o2 = -1e30f; int f1 = 0, f2 = 0;
    #pragma unroll
    for (int e = 0; e < NE; ++e) {
        float v = go[e];
        if (v > o1)      { o2 = o1; f2 = f1; o1 = v; f1 = e; }
        else if (v > o2) { o2 = v;  f2 = e; }
    }
    unsigned mask = (1u << f1) | (1u << f2);
    sel[item] = (unsigned)e1 | ((unsigned)e2 << 4) | (mask << 8);
}

// ---------------- V mix (bf16 in/out) ----------------
__global__ __launch_bounds__(256)
void mix_v_bf(const unsigned short* __restrict__ Pvb, const float2* __restrict__ wv,
              const unsigned* __restrict__ sel, unsigned short* __restrict__ Vmb)
{
    int idx = blockIdx.x * 256 + threadIdx.x;     // < MBT*16*8
    int bt = idx >> 7, hc = idx & 127, h = hc >> 3, dc = (hc & 7) * 8;
    unsigned s = sel[bt * 16 + h];
    float2 w = wv[bt * 16 + h];
    int e1 = s & 15, e2 = (s >> 4) & 15;
    uint4 a = *(const uint4*)(Pvb + (size_t)bt * 512 + e1 * 64 + dc);
    uint4 b = *(const uint4*)(Pvb + (size_t)bt * 512 + e2 * 64 + dc);
    unsigned short ea[8], eb[8], eo[8];
    *(uint4*)ea = a; *(uint4*)eb = b;
    #pragma unroll
    for (int j = 0; j < 8; ++j)
        eo[j] = f2bf(w.x * bf2f(ea[j]) + w.y * bf2f(eb[j]));
    *(uint4*)(Vmb + (size_t)bt * 1024 + h * 64 + dc) = *(const uint4*)eo;
}

// ---------------- MFMA flash attention: 64 q-rows/block, 4 waves ----------------
#define SP 72   // padded LDS row stride (bf16 elems) = 144B (16B-aligned)
__global__ __launch_bounds__(256)
void attn_mfma(const unsigned short* __restrict__ Qb,
               const unsigned short* __restrict__ Kb,
               const unsigned short* __restrict__ Vb,
               float* __restrict__ At)
{
    __shared__ __align__(16) unsigned short Qs[64 * SP];
    __shared__ __align__(16) unsigned short Ks[64 * SP];
    __shared__ __align__(16) unsigned short Vt[64 * SP];   // d-major, chunk-swizzled
    __shared__ __align__(16) unsigned short Ps[64 * SP];
    const int tid = threadIdx.x;
    const int lane = tid & 63, wave = tid >> 6;
    const int fr = lane & 15, fg = lane >> 4;
    const int q0 = blockIdx.x * 64;
    const int h = blockIdx.y, b = blockIdx.z;
    const size_t base = ((size_t)b * TSEQ) * MDIM + h * DHD;

    // stage Q once
    {
        int s = tid;
        #pragma unroll
        for (int it = 0; it < 2; ++it, s += 256) {
            int rr = s >> 3, cc = (s & 7) * 8;
            *(uint4*)(Qs + rr * SP + cc) =
                *(const uint4*)(Qb + base + (size_t)(q0 + rr) * MDIM + cc);
        }
    }
    float m_r[4], l_r[4];
    f32x4 o[4];
    #pragma unroll
    for (int i = 0; i < 4; ++i) { m_r[i] = -1e30f; l_r[i] = 0.f; o[i] = (f32x4)0.f; }

    __syncthreads();
    bf16x8 qa0 = *(const bf16x8*)(Qs + (wave * 16 + fr) * SP + fg * 8);
    bf16x8 qa1 = *(const bf16x8*)(Qs + (wave * 16 + fr) * SP + fg * 8 + 32);
    const float scale = 0.125f;

    for (int kb = 0; kb < TSEQ / 64; ++kb) {
        __syncthreads();   // all waves done reading Ks/Vt from prev iter
        {
            int s = tid;
            #pragma unroll
            for (int it = 0; it < 2; ++it, s += 256) {
                int rr = s >> 3, cc = (s & 7) * 8;
                *(uint4*)(Ks + rr * SP + cc) =
                    *(const uint4*)(Kb + base + (size_t)(kb * 64 + rr) * MDIM + cc);
            }
            s = tid;
            #pragma unroll
            for (int it = 0; it < 2; ++it, s += 256) {
                int key = s >> 3, dc = s & 7;
                uint4 v = *(const uint4*)(Vb + base + (size_t)(kb * 64 + key) * MDIM + dc * 8);
                unsigned short e[8]; *(uint4*)e = v;
                int kc = key >> 3, kl = key & 7;
                #pragma unroll
                for (int j = 0; j < 8; ++j) {
                    int d = dc * 8 + j;
                    Vt[d * SP + ((kc ^ (d >> 3)) * 8 + kl)] = e[j];
                }
            }
        }
        __syncthreads();
        // QK^T: wave's 16 q-rows x 64 keys
        f32x4 s4[4];
        #pragma unroll
        for (int nt = 0; nt < 4; ++nt) {
            s4[nt] = (f32x4)0.f;
            bf16x8 k0f = *(const bf16x8*)(Ks + (nt * 16 + fr) * SP + fg * 8);
            bf16x8 k1f = *(const bf16x8*)(Ks + (nt * 16 + fr) * SP + fg * 8 + 32);
            s4[nt] = __builtin_amdgcn_mfma_f32_16x16x32_bf16(qa0, k0f, s4[nt], 0, 0, 0);
            s4[nt] = __builtin_amdgcn_mfma_f32_16x16x32_bf16(qa1, k1f, s4[nt], 0, 0, 0);
        }
        // online softmax (rows = fg*4+rr, cols = fr+16*nt)
        float mx[4];
        #pragma unroll
        for (int rr = 0; rr < 4; ++rr)
            mx[rr] = fmaxf(fmaxf(s4[0][rr], s4[1][rr]), fmaxf(s4[2][rr], s4[3][rr])) * scale;
        #pragma unroll
        for (int off = 1; off < 16; off <<= 1)
            #pragma unroll
            for (int rr = 0; rr < 4; ++rr)
                mx[rr] = fmaxf(mx[rr], __shfl_xor(mx[rr], off));
        float cf[4], rs[4];
        #pragma unroll
        for (int rr = 0; rr < 4; ++rr) {
            float mnew = fmaxf(m_r[rr], mx[rr]);
            cf[rr] = __expf(m_r[rr] - mnew);
            m_r[rr] = mnew;
            rs[rr] = 0.f;
        }
        #pragma unroll
        for (int nt = 0; nt < 4; ++nt)
            #pragma unroll
            for (int rr = 0; rr < 4; ++rr) {
                float p = __expf(s4[nt][rr] * scale - m_r[rr]);
                s4[nt][rr] = p;
                rs[rr] += p;
            }
        #pragma unroll
        for (int off = 1; off < 16; off <<= 1)
            #pragma unroll
            for (int rr = 0; rr < 4; ++rr)
                rs[rr] += __shfl_xor(rs[rr], off);
        #pragma unroll
        for (int rr = 0; rr < 4; ++rr)
            l_r[rr] = l_r[rr] * cf[rr] + rs[rr];
        #pragma unroll
        for (int dt = 0; dt < 4; ++dt) {
            f32x4 t = o[dt];
            t[0] *= cf[0]; t[1] *= cf[1]; t[2] *= cf[2]; t[3] *= cf[3];
            o[dt] = t;
        }
        // write P (bf16) — consumed only by this wave (rows 16*wave..+15)
        #pragma unroll
        for (int nt = 0; nt < 4; ++nt)
            #pragma unroll
            for (int rr = 0; rr < 4; ++rr)
                Ps[(wave * 16 + fg * 4 + rr) * SP + fr + 16 * nt] = f2bf(s4[nt][rr]);
        // PV (same-wave in-order DS: no barrier needed for Ps)
        bf16x8 pa0 = *(const bf16x8*)(Ps + (wave * 16 + fr) * SP + fg * 8);
        bf16x8 pa1 = *(const bf16x8*)(Ps + (wave * 16 + fr) * SP + fg * 8 + 32);
        #pragma unroll
        for (int dt = 0; dt < 4; ++dt) {
            int d = fr + 16 * dt;
            bf16x8 b0 = *(const bf16x8*)(Vt + d * SP + ((fg       ^ (d >> 3)) * 8));
            bf16x8 b1 = *(const bf16x8*)(Vt + d * SP + (((fg + 4) ^ (d >> 3)) * 8));
            o[dt] = __builtin_amdgcn_mfma_f32_16x16x32_bf16(pa0, b0, o[dt], 0, 0, 0);
            o[dt] = __builtin_amdgcn_mfma_f32_16x16x32_bf16(pa1, b1, o[dt], 0, 0, 0);
        }
    }
    #pragma unroll
    for (int rr = 0; rr < 4; ++rr) {
        float inv = 1.f / l_r[rr];
        int row = q0 + wave * 16 + fg * 4 + rr;
        #pragma unroll
        for (int dt = 0; dt < 4; ++dt)
            At[base + (size_t)row * MDIM + fr + 16 * dt] = o[dt][rr] * inv;
    }
}

// ---------------- U[bt][e*64+d] = sum_h mask_o * At[bt][h*64+d] ----------------
__global__ __launch_bounds__(256)
void compute_U(const float* __restrict__ At, const unsigned* __restrict__ sel,
               float* __restrict__ U)
{
    int idx = blockIdx.x * 256 + threadIdx.x;
    int bt = idx >> 9, ed = idx & 511, e = ed >> 6, d = ed & 63;
    float sum = 0.f;
    const float* a = At + (size_t)bt * MDIM + d;
    const unsigned* sp = sel + bt * 16;
    #pragma unroll
    for (int h = 0; h < NH; ++h)
        if (sp[h] & (1u << (8 + e))) sum += a[h * DHD];
    U[idx] = sum;
}

extern "C" void kernel_launch(void* const* d_in, const int* in_sizes, int n_in,
                              void* d_out, int out_size, void* d_ws, size_t ws_size,
                              hipStream_t stream)
{
    const float* x  = (const float*)d_in[0];
    const float* Wq = (const float*)d_in[1];
    const float* Wk = (const float*)d_in[2];
    const float* Wv = (const float*)d_in[3];
    const float* Ws = (const float*)d_in[4];
    const float* Wd = (const float*)d_in[5];
    const float* Wo = (const float*)d_in[6];
    float* out = (float*)d_out;
    float* ws = (float*)d_ws;

    float* Gv  = ws;                         // 524288
    float* Go  = Gv + 524288;                // 524288
    float* At  = Go + 524288;                // 4194304
    float* U   = At + 4194304;               // 2097152
    float* WoT = U + 2097152;                // 524288
    float2*   wvp  = (float2*)(WoT + 524288);   // 65536 float2
    unsigned* selp = (unsigned*)(wvp + 65536);  // 65536 u32
    unsigned short* xb  = (unsigned short*)(selp + 65536);
    unsigned short* Qbf = xb  + 4194304;
    unsigned short* Kbf = Qbf + 4194304;
    unsigned short* Pvb = Kbf + 4194304;     // 2097152
    unsigned short* Vmb = Pvb + 2097152;     // 4194304
    unsigned short* Wqb = Vmb + 4194304;     // 1048576
    unsigned short* Wkb = Wqb + 1048576;     // 1048576
    unsigned short* Wvb = Wkb + 1048576;     // 524288

    dim3 blk(256);
    cast_bf16<<<2048, blk, 0, stream>>>(x,  xb,  524288);
    cast_bf16<<<512,  blk, 0, stream>>>(Wq, Wqb, 131072);
    cast_bf16<<<512,  blk, 0, stream>>>(Wk, Wkb, 131072);
    cast_bf16<<<256,  blk, 0, stream>>>(Wv, Wvb, 65536);

    mfma_gemm<<<dim3(8, 32), blk, 0, stream>>>(xb, Wqb, Qbf, 1024, 1024);
    mfma_gemm<<<dim3(8, 32), blk, 0, stream>>>(xb, Wkb, Kbf, 1024, 1024);
    mfma_gemm<<<dim3(4, 32), blk, 0, stream>>>(xb, Wvb, Pvb, 512, 1024);

    // gates: fp64 accumulation pins top-k ranking to the reference
    gemm_nt<double><<<dim3(2, 64), blk, 0, stream>>>(x, MDIM, Ws, MDIM, Gv, 128, MDIM);
    gemm_nt<double><<<dim3(2, 64), blk, 0, stream>>>(x, MDIM, Wd, MDIM, Go, 128, MDIM);

    repack_wo<<<2048, blk, 0, stream>>>(Wo, WoT);
    gate_topk<<<256, blk, 0, stream>>>(Gv, Go, wvp, selp);
    mix_v_bf<<<2048, blk, 0, stream>>>(Pvb, wvp, selp, Vmb);

    attn_mfma<<<dim3(TSEQ / 64, NH, NB), blk, 0, stream>>>(Qbf, Kbf, Vmb, At);

    compute_U<<<8192, blk, 0, stream>>>(At, selp, U);
    gemm_nt<float><<<dim3(16, 64), blk, 0, stream>>>(U, 512, WoT, 512, out, MDIM, 512);
}

// Round 3
// 444.757 us; speedup vs baseline: 3.5462x; 1.2626x over previous
//
#include <hip/hip_runtime.h>
#include <math.h>

#define TSEQ 2048
#define NB   2
#define NH   16
#define NE   8
#define DHD  64
#define MDIM 1024
#define MBT  4096   // NB*TSEQ
#define LDQKV 2560  // Q(1024) | K(1024) | V-experts(512)

typedef __attribute__((ext_vector_type(8))) short bf16x8;
typedef __attribute__((ext_vector_type(4))) float f32x4;

__device__ inline unsigned short f2bf(float f) {
    union { float f; unsigned u; } v; v.f = f;
    unsigned r = v.u + 0x7fff + ((v.u >> 16) & 1);
    return (unsigned short)(r >> 16);
}
__device__ inline float bf2f(unsigned short h) {
    union { unsigned u; float f; } v; v.u = ((unsigned)h) << 16;
    return v.f;
}

// ---------------- fp32 -> bf16 cast (8 elems/thread) ----------------
__global__ __launch_bounds__(256)
void cast_bf16(const float* __restrict__ in, unsigned short* __restrict__ out, int n8)
{
    int i = blockIdx.x * 256 + threadIdx.x;
    if (i >= n8) return;
    const float4* p = (const float4*)(in + (size_t)i * 8);
    float4 a = p[0], b = p[1];
    unsigned short o[8] = { f2bf(a.x), f2bf(a.y), f2bf(a.z), f2bf(a.w),
                            f2bf(b.x), f2bf(b.y), f2bf(b.z), f2bf(b.w) };
    *(uint4*)(out + (size_t)i * 8) = *(const uint4*)o;
}

// ---------------- concat Ws|Wd into Wsd[256][1024] ----------------
__global__ __launch_bounds__(256)
void copy_wsd(const float* __restrict__ Ws, const float* __restrict__ Wd,
              float* __restrict__ Wsd)
{
    int i = blockIdx.x * 256 + threadIdx.x;   // < 65536 float4
    const float4* s = (i < 32768) ? (const float4*)Ws + i : (const float4*)Wd + (i - 32768);
    ((float4*)Wsd)[i] = *s;
}

// ---------------- bf16 MFMA GEMM: C[M,N]=A[M,K]*B[N,K]^T, bf16 out ----------------
__global__ __launch_bounds__(256)
void mfma_gemm(const unsigned short* __restrict__ A,
               const unsigned short* __restrict__ B,
               unsigned short* __restrict__ C, int N, int K)
{
    __shared__ __align__(16) unsigned short As[128 * 40];
    __shared__ __align__(16) unsigned short Bs[128 * 40];
    const int tid = threadIdx.x;
    const int lane = tid & 63, wave = tid >> 6;
    const int m0 = blockIdx.y * 128, n0 = blockIdx.x * 128;
    const int wm = (wave >> 1) * 64, wn = (wave & 1) * 64;
    const int sr = tid >> 2, sc = (tid & 3) * 8;
    const int fr = lane & 15, fg = lane >> 4;

    f32x4 acc[4][4];
    #pragma unroll
    for (int i = 0; i < 4; ++i)
        #pragma unroll
        for (int j = 0; j < 4; ++j) acc[i][j] = (f32x4)0.f;

    for (int k0 = 0; k0 < K; k0 += 32) {
        __syncthreads();
        uint4 a0 = *(const uint4*)(A + (size_t)(m0 + sr) * K + k0 + sc);
        uint4 a1 = *(const uint4*)(A + (size_t)(m0 + 64 + sr) * K + k0 + sc);
        uint4 b0 = *(const uint4*)(B + (size_t)(n0 + sr) * K + k0 + sc);
        uint4 b1 = *(const uint4*)(B + (size_t)(n0 + 64 + sr) * K + k0 + sc);
        *(uint4*)(As + sr * 40 + sc)        = a0;
        *(uint4*)(As + (64 + sr) * 40 + sc) = a1;
        *(uint4*)(Bs + sr * 40 + sc)        = b0;
        *(uint4*)(Bs + (64 + sr) * 40 + sc) = b1;
        __syncthreads();
        bf16x8 af[4], bfr[4];
        #pragma unroll
        for (int t = 0; t < 4; ++t) {
            af[t]  = *(const bf16x8*)(As + (wm + t * 16 + fr) * 40 + fg * 8);
            bfr[t] = *(const bf16x8*)(Bs + (wn + t * 16 + fr) * 40 + fg * 8);
        }
        #pragma unroll
        for (int i = 0; i < 4; ++i)
            #pragma unroll
            for (int j = 0; j < 4; ++j)
                acc[i][j] = __builtin_amdgcn_mfma_f32_16x16x32_bf16(af[i], bfr[j], acc[i][j], 0, 0, 0);
    }
    #pragma unroll
    for (int i = 0; i < 4; ++i)
        #pragma unroll
        for (int j = 0; j < 4; ++j)
            #pragma unroll
            for (int rr = 0; rr < 4; ++rr) {
                int row = m0 + wm + i * 16 + fg * 4 + rr;
                int col = n0 + wn + j * 16 + fr;
                C[(size_t)row * N + col] = f2bf(acc[i][j][rr]);
            }
}

// ---------------- split-bf16 3-pass MFMA GEMM, fp32 out (final projection) ----------------
// C[4096,1024] = (Uh+Ul)[4096,512] * (Wh+Wl)[1024,512]^T  (drop Ul*Wl)
__global__ __launch_bounds__(256)
void mfma_gemm3(const unsigned short* __restrict__ Ah, const unsigned short* __restrict__ Al,
                const unsigned short* __restrict__ Bh, const unsigned short* __restrict__ Bl,
                float* __restrict__ C)
{
    const int Kc = 512, N = 1024;
    __shared__ __align__(16) unsigned short Ash[128 * 40];
    __shared__ __align__(16) unsigned short Asl[128 * 40];
    __shared__ __align__(16) unsigned short Bsh[128 * 40];
    __shared__ __align__(16) unsigned short Bsl[128 * 40];
    const int tid = threadIdx.x;
    const int lane = tid & 63, wave = tid >> 6;
    const int m0 = blockIdx.y * 128, n0 = blockIdx.x * 128;
    const int wm = (wave >> 1) * 64, wn = (wave & 1) * 64;
    const int sr = tid >> 2, sc = (tid & 3) * 8;
    const int fr = lane & 15, fg = lane >> 4;

    f32x4 acc[4][4];
    #pragma unroll
    for (int i = 0; i < 4; ++i)
        #pragma unroll
        for (int j = 0; j < 4; ++j) acc[i][j] = (f32x4)0.f;

    for (int k0 = 0; k0 < Kc; k0 += 32) {
        __syncthreads();
        #pragma unroll
        for (int half = 0; half < 2; ++half) {
            int r = sr + half * 64;
            *(uint4*)(Ash + r * 40 + sc) = *(const uint4*)(Ah + (size_t)(m0 + r) * Kc + k0 + sc);
            *(uint4*)(Asl + r * 40 + sc) = *(const uint4*)(Al + (size_t)(m0 + r) * Kc + k0 + sc);
            *(uint4*)(Bsh + r * 40 + sc) = *(const uint4*)(Bh + (size_t)(n0 + r) * Kc + k0 + sc);
            *(uint4*)(Bsl + r * 40 + sc) = *(const uint4*)(Bl + (size_t)(n0 + r) * Kc + k0 + sc);
        }
        __syncthreads();
        bf16x8 ah[4], al[4], bh[4], bl[4];
        #pragma unroll
        for (int t = 0; t < 4; ++t) {
            ah[t] = *(const bf16x8*)(Ash + (wm + t * 16 + fr) * 40 + fg * 8);
            al[t] = *(const bf16x8*)(Asl + (wm + t * 16 + fr) * 40 + fg * 8);
            bh[t] = *(const bf16x8*)(Bsh + (wn + t * 16 + fr) * 40 + fg * 8);
            bl[t] = *(const bf16x8*)(Bsl + (wn + t * 16 + fr) * 40 + fg * 8);
        }
        #pragma unroll
        for (int i = 0; i < 4; ++i)
            #pragma unroll
            for (int j = 0; j < 4; ++j) {
                acc[i][j] = __builtin_amdgcn_mfma_f32_16x16x32_bf16(ah[i], bh[j], acc[i][j], 0, 0, 0);
                acc[i][j] = __builtin_amdgcn_mfma_f32_16x16x32_bf16(ah[i], bl[j], acc[i][j], 0, 0, 0);
                acc[i][j] = __builtin_amdgcn_mfma_f32_16x16x32_bf16(al[i], bh[j], acc[i][j], 0, 0, 0);
            }
    }
    #pragma unroll
    for (int i = 0; i < 4; ++i)
        #pragma unroll
        for (int j = 0; j < 4; ++j)
            #pragma unroll
            for (int rr = 0; rr < 4; ++rr) {
                int row = m0 + wm + i * 16 + fg * 4 + rr;
                int col = n0 + wn + j * 16 + fr;
                C[(size_t)row * N + col] = acc[i][j][rr];
            }
}

// ---------------- fp32-in GEMM, fp64 accumulate (gates) ----------------
template <typename ACC>
__global__ __launch_bounds__(256)
void gemm_nt(const float* __restrict__ A, int lda,
             const float* __restrict__ B, int ldb,
             float* __restrict__ C, int ldc, int Kc)
{
    __shared__ float As[64][17];
    __shared__ float Bs[64][17];
    const int tid = threadIdx.x;
    const int tx = tid & 15, ty = tid >> 4;
    const int m0 = blockIdx.y * 64, n0 = blockIdx.x * 64;
    const int lr = tid >> 2;
    const int lc = (tid & 3) << 2;
    ACC acc[4][4] = {};
    for (int k0 = 0; k0 < Kc; k0 += 16) {
        __syncthreads();
        float4 av = *(const float4*)(A + (size_t)(m0 + lr) * lda + k0 + lc);
        As[lr][lc] = av.x; As[lr][lc+1] = av.y; As[lr][lc+2] = av.z; As[lr][lc+3] = av.w;
        float4 bv = *(const float4*)(B + (size_t)(n0 + lr) * ldb + k0 + lc);
        Bs[lr][lc] = bv.x; Bs[lr][lc+1] = bv.y; Bs[lr][lc+2] = bv.z; Bs[lr][lc+3] = bv.w;
        __syncthreads();
        #pragma unroll
        for (int kk = 0; kk < 16; ++kk) {
            float a[4], b[4];
            #pragma unroll
            for (int i = 0; i < 4; ++i) a[i] = As[ty*4+i][kk];
            #pragma unroll
            for (int j = 0; j < 4; ++j) b[j] = Bs[tx*4+j][kk];
            #pragma unroll
            for (int i = 0; i < 4; ++i)
                #pragma unroll
                for (int j = 0; j < 4; ++j)
                    acc[i][j] += (ACC)a[i] * (ACC)b[j];
        }
    }
    #pragma unroll
    for (int i = 0; i < 4; ++i) {
        float4 o = make_float4((float)acc[i][0], (float)acc[i][1],
                               (float)acc[i][2], (float)acc[i][3]);
        *(float4*)(C + (size_t)(m0 + ty*4 + i) * ldc + n0 + tx*4) = o;
    }
}

// ---------------- Wo repack + bf16 split: WoT[f][e*64+d] = Wo[e][f][d] ----------------
__global__ __launch_bounds__(256)
void repack_wo_split(const float* __restrict__ Wo,
                     unsigned short* __restrict__ Wh, unsigned short* __restrict__ Wl)
{
    int idx = blockIdx.x * 256 + threadIdx.x;    // < 524288
    int f = idx >> 9, ed = idx & 511, e = ed >> 6, d = ed & 63;
    float v = Wo[(size_t)e * (MDIM * DHD) + (size_t)f * DHD + d];
    unsigned short hi = f2bf(v);
    Wh[idx] = hi;
    Wl[idx] = f2bf(v - bf2f(hi));
}

// ---------------- top-2 gates (V: sigmoid weights, O: mask) ----------------
__global__ __launch_bounds__(256)
void gate_topk(const float* __restrict__ Gsd,
               float2* __restrict__ wv, unsigned* __restrict__ sel)
{
    int item = blockIdx.x * 256 + threadIdx.x;   // < 65536
    int bt = item >> 4, h = item & 15;
    const float* g = Gsd + (size_t)bt * 256 + h * NE;
    float b1 = -1e30f, b2 = -1e30f; int e1 = 0, e2 = 0;
    #pragma unroll
    for (int e = 0; e < NE; ++e) {
        float v = g[e];
        if (v > b1)      { b2 = b1; e2 = e1; b1 = v; e1 = e; }
        else if (v > b2) { b2 = v;  e2 = e; }
    }
    float w1 = 1.f / (1.f + __expf(-b1));
    float w2 = 1.f / (1.f + __expf(-b2));
    wv[item] = make_float2(w1, w2);
    const float* go = g + 128;
    float o1 = -1e30f, o2 = -1e30f; int f1 = 0, f2 = 0;
    #pragma unroll
    for (int e = 0; e < NE; ++e) {
        float v = go[e];
        if (v > o1)      { o2 = o1; f2 = f1; o1 = v; f1 = e; }
        else if (v > o2) { o2 = v;  f2 = e; }
    }
    unsigned mask = (1u << f1) | (1u << f2);
    sel[item] = (unsigned)e1 | ((unsigned)e2 << 4) | (mask << 8);
}

// ---------------- V mix + transpose: Vtg[b][h][d][t] ----------------
__global__ __launch_bounds__(256)
void vtrans(const unsigned short* __restrict__ QKVb, const float2* __restrict__ wv,
            const unsigned* __restrict__ sel, unsigned short* __restrict__ Vtg)
{
    int idx = blockIdx.x * 256 + threadIdx.x;    // < 524288
    int tc = idx & 255;
    int d  = (idx >> 8) & 63;
    int h  = (idx >> 14) & 15;
    int b  = idx >> 18;
    unsigned short o[8];
    #pragma unroll
    for (int j = 0; j < 8; ++j) {
        int bt = b * TSEQ + tc * 8 + j;
        unsigned s = sel[bt * 16 + h];
        float2 w = wv[bt * 16 + h];
        int e1 = s & 15, e2 = (s >> 4) & 15;
        const unsigned short* pv = QKVb + (size_t)bt * LDQKV + 2048;
        float v = w.x * bf2f(pv[e1 * 64 + d]) + w.y * bf2f(pv[e2 * 64 + d]);
        o[j] = f2bf(v);
    }
    *(uint4*)(Vtg + ((size_t)((b * NH + h) * DHD + d)) * TSEQ + tc * 8) = *(const uint4*)o;
}

// ---------------- MFMA flash attention: 64 q-rows, 128-key tiles, 4 waves ----------------
#define SPK 72    // K/Q row stride (bf16 elems)
#define SPV 136   // V^T row stride (128 keys + pad)
#define SPP 144   // P row stride (aliased over Ks: 64*144 == 128*72)
__global__ __launch_bounds__(256)
void attn_mfma(const unsigned short* __restrict__ QKVb,
               const unsigned short* __restrict__ Vtg,
               float* __restrict__ At)
{
    __shared__ __align__(16) unsigned short Qs[64 * SPK];
    __shared__ __align__(16) unsigned short Ks[128 * SPK];   // aliased as P[64][SPP]
    __shared__ __align__(16) unsigned short Vt[64 * SPV];
    const int tid = threadIdx.x;
    const int lane = tid & 63, wave = tid >> 6;
    const int fr = lane & 15, fg = lane >> 4;
    const int q0 = blockIdx.x * 64;
    const int h = blockIdx.y, b = blockIdx.z;
    const size_t base_q = ((size_t)b * TSEQ) * LDQKV + h * DHD;          // Q cols
    const size_t base_k = base_q + 1024;                                 // K cols
    const size_t base_v = ((size_t)(b * NH + h) * DHD) * TSEQ;           // Vtg
    const size_t base_o = ((size_t)b * TSEQ) * MDIM + h * DHD;

    // stage Q once: 64 rows x 8 chunks
    #pragma unroll
    for (int it = 0; it < 2; ++it) {
        int s = tid + it * 256;
        int rr = s >> 3, cc = (s & 7) * 8;
        *(uint4*)(Qs + rr * SPK + cc) =
            *(const uint4*)(QKVb + base_q + (size_t)(q0 + rr) * LDQKV + cc);
    }
    float m_r[4], l_r[4];
    f32x4 o[4];
    #pragma unroll
    for (int i = 0; i < 4; ++i) { m_r[i] = -1e30f; l_r[i] = 0.f; o[i] = (f32x4)0.f; }

    __syncthreads();
    bf16x8 qa0 = *(const bf16x8*)(Qs + (wave * 16 + fr) * SPK + fg * 8);
    bf16x8 qa1 = *(const bf16x8*)(Qs + (wave * 16 + fr) * SPK + fg * 8 + 32);
    const float scale = 0.125f;

    for (int kb = 0; kb < TSEQ / 128; ++kb) {
        __syncthreads();   // prev iter: all PV reads of Ks(P)/Vt done
        // stage K: 128 rows x 8 chunks = 1024 chunk-loads
        #pragma unroll
        for (int it = 0; it < 4; ++it) {
            int s = tid + it * 256;
            int rr = s >> 3, cc = (s & 7) * 8;
            *(uint4*)(Ks + rr * SPK + cc) =
                *(const uint4*)(QKVb + base_k + (size_t)(kb * 128 + rr) * LDQKV + cc);
        }
        // stage V^T: 64 d-rows x 16 chunks = 1024 chunk-loads (linear b128, no scatter)
        #pragma unroll
        for (int it = 0; it < 4; ++it) {
            int s = tid + it * 256;
            int dr = s >> 4, cc = (s & 15) * 8;
            *(uint4*)(Vt + dr * SPV + cc) =
                *(const uint4*)(Vtg + base_v + (size_t)dr * TSEQ + kb * 128 + cc);
        }
        __syncthreads();
        // QK^T: wave's 16 q-rows x 128 keys
        f32x4 s4[8];
        #pragma unroll
        for (int nt = 0; nt < 8; ++nt) {
            s4[nt] = (f32x4)0.f;
            bf16x8 k0f = *(const bf16x8*)(Ks + (nt * 16 + fr) * SPK + fg * 8);
            bf16x8 k1f = *(const bf16x8*)(Ks + (nt * 16 + fr) * SPK + fg * 8 + 32);
            s4[nt] = __builtin_amdgcn_mfma_f32_16x16x32_bf16(qa0, k0f, s4[nt], 0, 0, 0);
            s4[nt] = __builtin_amdgcn_mfma_f32_16x16x32_bf16(qa1, k1f, s4[nt], 0, 0, 0);
        }
        // online softmax (rows = fg*4+rr, cols = fr+16*nt)
        float mx[4];
        #pragma unroll
        for (int rr = 0; rr < 4; ++rr) {
            float a = fmaxf(fmaxf(s4[0][rr], s4[1][rr]), fmaxf(s4[2][rr], s4[3][rr]));
            float c = fmaxf(fmaxf(s4[4][rr], s4[5][rr]), fmaxf(s4[6][rr], s4[7][rr]));
            mx[rr] = fmaxf(a, c) * scale;
        }
        #pragma unroll
        for (int off = 1; off < 16; off <<= 1)
            #pragma unroll
            for (int rr = 0; rr < 4; ++rr)
                mx[rr] = fmaxf(mx[rr], __shfl_xor(mx[rr], off));
        float cf[4], rs[4];
        #pragma unroll
        for (int rr = 0; rr < 4; ++rr) {
            float mnew = fmaxf(m_r[rr], mx[rr]);
            cf[rr] = __expf(m_r[rr] - mnew);
            m_r[rr] = mnew;
            rs[rr] = 0.f;
        }
        #pragma unroll
        for (int nt = 0; nt < 8; ++nt)
            #pragma unroll
            for (int rr = 0; rr < 4; ++rr) {
                float p = __expf(s4[nt][rr] * scale - m_r[rr]);
                s4[nt][rr] = p;
                rs[rr] += p;
            }
        #pragma unroll
        for (int off = 1; off < 16; off <<= 1)
            #pragma unroll
            for (int rr = 0; rr < 4; ++rr)
                rs[rr] += __shfl_xor(rs[rr], off);
        #pragma unroll
        for (int rr = 0; rr < 4; ++rr)
            l_r[rr] = l_r[rr] * cf[rr] + rs[rr];
        #pragma unroll
        for (int dt = 0; dt < 4; ++dt) {
            f32x4 t = o[dt];
            t[0] *= cf[0]; t[1] *= cf[1]; t[2] *= cf[2]; t[3] *= cf[3];
            o[dt] = t;
        }
        __syncthreads();   // all waves' QK^T reads of Ks complete -> safe to overwrite as P
        unsigned short* Ps = Ks;
        #pragma unroll
        for (int nt = 0; nt < 8; ++nt)
            #pragma unroll
            for (int rr = 0; rr < 4; ++rr)
                Ps[(wave * 16 + fg * 4 + rr) * SPP + fr + 16 * nt] = f2bf(s4[nt][rr]);
        // PV (same-wave in-order DS: own P rows only, no barrier needed)
        bf16x8 pa[4];
        #pragma unroll
        for (int kc = 0; kc < 4; ++kc)
            pa[kc] = *(const bf16x8*)(Ps + (wave * 16 + fr) * SPP + kc * 32 + fg * 8);
        #pragma unroll
        for (int dt = 0; dt < 4; ++dt) {
            #pragma unroll
            for (int kc = 0; kc < 4; ++kc) {
                bf16x8 bv = *(const bf16x8*)(Vt + (dt * 16 + fr) * SPV + kc * 32 + fg * 8);
                o[dt] = __builtin_amdgcn_mfma_f32_16x16x32_bf16(pa[kc], bv, o[dt], 0, 0, 0);
            }
        }
    }
    #pragma unroll
    for (int rr = 0; rr < 4; ++rr) {
        float inv = 1.f / l_r[rr];
        int row = q0 + wave * 16 + fg * 4 + rr;
        #pragma unroll
        for (int dt = 0; dt < 4; ++dt)
            At[base_o + (size_t)row * MDIM + fr + 16 * dt] = o[dt][rr] * inv;
    }
}

// ---------------- U + bf16 split: U[bt][e*64+d] = sum_h mask_o * At ----------------
__global__ __launch_bounds__(256)
void compute_U_split(const float* __restrict__ At, const unsigned* __restrict__ sel,
                     unsigned short* __restrict__ Uh, unsigned short* __restrict__ Ul)
{
    int idx = blockIdx.x * 256 + threadIdx.x;    // < MBT*512
    int bt = idx >> 9, ed = idx & 511, e = ed >> 6, d = ed & 63;
    float sum = 0.f;
    const float* a = At + (size_t)bt * MDIM + d;
    const unsigned* sp = sel + bt * 16;
    #pragma unroll
    for (int h = 0; h < NH; ++h)
        if (sp[h] & (1u << (8 + e))) sum += a[h * DHD];
    unsigned short hi = f2bf(sum);
    Uh[idx] = hi;
    Ul[idx] = f2bf(sum - bf2f(hi));
}

extern "C" void kernel_launch(void* const* d_in, const int* in_sizes, int n_in,
                              void* d_out, int out_size, void* d_ws, size_t ws_size,
                              hipStream_t stream)
{
    const float* x  = (const float*)d_in[0];
    const float* Wq = (const float*)d_in[1];
    const float* Wk = (const float*)d_in[2];
    const float* Wv = (const float*)d_in[3];
    const float* Ws = (const float*)d_in[4];
    const float* Wd = (const float*)d_in[5];
    const float* Wo = (const float*)d_in[6];
    float* out = (float*)d_out;
    char* ws = (char*)d_ws;

    // region 0: At (16 MB) aliased earlier as [xb 8MB | Wqkvb 5.25MB] (both dead before attn)
    float*          At    = (float*)(ws);
    unsigned short* xb    = (unsigned short*)(ws);
    unsigned short* Wqkvb = (unsigned short*)(ws + 8388608);
    unsigned short* QKVb  = (unsigned short*)(ws + 16777216);   // 4096x2560 bf16 = 20 MB
    unsigned short* Vtg   = (unsigned short*)(ws + 37748736);   // 8 MB
    float*          Gsd   = (float*)(ws + 46137344);            // 4096x256 f32 = 4 MB
    float*          Wsd   = (float*)(ws + 50331648);            // 256x1024 f32 = 1 MB
    unsigned short* Uh    = (unsigned short*)(ws + 51380224);   // 4 MB
    unsigned short* Ul    = (unsigned short*)(ws + 55574528);   // 4 MB
    unsigned short* WoTh  = (unsigned short*)(ws + 59768832);   // 1 MB
    unsigned short* WoTl  = (unsigned short*)(ws + 60817408);   // 1 MB
    float2*         wvp   = (float2*)(ws + 61865984);           // 512 KB
    unsigned*       selp  = (unsigned*)(ws + 62390272);         // 256 KB

    dim3 blk(256);
    cast_bf16<<<2048, blk, 0, stream>>>(x,  xb, 524288);
    cast_bf16<<<512,  blk, 0, stream>>>(Wq, Wqkvb,           131072);
    cast_bf16<<<512,  blk, 0, stream>>>(Wk, Wqkvb + 1048576, 131072);
    cast_bf16<<<256,  blk, 0, stream>>>(Wv, Wqkvb + 2097152, 65536);
    copy_wsd<<<256, blk, 0, stream>>>(Ws, Wd, Wsd);

    // fused QKV projection: [4096,2560] = xb * Wqkv^T
    mfma_gemm<<<dim3(20, 32), blk, 0, stream>>>(xb, Wqkvb, QKVb, LDQKV, 1024);

    // gates (fp64 accumulation pins top-k ranking), one full-grid GEMM
    gemm_nt<double><<<dim3(4, 64), blk, 0, stream>>>(x, MDIM, Wsd, MDIM, Gsd, 256, MDIM);

    repack_wo_split<<<2048, blk, 0, stream>>>(Wo, WoTh, WoTl);
    gate_topk<<<256, blk, 0, stream>>>(Gsd, wvp, selp);
    vtrans<<<2048, blk, 0, stream>>>(QKVb, wvp, selp, Vtg);

    attn_mfma<<<dim3(TSEQ / 64, NH, NB), blk, 0, stream>>>(QKVb, Vtg, At);

    compute_U_split<<<8192, blk, 0, stream>>>(At, selp, Uh, Ul);
    mfma_gemm3<<<dim3(8, 32), blk, 0, stream>>>(Uh, Ul, WoTh, WoTl, out);
}

// Round 4
// 365.756 us; speedup vs baseline: 4.3122x; 1.2160x over previous
//
#include <hip/hip_runtime.h>
#include <math.h>

#define TSEQ 2048
#define NB   2
#define NH   16
#define NE   8
#define DHD  64
#define MDIM 1024
#define MBT  4096   // NB*TSEQ
#define LDQKV 2560  // Q(1024) | K(1024) | V-experts(512)

typedef __attribute__((ext_vector_type(8))) short bf16x8;
typedef __attribute__((ext_vector_type(4))) float f32x4;
typedef unsigned int u32;

__device__ inline unsigned short f2bf(float f) {
    union { float f; unsigned u; } v; v.f = f;
    unsigned r = v.u + 0x7fff + ((v.u >> 16) & 1);
    return (unsigned short)(r >> 16);
}
__device__ inline float bf2f(unsigned short h) {
    union { unsigned u; float f; } v; v.u = ((unsigned)h) << 16;
    return v.f;
}

// async global->LDS, 16B per lane. dst must be wave-uniform; src is per-lane.
__device__ inline void gload16(const void* g, void* l) {
    __builtin_amdgcn_global_load_lds((const __attribute__((address_space(1))) u32*)g,
                                     (__attribute__((address_space(3))) u32*)l, 16, 0, 0);
}

__device__ inline void cast8(const float* __restrict__ in, unsigned short* __restrict__ out, int i) {
    const float4* p = (const float4*)(in + (size_t)i * 8);
    float4 a = p[0], b = p[1];
    unsigned short o[8] = { f2bf(a.x), f2bf(a.y), f2bf(a.z), f2bf(a.w),
                            f2bf(b.x), f2bf(b.y), f2bf(b.z), f2bf(b.w) };
    *(uint4*)(out + (size_t)i * 8) = *(const uint4*)o;
}

// ---------------- fused prep: casts + Wsd concat + Wo repack/split ----------------
__global__ __launch_bounds__(256)
void prep(const float* __restrict__ x,  const float* __restrict__ Wq,
          const float* __restrict__ Wk, const float* __restrict__ Wv,
          const float* __restrict__ Ws, const float* __restrict__ Wd,
          const float* __restrict__ Wo,
          unsigned short* __restrict__ xb, unsigned short* __restrict__ Wqkvb,
          float* __restrict__ Wsd,
          unsigned short* __restrict__ WoTh, unsigned short* __restrict__ WoTl)
{
    int b = blockIdx.x, tid = threadIdx.x;
    if (b < 2048)      cast8(x,  xb,                (b        ) * 256 + tid);
    else if (b < 2560) cast8(Wq, Wqkvb,             (b - 2048) * 256 + tid);
    else if (b < 3072) cast8(Wk, Wqkvb + 1048576,   (b - 2560) * 256 + tid);
    else if (b < 3328) cast8(Wv, Wqkvb + 2097152,   (b - 3072) * 256 + tid);
    else if (b < 3584) {
        int i = (b - 3328) * 256 + tid;   // < 65536 float4
        const float4* s = (i < 32768) ? (const float4*)Ws + i : (const float4*)Wd + (i - 32768);
        ((float4*)Wsd)[i] = *s;
    } else {
        int idx = (b - 3584) * 256 + tid;  // < 524288
        int f = idx >> 9, ed = idx & 511, e = ed >> 6, d = ed & 63;
        float v = Wo[(size_t)e * (MDIM * DHD) + (size_t)f * DHD + d];
        unsigned short hi = f2bf(v);
        WoTh[idx] = hi;
        WoTl[idx] = f2bf(v - bf2f(hi));
    }
}

// ---------------- bf16 MFMA GEMM (global_load_lds staging): C[M,N]=A*B^T, bf16 out ----------------
__global__ __launch_bounds__(256)
void mfma_gemm(const unsigned short* __restrict__ A,
               const unsigned short* __restrict__ B,
               unsigned short* __restrict__ C, int N, int K)
{
    __shared__ __align__(16) unsigned short As[128 * 32];
    __shared__ __align__(16) unsigned short Bs[128 * 32];
    const int tid = threadIdx.x;
    const int lane = tid & 63, wave = tid >> 6;
    const int m0 = blockIdx.y * 128, n0 = blockIdx.x * 128;
    const int wm = (wave >> 1) * 64, wn = (wave & 1) * 64;
    const int fr = lane & 15, fg = lane >> 4;
    const int grow = lane >> 2, gcol = (lane & 3) * 8;

    f32x4 acc[4][4];
    #pragma unroll
    for (int i = 0; i < 4; ++i)
        #pragma unroll
        for (int j = 0; j < 4; ++j) acc[i][j] = (f32x4)0.f;

    for (int k0 = 0; k0 < K; k0 += 32) {
        __syncthreads();
        const unsigned short* gA = A + (size_t)(m0 + wave * 32 + grow) * K + k0 + gcol;
        gload16(gA,                 As + wave * 1024);
        gload16(gA + (size_t)16 * K, As + wave * 1024 + 512);
        const unsigned short* gB = B + (size_t)(n0 + wave * 32 + grow) * K + k0 + gcol;
        gload16(gB,                 Bs + wave * 1024);
        gload16(gB + (size_t)16 * K, Bs + wave * 1024 + 512);
        __syncthreads();
        bf16x8 af[4], bfr[4];
        #pragma unroll
        for (int t = 0; t < 4; ++t) {
            af[t]  = *(const bf16x8*)(As + (wm + t * 16 + fr) * 32 + fg * 8);
            bfr[t] = *(const bf16x8*)(Bs + (wn + t * 16 + fr) * 32 + fg * 8);
        }
        #pragma unroll
        for (int i = 0; i < 4; ++i)
            #pragma unroll
            for (int j = 0; j < 4; ++j)
                acc[i][j] = __builtin_amdgcn_mfma_f32_16x16x32_bf16(af[i], bfr[j], acc[i][j], 0, 0, 0);
    }
    #pragma unroll
    for (int i = 0; i < 4; ++i)
        #pragma unroll
        for (int j = 0; j < 4; ++j)
            #pragma unroll
            for (int rr = 0; rr < 4; ++rr) {
                int row = m0 + wm + i * 16 + fg * 4 + rr;
                int col = n0 + wn + j * 16 + fr;
                C[(size_t)row * N + col] = f2bf(acc[i][j][rr]);
            }
}

// ---------------- split-bf16 3-pass MFMA GEMM, fp32 out (final projection) ----------------
__global__ __launch_bounds__(256)
void mfma_gemm3(const unsigned short* __restrict__ Ah, const unsigned short* __restrict__ Al,
                const unsigned short* __restrict__ Bh, const unsigned short* __restrict__ Bl,
                float* __restrict__ C)
{
    const int Kc = 512, N = 1024;
    __shared__ __align__(16) unsigned short Ash[128 * 32];
    __shared__ __align__(16) unsigned short Asl[128 * 32];
    __shared__ __align__(16) unsigned short Bsh[128 * 32];
    __shared__ __align__(16) unsigned short Bsl[128 * 32];
    const int tid = threadIdx.x;
    const int lane = tid & 63, wave = tid >> 6;
    const int m0 = blockIdx.y * 128, n0 = blockIdx.x * 128;
    const int wm = (wave >> 1) * 64, wn = (wave & 1) * 64;
    const int fr = lane & 15, fg = lane >> 4;
    const int grow = lane >> 2, gcol = (lane & 3) * 8;

    f32x4 acc[4][4];
    #pragma unroll
    for (int i = 0; i < 4; ++i)
        #pragma unroll
        for (int j = 0; j < 4; ++j) acc[i][j] = (f32x4)0.f;

    for (int k0 = 0; k0 < Kc; k0 += 32) {
        __syncthreads();
        const size_t roff = (size_t)(m0 + wave * 32 + grow) * Kc + k0 + gcol;
        const size_t roffB = (size_t)(n0 + wave * 32 + grow) * Kc + k0 + gcol;
        gload16(Ah + roff,             Ash + wave * 1024);
        gload16(Ah + roff + 16 * Kc,   Ash + wave * 1024 + 512);
        gload16(Al + roff,             Asl + wave * 1024);
        gload16(Al + roff + 16 * Kc,   Asl + wave * 1024 + 512);
        gload16(Bh + roffB,            Bsh + wave * 1024);
        gload16(Bh + roffB + 16 * Kc,  Bsh + wave * 1024 + 512);
        gload16(Bl + roffB,            Bsl + wave * 1024);
        gload16(Bl + roffB + 16 * Kc,  Bsl + wave * 1024 + 512);
        __syncthreads();
        bf16x8 ah[4], al[4], bh[4], bl[4];
        #pragma unroll
        for (int t = 0; t < 4; ++t) {
            ah[t] = *(const bf16x8*)(Ash + (wm + t * 16 + fr) * 32 + fg * 8);
            al[t] = *(const bf16x8*)(Asl + (wm + t * 16 + fr) * 32 + fg * 8);
            bh[t] = *(const bf16x8*)(Bsh + (wn + t * 16 + fr) * 32 + fg * 8);
            bl[t] = *(const bf16x8*)(Bsl + (wn + t * 16 + fr) * 32 + fg * 8);
        }
        #pragma unroll
        for (int i = 0; i < 4; ++i)
            #pragma unroll
            for (int j = 0; j < 4; ++j) {
                acc[i][j] = __builtin_amdgcn_mfma_f32_16x16x32_bf16(ah[i], bh[j], acc[i][j], 0, 0, 0);
                acc[i][j] = __builtin_amdgcn_mfma_f32_16x16x32_bf16(ah[i], bl[j], acc[i][j], 0, 0, 0);
                acc[i][j] = __builtin_amdgcn_mfma_f32_16x16x32_bf16(al[i], bh[j], acc[i][j], 0, 0, 0);
            }
    }
    #pragma unroll
    for (int i = 0; i < 4; ++i)
        #pragma unroll
        for (int j = 0; j < 4; ++j)
            #pragma unroll
            for (int rr = 0; rr < 4; ++rr) {
                int row = m0 + wm + i * 16 + fg * 4 + rr;
                int col = n0 + wn + j * 16 + fr;
                C[(size_t)row * N + col] = acc[i][j][rr];
            }
}

// ---------------- gates: fp64-accum GEMM, split-K=2 ----------------
__global__ __launch_bounds__(256)
void gemm_gate_sk(const float* __restrict__ A, const float* __restrict__ B,
                  double* __restrict__ Cp)
{
    __shared__ float As[64][17];
    __shared__ float Bs[64][17];
    const int tid = threadIdx.x;
    const int tx = tid & 15, ty = tid >> 4;
    const int m0 = blockIdx.y * 64, n0 = blockIdx.x * 64;
    const int kz = blockIdx.z;
    const int lr = tid >> 2;
    const int lc = (tid & 3) << 2;
    double acc[4][4] = {};
    for (int k0 = kz * 512; k0 < kz * 512 + 512; k0 += 16) {
        __syncthreads();
        float4 av = *(const float4*)(A + (size_t)(m0 + lr) * MDIM + k0 + lc);
        As[lr][lc] = av.x; As[lr][lc+1] = av.y; As[lr][lc+2] = av.z; As[lr][lc+3] = av.w;
        float4 bv = *(const float4*)(B + (size_t)(n0 + lr) * MDIM + k0 + lc);
        Bs[lr][lc] = bv.x; Bs[lr][lc+1] = bv.y; Bs[lr][lc+2] = bv.z; Bs[lr][lc+3] = bv.w;
        __syncthreads();
        #pragma unroll
        for (int kk = 0; kk < 16; ++kk) {
            float a[4], b[4];
            #pragma unroll
            for (int i = 0; i < 4; ++i) a[i] = As[ty*4+i][kk];
            #pragma unroll
            for (int j = 0; j < 4; ++j) b[j] = Bs[tx*4+j][kk];
            #pragma unroll
            for (int i = 0; i < 4; ++i)
                #pragma unroll
                for (int j = 0; j < 4; ++j)
                    acc[i][j] += (double)a[i] * (double)b[j];
        }
    }
    double* Cz = Cp + (size_t)kz * (MBT * 256);
    #pragma unroll
    for (int i = 0; i < 4; ++i)
        #pragma unroll
        for (int j = 0; j < 4; ++j)
            Cz[(size_t)(m0 + ty*4 + i) * 256 + n0 + tx*4 + j] = acc[i][j];
}

__global__ __launch_bounds__(256)
void gate_reduce(const double* __restrict__ Cp, float* __restrict__ Gsd)
{
    int i = blockIdx.x * 256 + threadIdx.x;   // < 524288 double2
    double2 a = ((const double2*)Cp)[i];
    double2 b = ((const double2*)(Cp + MBT * 256))[i];
    ((float2*)Gsd)[i] = make_float2((float)(a.x + b.x), (float)(a.y + b.y));
}

// ---------------- top-2 gates (V: sigmoid weights, O: mask) ----------------
__global__ __launch_bounds__(256)
void gate_topk(const float* __restrict__ Gsd,
               float2* __restrict__ wv, unsigned* __restrict__ sel)
{
    int item = blockIdx.x * 256 + threadIdx.x;   // < 65536
    int bt = item >> 4, h = item & 15;
    const float* g = Gsd + (size_t)bt * 256 + h * NE;
    float b1 = -1e30f, b2 = -1e30f; int e1 = 0, e2 = 0;
    #pragma unroll
    for (int e = 0; e < NE; ++e) {
        float v = g[e];
        if (v > b1)      { b2 = b1; e2 = e1; b1 = v; e1 = e; }
        else if (v > b2) { b2 = v;  e2 = e; }
    }
    float w1 = 1.f / (1.f + __expf(-b1));
    float w2 = 1.f / (1.f + __expf(-b2));
    wv[item] = make_float2(w1, w2);
    const float* go = g + 128;
    float o1 = -1e30f, o2 = -1e30f; int f1 = 0, f2 = 0;
    #pragma unroll
    for (int e = 0; e < NE; ++e) {
        float v = go[e];
        if (v > o1)      { o2 = o1; f2 = f1; o1 = v; f1 = e; }
        else if (v > o2) { o2 = v;  f2 = e; }
    }
    unsigned mask = (1u << f1) | (1u << f2);
    sel[item] = (unsigned)e1 | ((unsigned)e2 << 4) | (mask << 8);
}

// ---------------- V mix + transpose: Vtg[b][h][d][t] ----------------
__global__ __launch_bounds__(256)
void vtrans(const unsigned short* __restrict__ QKVb, const float2* __restrict__ wv,
            const unsigned* __restrict__ sel, unsigned short* __restrict__ Vtg)
{
    int idx = blockIdx.x * 256 + threadIdx.x;    // < 524288
    int tc = idx & 255;
    int d  = (idx >> 8) & 63;
    int h  = (idx >> 14) & 15;
    int b  = idx >> 18;
    unsigned short o[8];
    #pragma unroll
    for (int j = 0; j < 8; ++j) {
        int bt = b * TSEQ + tc * 8 + j;
        unsigned s = sel[bt * 16 + h];
        float2 w = wv[bt * 16 + h];
        int e1 = s & 15, e2 = (s >> 4) & 15;
        const unsigned short* pv = QKVb + (size_t)bt * LDQKV + 2048;
        float v = w.x * bf2f(pv[e1 * 64 + d]) + w.y * bf2f(pv[e2 * 64 + d]);
        o[j] = f2bf(v);
    }
    *(uint4*)(Vtg + ((size_t)((b * NH + h) * DHD + d)) * TSEQ + tc * 8) = *(const uint4*)o;
}

// ---------------- MFMA flash attention: 64 q-rows, 64-key tiles, async staged ----------------
#define SPK 72   // LDS row stride (bf16 elems) = 144B
__global__ __launch_bounds__(256)
void attn_mfma(const unsigned short* __restrict__ QKVb,
               const unsigned short* __restrict__ Vtg,
               float* __restrict__ At)
{
    __shared__ __align__(16) unsigned short Ks[64 * SPK];
    __shared__ __align__(16) unsigned short Vt[64 * SPK];   // V^T: rows=d, cols=key
    __shared__ __align__(16) unsigned short Ps[64 * SPK];
    const int tid = threadIdx.x;
    const int lane = tid & 63, wave = tid >> 6;
    const int fr = lane & 15, fg = lane >> 4;
    const int q0 = blockIdx.x * 64;
    const int h = blockIdx.y, b = blockIdx.z;
    const size_t base_q = ((size_t)b * TSEQ) * LDQKV + h * DHD;
    const size_t base_k = base_q + 1024;
    const size_t base_v = ((size_t)(b * NH + h) * DHD) * TSEQ;
    const size_t base_o = ((size_t)b * TSEQ) * MDIM + h * DHD;

    // Q fragments straight from global (one-time, 16B/lane)
    const int qrow = q0 + wave * 16 + fr;
    bf16x8 qa0 = *(const bf16x8*)(QKVb + base_q + (size_t)qrow * LDQKV + fg * 8);
    bf16x8 qa1 = *(const bf16x8*)(QKVb + base_q + (size_t)qrow * LDQKV + fg * 8 + 32);

    float m_r[4], l_r[4];
    f32x4 o[4];
    #pragma unroll
    for (int i = 0; i < 4; ++i) { m_r[i] = -1e30f; l_r[i] = 0.f; o[i] = (f32x4)0.f; }
    const float scale = 0.125f;

    // async staging registers (tile 0 prefetch)
    const int srow = tid >> 2;            // 0..63
    const int scol = (tid & 3) * 8;       // elems; chunks at scol and scol+32
    uint4 kr0, kr1, vr0, vr1;
    kr0 = *(const uint4*)(QKVb + base_k + (size_t)srow * LDQKV + scol);
    kr1 = *(const uint4*)(QKVb + base_k + (size_t)srow * LDQKV + scol + 32);
    vr0 = *(const uint4*)(Vtg + base_v + (size_t)srow * TSEQ + scol);
    vr1 = *(const uint4*)(Vtg + base_v + (size_t)srow * TSEQ + scol + 32);

    const int NT = TSEQ / 64;
    for (int kb = 0; kb < NT; ++kb) {
        __syncthreads();   // all waves done reading Ks/Vt of prev tile
        *(uint4*)(Ks + srow * SPK + scol)      = kr0;
        *(uint4*)(Ks + srow * SPK + scol + 32) = kr1;
        *(uint4*)(Vt + srow * SPK + scol)      = vr0;
        *(uint4*)(Vt + srow * SPK + scol + 32) = vr1;
        __syncthreads();
        if (kb + 1 < NT) {  // prefetch next tile; completes under compute below
            const size_t gk = base_k + (size_t)((kb + 1) * 64 + srow) * LDQKV + scol;
            const size_t gv = base_v + (size_t)srow * TSEQ + (kb + 1) * 64 + scol;
            kr0 = *(const uint4*)(QKVb + gk);
            kr1 = *(const uint4*)(QKVb + gk + 32);
            vr0 = *(const uint4*)(Vtg + gv);
            vr1 = *(const uint4*)(Vtg + gv + 32);
        }
        // QK^T: wave's 16 q-rows x 64 keys
        f32x4 s4[4];
        #pragma unroll
        for (int nt = 0; nt < 4; ++nt) {
            s4[nt] = (f32x4)0.f;
            bf16x8 k0f = *(const bf16x8*)(Ks + (nt * 16 + fr) * SPK + fg * 8);
            bf16x8 k1f = *(const bf16x8*)(Ks + (nt * 16 + fr) * SPK + fg * 8 + 32);
            s4[nt] = __builtin_amdgcn_mfma_f32_16x16x32_bf16(qa0, k0f, s4[nt], 0, 0, 0);
            s4[nt] = __builtin_amdgcn_mfma_f32_16x16x32_bf16(qa1, k1f, s4[nt], 0, 0, 0);
        }
        // online softmax (rows = fg*4+rr, cols = fr+16*nt)
        float mx[4];
        #pragma unroll
        for (int rr = 0; rr < 4; ++rr)
            mx[rr] = fmaxf(fmaxf(s4[0][rr], s4[1][rr]), fmaxf(s4[2][rr], s4[3][rr])) * scale;
        #pragma unroll
        for (int off = 1; off < 16; off <<= 1)
            #pragma unroll
            for (int rr = 0; rr < 4; ++rr)
                mx[rr] = fmaxf(mx[rr], __shfl_xor(mx[rr], off));
        float cf[4], rs[4];
        #pragma unroll
        for (int rr = 0; rr < 4; ++rr) {
            float mnew = fmaxf(m_r[rr], mx[rr]);
            cf[rr] = __expf(m_r[rr] - mnew);
            m_r[rr] = mnew;
            rs[rr] = 0.f;
        }
        #pragma unroll
        for (int nt = 0; nt < 4; ++nt)
            #pragma unroll
            for (int rr = 0; rr < 4; ++rr) {
                float p = __expf(s4[nt][rr] * scale - m_r[rr]);
                s4[nt][rr] = p;
                rs[rr] += p;
            }
        #pragma unroll
        for (int off = 1; off < 16; off <<= 1)
            #pragma unroll
            for (int rr = 0; rr < 4; ++rr)
                rs[rr] += __shfl_xor(rs[rr], off);
        #pragma unroll
        for (int rr = 0; rr < 4; ++rr)
            l_r[rr] = l_r[rr] * cf[rr] + rs[rr];
        #pragma unroll
        for (int dt = 0; dt < 4; ++dt) {
            f32x4 t = o[dt];
            t[0] *= cf[0]; t[1] *= cf[1]; t[2] *= cf[2]; t[3] *= cf[3];
            o[dt] = t;
        }
        // P (bf16) to own-wave region; same-wave in-order DS -> no barrier
        #pragma unroll
        for (int nt = 0; nt < 4; ++nt)
            #pragma unroll
            for (int rr = 0; rr < 4; ++rr)
                Ps[(wave * 16 + fg * 4 + rr) * SPK + fr + 16 * nt] = f2bf(s4[nt][rr]);
        bf16x8 pa0 = *(const bf16x8*)(Ps + (wave * 16 + fr) * SPK + fg * 8);
        bf16x8 pa1 = *(const bf16x8*)(Ps + (wave * 16 + fr) * SPK + fg * 8 + 32);
        #pragma unroll
        for (int dt = 0; dt < 4; ++dt) {
            bf16x8 b0 = *(const bf16x8*)(Vt + (dt * 16 + fr) * SPK + fg * 8);
            bf16x8 b1 = *(const bf16x8*)(Vt + (dt * 16 + fr) * SPK + fg * 8 + 32);
            o[dt] = __builtin_amdgcn_mfma_f32_16x16x32_bf16(pa0, b0, o[dt], 0, 0, 0);
            o[dt] = __builtin_amdgcn_mfma_f32_16x16x32_bf16(pa1, b1, o[dt], 0, 0, 0);
        }
    }
    #pragma unroll
    for (int rr = 0; rr < 4; ++rr) {
        float inv = 1.f / l_r[rr];
        int row = q0 + wave * 16 + fg * 4 + rr;
        #pragma unroll
        for (int dt = 0; dt < 4; ++dt)
            At[base_o + (size_t)row * MDIM + fr + 16 * dt] = o[dt][rr] * inv;
    }
}

// ---------------- U + bf16 split ----------------
__global__ __launch_bounds__(256)
void compute_U_split(const float* __restrict__ At, const unsigned* __restrict__ sel,
                     unsigned short* __restrict__ Uh, unsigned short* __restrict__ Ul)
{
    int idx = blockIdx.x * 256 + threadIdx.x;    // < MBT*512
    int bt = idx >> 9, ed = idx & 511, e = ed >> 6, d = ed & 63;
    float sum = 0.f;
    const float* a = At + (size_t)bt * MDIM + d;
    const unsigned* sp = sel + bt * 16;
    #pragma unroll
    for (int h = 0; h < NH; ++h)
        if (sp[h] & (1u << (8 + e))) sum += a[h * DHD];
    unsigned short hi = f2bf(sum);
    Uh[idx] = hi;
    Ul[idx] = f2bf(sum - bf2f(hi));
}

extern "C" void kernel_launch(void* const* d_in, const int* in_sizes, int n_in,
                              void* d_out, int out_size, void* d_ws, size_t ws_size,
                              hipStream_t stream)
{
    const float* x  = (const float*)d_in[0];
    const float* Wq = (const float*)d_in[1];
    const float* Wk = (const float*)d_in[2];
    const float* Wv = (const float*)d_in[3];
    const float* Ws = (const float*)d_in[4];
    const float* Wd = (const float*)d_in[5];
    const float* Wo = (const float*)d_in[6];
    float* out = (float*)d_out;
    char* ws = (char*)d_ws;

    // region 0 (16.78 MB), time-multiplexed: [xb|Wqkvb] -> Gpart(f64) -> At(f32)
    unsigned short* xb    = (unsigned short*)(ws);              // 8.39 MB
    unsigned short* Wqkvb = (unsigned short*)(ws + 8388608);    // 5.24 MB
    double*         Gpart = (double*)(ws);                      // 2 x 8.39 MB
    float*          At    = (float*)(ws);                       // 16.78 MB
    unsigned short* QKVb  = (unsigned short*)(ws + 16777216);   // 20.97 MB
    unsigned short* Vtg   = (unsigned short*)(ws + 37748736);   // 8.39 MB
    float*          Gsd   = (float*)(ws + 46137344);            // 4.19 MB
    float*          Wsd   = (float*)(ws + 50331648);            // 1.05 MB
    unsigned short* Uh    = (unsigned short*)(ws + 51380224);   // 4.19 MB
    unsigned short* Ul    = (unsigned short*)(ws + 55574528);   // 4.19 MB
    unsigned short* WoTh  = (unsigned short*)(ws + 59768832);   // 1.05 MB
    unsigned short* WoTl  = (unsigned short*)(ws + 60817408);   // 1.05 MB
    float2*         wvp   = (float2*)(ws + 61865984);           // 0.52 MB
    unsigned*       selp  = (unsigned*)(ws + 62390272);         // 0.26 MB

    dim3 blk(256);
    prep<<<5632, blk, 0, stream>>>(x, Wq, Wk, Wv, Ws, Wd, Wo, xb, Wqkvb, Wsd, WoTh, WoTl);

    // fused QKV projection: [4096,2560] = xb * Wqkv^T  (consumes xb/Wqkvb)
    mfma_gemm<<<dim3(20, 32), blk, 0, stream>>>(xb, Wqkvb, QKVb, LDQKV, 1024);

    // gates: fp64 accumulation, split-K=2 (overwrites xb/Wqkvb region — now dead)
    gemm_gate_sk<<<dim3(4, 64, 2), blk, 0, stream>>>(x, Wsd, Gpart);
    gate_reduce<<<2048, blk, 0, stream>>>(Gpart, Gsd);

    gate_topk<<<256, blk, 0, stream>>>(Gsd, wvp, selp);
    vtrans<<<2048, blk, 0, stream>>>(QKVb, wvp, selp, Vtg);

    attn_mfma<<<dim3(TSEQ / 64, NH, NB), blk, 0, stream>>>(QKVb, Vtg, At);

    compute_U_split<<<8192, blk, 0, stream>>>(At, selp, Uh, Ul);
    mfma_gemm3<<<dim3(8, 32), blk, 0, stream>>>(Uh, Ul, WoTh, WoTl, out);
}

// Round 5
// 305.029 us; speedup vs baseline: 5.1707x; 1.1991x over previous
//
#include <hip/hip_runtime.h>
#include <math.h>

#define TSEQ 2048
#define NB   2
#define NH   16
#define NE   8
#define DHD  64
#define MDIM 1024
#define MBT  4096   // NB*TSEQ
#define LDQKV 2560  // Q(1024) | K(1024) | V-experts(512)

typedef __attribute__((ext_vector_type(8))) short bf16x8;
typedef __attribute__((ext_vector_type(4))) float f32x4;
typedef __attribute__((ext_vector_type(16))) float f32x16;
typedef unsigned int u32;

__device__ inline unsigned short f2bf(float f) {
    union { float f; unsigned u; } v; v.f = f;
    unsigned r = v.u + 0x7fff + ((v.u >> 16) & 1);
    return (unsigned short)(r >> 16);
}
__device__ inline float bf2f(unsigned short h) {
    union { unsigned u; float f; } v; v.u = ((unsigned)h) << 16;
    return v.f;
}
__device__ inline u32 cvtpk(float a, float b) {   // low16=bf16(a), high16=bf16(b)
    u32 r;
    asm("v_cvt_pk_bf16_f32 %0, %1, %2" : "=v"(r) : "v"(a), "v"(b));
    return r;
}

// async global->LDS, 16B per lane (dst wave-uniform base + lane*16)
__device__ inline void gload16(const void* g, void* l) {
    __builtin_amdgcn_global_load_lds((const __attribute__((address_space(1))) u32*)g,
                                     (__attribute__((address_space(3))) u32*)l, 16, 0, 0);
}

__device__ inline void cast8s(const float* __restrict__ in, unsigned short* __restrict__ out,
                              int i, float sc) {
    const float4* p = (const float4*)(in + (size_t)i * 8);
    float4 a = p[0], b = p[1];
    unsigned short o[8] = { f2bf(a.x*sc), f2bf(a.y*sc), f2bf(a.z*sc), f2bf(a.w*sc),
                            f2bf(b.x*sc), f2bf(b.y*sc), f2bf(b.z*sc), f2bf(b.w*sc) };
    *(uint4*)(out + (size_t)i * 8) = *(const uint4*)o;
}

// ---------------- fused prep: casts (Wq pre-scaled) + Wsd concat + Wo repack/split ----------------
__global__ __launch_bounds__(256)
void prep(const float* __restrict__ x,  const float* __restrict__ Wq,
          const float* __restrict__ Wk, const float* __restrict__ Wv,
          const float* __restrict__ Ws, const float* __restrict__ Wd,
          const float* __restrict__ Wo,
          unsigned short* __restrict__ xb, unsigned short* __restrict__ Wqkvb,
          float* __restrict__ Wsd,
          unsigned short* __restrict__ WoTh, unsigned short* __restrict__ WoTl)
{
    const float qsc = 0.125f * 1.4426950408889634f;  // fold scale*log2(e) into Q
    int b = blockIdx.x, tid = threadIdx.x;
    if (b < 2048)      cast8s(x,  xb,                (b        ) * 256 + tid, 1.f);
    else if (b < 2560) cast8s(Wq, Wqkvb,             (b - 2048) * 256 + tid, qsc);
    else if (b < 3072) cast8s(Wk, Wqkvb + 1048576,   (b - 2560) * 256 + tid, 1.f);
    else if (b < 3328) cast8s(Wv, Wqkvb + 2097152,   (b - 3072) * 256 + tid, 1.f);
    else if (b < 3584) {
        int i = (b - 3328) * 256 + tid;   // < 65536 float4
        const float4* s = (i < 32768) ? (const float4*)Ws + i : (const float4*)Wd + (i - 32768);
        ((float4*)Wsd)[i] = *s;
    } else {
        int idx = (b - 3584) * 256 + tid;  // < 524288
        int f = idx >> 9, ed = idx & 511, e = ed >> 6, d = ed & 63;
        float v = Wo[(size_t)e * (MDIM * DHD) + (size_t)f * DHD + d];
        unsigned short hi = f2bf(v);
        WoTh[idx] = hi;
        WoTl[idx] = f2bf(v - bf2f(hi));
    }
}

// ---------------- bf16 MFMA GEMM (global_load_lds staging): C[M,N]=A*B^T, bf16 out ----------------
__global__ __launch_bounds__(256)
void mfma_gemm(const unsigned short* __restrict__ A,
               const unsigned short* __restrict__ B,
               unsigned short* __restrict__ C, int N, int K)
{
    __shared__ __align__(16) unsigned short As[128 * 32];
    __shared__ __align__(16) unsigned short Bs[128 * 32];
    const int tid = threadIdx.x;
    const int lane = tid & 63, wave = tid >> 6;
    const int m0 = blockIdx.y * 128, n0 = blockIdx.x * 128;
    const int wm = (wave >> 1) * 64, wn = (wave & 1) * 64;
    const int fr = lane & 15, fg = lane >> 4;
    const int grow = lane >> 2, gcol = (lane & 3) * 8;

    f32x4 acc[4][4];
    #pragma unroll
    for (int i = 0; i < 4; ++i)
        #pragma unroll
        for (int j = 0; j < 4; ++j) acc[i][j] = (f32x4)0.f;

    for (int k0 = 0; k0 < K; k0 += 32) {
        __syncthreads();
        const unsigned short* gA = A + (size_t)(m0 + wave * 32 + grow) * K + k0 + gcol;
        gload16(gA,                 As + wave * 1024);
        gload16(gA + (size_t)16 * K, As + wave * 1024 + 512);
        const unsigned short* gB = B + (size_t)(n0 + wave * 32 + grow) * K + k0 + gcol;
        gload16(gB,                 Bs + wave * 1024);
        gload16(gB + (size_t)16 * K, Bs + wave * 1024 + 512);
        __syncthreads();
        bf16x8 af[4], bfr[4];
        #pragma unroll
        for (int t = 0; t < 4; ++t) {
            af[t]  = *(const bf16x8*)(As + (wm + t * 16 + fr) * 32 + fg * 8);
            bfr[t] = *(const bf16x8*)(Bs + (wn + t * 16 + fr) * 32 + fg * 8);
        }
        #pragma unroll
        for (int i = 0; i < 4; ++i)
            #pragma unroll
            for (int j = 0; j < 4; ++j)
                acc[i][j] = __builtin_amdgcn_mfma_f32_16x16x32_bf16(af[i], bfr[j], acc[i][j], 0, 0, 0);
    }
    #pragma unroll
    for (int i = 0; i < 4; ++i)
        #pragma unroll
        for (int j = 0; j < 4; ++j)
            #pragma unroll
            for (int rr = 0; rr < 4; ++rr) {
                int row = m0 + wm + i * 16 + fg * 4 + rr;
                int col = n0 + wn + j * 16 + fr;
                C[(size_t)row * N + col] = f2bf(acc[i][j][rr]);
            }
}

// ---------------- split-bf16 3-pass MFMA GEMM, fp32 out (final projection) ----------------
__global__ __launch_bounds__(256)
void mfma_gemm3(const unsigned short* __restrict__ Ah, const unsigned short* __restrict__ Al,
                const unsigned short* __restrict__ Bh, const unsigned short* __restrict__ Bl,
                float* __restrict__ C)
{
    const int Kc = 512, N = 1024;
    __shared__ __align__(16) unsigned short Ash[128 * 32];
    __shared__ __align__(16) unsigned short Asl[128 * 32];
    __shared__ __align__(16) unsigned short Bsh[128 * 32];
    __shared__ __align__(16) unsigned short Bsl[128 * 32];
    const int tid = threadIdx.x;
    const int lane = tid & 63, wave = tid >> 6;
    const int m0 = blockIdx.y * 128, n0 = blockIdx.x * 128;
    const int wm = (wave >> 1) * 64, wn = (wave & 1) * 64;
    const int fr = lane & 15, fg = lane >> 4;
    const int grow = lane >> 2, gcol = (lane & 3) * 8;

    f32x4 acc[4][4];
    #pragma unroll
    for (int i = 0; i < 4; ++i)
        #pragma unroll
        for (int j = 0; j < 4; ++j) acc[i][j] = (f32x4)0.f;

    for (int k0 = 0; k0 < Kc; k0 += 32) {
        __syncthreads();
        const size_t roff  = (size_t)(m0 + wave * 32 + grow) * Kc + k0 + gcol;
        const size_t roffB = (size_t)(n0 + wave * 32 + grow) * Kc + k0 + gcol;
        gload16(Ah + roff,             Ash + wave * 1024);
        gload16(Ah + roff + 16 * Kc,   Ash + wave * 1024 + 512);
        gload16(Al + roff,             Asl + wave * 1024);
        gload16(Al + roff + 16 * Kc,   Asl + wave * 1024 + 512);
        gload16(Bh + roffB,            Bsh + wave * 1024);
        gload16(Bh + roffB + 16 * Kc,  Bsh + wave * 1024 + 512);
        gload16(Bl + roffB,            Bsl + wave * 1024);
        gload16(Bl + roffB + 16 * Kc,  Bsl + wave * 1024 + 512);
        __syncthreads();
        bf16x8 ah[4], al[4], bh[4], bl[4];
        #pragma unroll
        for (int t = 0; t < 4; ++t) {
            ah[t] = *(const bf16x8*)(Ash + (wm + t * 16 + fr) * 32 + fg * 8);
            al[t] = *(const bf16x8*)(Asl + (wm + t * 16 + fr) * 32 + fg * 8);
            bh[t] = *(const bf16x8*)(Bsh + (wn + t * 16 + fr) * 32 + fg * 8);
            bl[t] = *(const bf16x8*)(Bsl + (wn + t * 16 + fr) * 32 + fg * 8);
        }
        #pragma unroll
        for (int i = 0; i < 4; ++i)
            #pragma unroll
            for (int j = 0; j < 4; ++j) {
                acc[i][j] = __builtin_amdgcn_mfma_f32_16x16x32_bf16(ah[i], bh[j], acc[i][j], 0, 0, 0);
                acc[i][j] = __builtin_amdgcn_mfma_f32_16x16x32_bf16(ah[i], bl[j], acc[i][j], 0, 0, 0);
                acc[i][j] = __builtin_amdgcn_mfma_f32_16x16x32_bf16(al[i], bh[j], acc[i][j], 0, 0, 0);
            }
    }
    #pragma unroll
    for (int i = 0; i < 4; ++i)
        #pragma unroll
        for (int j = 0; j < 4; ++j)
            #pragma unroll
            for (int rr = 0; rr < 4; ++rr) {
                int row = m0 + wm + i * 16 + fg * 4 + rr;
                int col = n0 + wn + j * 16 + fr;
                C[(size_t)row * N + col] = acc[i][j][rr];
            }
}

// ---------------- gates: fp64-accum GEMM, split-K=2 ----------------
__global__ __launch_bounds__(256)
void gemm_gate_sk(const float* __restrict__ A, const float* __restrict__ B,
                  double* __restrict__ Cp)
{
    __shared__ float As[64][17];
    __shared__ float Bs[64][17];
    const int tid = threadIdx.x;
    const int tx = tid & 15, ty = tid >> 4;
    const int m0 = blockIdx.y * 64, n0 = blockIdx.x * 64;
    const int kz = blockIdx.z;
    const int lr = tid >> 2;
    const int lc = (tid & 3) << 2;
    double acc[4][4] = {};
    for (int k0 = kz * 512; k0 < kz * 512 + 512; k0 += 16) {
        __syncthreads();
        float4 av = *(const float4*)(A + (size_t)(m0 + lr) * MDIM + k0 + lc);
        As[lr][lc] = av.x; As[lr][lc+1] = av.y; As[lr][lc+2] = av.z; As[lr][lc+3] = av.w;
        float4 bv = *(const float4*)(B + (size_t)(n0 + lr) * MDIM + k0 + lc);
        Bs[lr][lc] = bv.x; Bs[lr][lc+1] = bv.y; Bs[lr][lc+2] = bv.z; Bs[lr][lc+3] = bv.w;
        __syncthreads();
        #pragma unroll
        for (int kk = 0; kk < 16; ++kk) {
            float a[4], b[4];
            #pragma unroll
            for (int i = 0; i < 4; ++i) a[i] = As[ty*4+i][kk];
            #pragma unroll
            for (int j = 0; j < 4; ++j) b[j] = Bs[tx*4+j][kk];
            #pragma unroll
            for (int i = 0; i < 4; ++i)
                #pragma unroll
                for (int j = 0; j < 4; ++j)
                    acc[i][j] += (double)a[i] * (double)b[j];
        }
    }
    double* Cz = Cp + (size_t)kz * (MBT * 256);
    #pragma unroll
    for (int i = 0; i < 4; ++i)
        #pragma unroll
        for (int j = 0; j < 4; ++j)
            Cz[(size_t)(m0 + ty*4 + i) * 256 + n0 + tx*4 + j] = acc[i][j];
}

// ---------------- top-2 gates (fused split-K reduce + sigmoid/top-k) ----------------
__global__ __launch_bounds__(256)
void gate_topk(const double* __restrict__ Gpart,
               float2* __restrict__ wv, unsigned* __restrict__ sel)
{
    int item = blockIdx.x * 256 + threadIdx.x;   // < 65536
    int bt = item >> 4, h = item & 15;
    const double* g0 = Gpart + (size_t)bt * 256 + h * NE;
    const double* g1 = g0 + (size_t)MBT * 256;
    float b1 = -1e30f, b2 = -1e30f; int e1 = 0, e2 = 0;
    #pragma unroll
    for (int e = 0; e < NE; ++e) {
        float v = (float)(g0[e] + g1[e]);
        if (v > b1)      { b2 = b1; e2 = e1; b1 = v; e1 = e; }
        else if (v > b2) { b2 = v;  e2 = e; }
    }
    float w1 = 1.f / (1.f + __expf(-b1));
    float w2 = 1.f / (1.f + __expf(-b2));
    wv[item] = make_float2(w1, w2);
    float o1 = -1e30f, o2 = -1e30f; int f1 = 0, f2 = 0;
    #pragma unroll
    for (int e = 0; e < NE; ++e) {
        float v = (float)(g0[128 + e] + g1[128 + e]);
        if (v > o1)      { o2 = o1; f2 = f1; o1 = v; f1 = e; }
        else if (v > o2) { o2 = v;  f2 = e; }
    }
    unsigned mask = (1u << f1) | (1u << f2);
    sel[item] = (unsigned)e1 | ((unsigned)e2 << 4) | (mask << 8);
}

// ---------------- V mix + transpose: Vtg[b][h][d][t] ----------------
__global__ __launch_bounds__(256)
void vtrans(const unsigned short* __restrict__ QKVb, const float2* __restrict__ wv,
            const unsigned* __restrict__ sel, unsigned short* __restrict__ Vtg)
{
    int idx = blockIdx.x * 256 + threadIdx.x;    // < 524288
    int tc = idx & 255;
    int d  = (idx >> 8) & 63;
    int h  = (idx >> 14) & 15;
    int b  = idx >> 18;
    unsigned short o[8];
    #pragma unroll
    for (int j = 0; j < 8; ++j) {
        int bt = b * TSEQ + tc * 8 + j;
        unsigned s = sel[bt * 16 + h];
        float2 w = wv[bt * 16 + h];
        int e1 = s & 15, e2 = (s >> 4) & 15;
        const unsigned short* pv = QKVb + (size_t)bt * LDQKV + 2048;
        float v = w.x * bf2f(pv[e1 * 64 + d]) + w.y * bf2f(pv[e2 * 64 + d]);
        o[j] = f2bf(v);
    }
    *(uint4*)(Vtg + ((size_t)((b * NH + h) * DHD + d)) * TSEQ + tc * 8) = *(const uint4*)o;
}

// ---------------- attn: swapped-QK 32x32 MFMA, in-register P, fixed-max softmax ----------------
// block = 4 waves x 32 q-rows = 128 q; 64-key tiles; key-split x2 via blockIdx.z
#define SPA 72   // LDS row stride (bf16) = 144 B
#define MFMA32(A,B,C) __builtin_amdgcn_mfma_f32_32x32x16_bf16(A, B, C, 0, 0, 0)
__global__ __launch_bounds__(256)
void attn_mfma(const unsigned short* __restrict__ QKVb,
               const unsigned short* __restrict__ Vtg,
               float* __restrict__ Op0, float* __restrict__ Op1,
               float* __restrict__ lp)
{
    __shared__ __align__(16) unsigned short Ks[64 * SPA];
    __shared__ __align__(16) unsigned short Vt[64 * SPA];   // V^T: rows=d, cols=key
    const int tid = threadIdx.x;
    const int lane = tid & 63, wq = tid >> 6;
    const int ql = lane & 31;      // q-col / d-col / key-row (per role)
    const int hi = lane >> 5;
    const int q0 = blockIdx.x * 128;
    const int h = blockIdx.y;
    const int b = blockIdx.z >> 1, split = blockIdx.z & 1;
    const size_t base_q = ((size_t)b * TSEQ) * LDQKV + h * DHD;
    const size_t base_k = base_q + 1024;
    const size_t base_v = ((size_t)(b * NH + h) * DHD) * TSEQ;
    const int k00 = split * 1024;

    // Q fragments (B-operand of swapped QK): lane ql = q, d = 16t + 8hi + j
    const int qrow = q0 + wq * 32 + ql;
    bf16x8 qa[4];
    #pragma unroll
    for (int t = 0; t < 4; ++t)
        qa[t] = *(const bf16x8*)(QKVb + base_q + (size_t)qrow * LDQKV + t * 16 + hi * 8);

    f32x16 o0 = (f32x16)0.f, o1 = (f32x16)0.f;   // O[q][d], d-halves
    float l_lane = 0.f;

    // staging (per thread: one 64-elem row chunked)
    const int srow = tid >> 2, scol = (tid & 3) * 8;
    uint4 kr0 = *(const uint4*)(QKVb + base_k + (size_t)(k00 + srow) * LDQKV + scol);
    uint4 kr1 = *(const uint4*)(QKVb + base_k + (size_t)(k00 + srow) * LDQKV + scol + 32);
    uint4 vr0 = *(const uint4*)(Vtg + base_v + (size_t)srow * TSEQ + k00 + scol);
    uint4 vr1 = *(const uint4*)(Vtg + base_v + (size_t)srow * TSEQ + k00 + scol + 32);

    const int NT = 1024 / 64;
    for (int kb = 0; kb < NT; ++kb) {
        __syncthreads();   // prev tile reads done
        *(uint4*)(Ks + srow * SPA + scol)      = kr0;
        *(uint4*)(Ks + srow * SPA + scol + 32) = kr1;
        *(uint4*)(Vt + srow * SPA + scol)      = vr0;
        *(uint4*)(Vt + srow * SPA + scol + 32) = vr1;
        __syncthreads();
        if (kb + 1 < NT) {   // prefetch next tile under compute
            const size_t gk = base_k + (size_t)(k00 + (kb + 1) * 64 + srow) * LDQKV + scol;
            const size_t gv = base_v + (size_t)srow * TSEQ + k00 + (kb + 1) * 64 + scol;
            kr0 = *(const uint4*)(QKVb + gk);
            kr1 = *(const uint4*)(QKVb + gk + 32);
            vr0 = *(const uint4*)(Vtg + gv);
            vr1 = *(const uint4*)(Vtg + gv + 32);
        }
        // QK^T swapped: s[ks] = K_sub(32k x 64d) . Q^T -> S^T[k][q], k lane-local
        f32x16 s0 = (f32x16)0.f, s1 = (f32x16)0.f;
        #pragma unroll
        for (int t = 0; t < 4; ++t) {
            bf16x8 k0 = *(const bf16x8*)(Ks + ql * SPA + t * 16 + hi * 8);
            bf16x8 k1 = *(const bf16x8*)(Ks + (32 + ql) * SPA + t * 16 + hi * 8);
            s0 = MFMA32(k0, qa[t], s0);
            s1 = MFMA32(k1, qa[t], s1);
        }
        float ls = 0.f;
        u32 w[8];
        // ---- ksub 0: exp2 (scale/log2e pre-folded into Q), pack, PV k-steps 0,1 ----
        #pragma unroll
        for (int r = 0; r < 16; ++r) { float p = exp2f(s0[r]); s0[r] = p; ls += p; }
        #pragma unroll
        for (int m = 0; m < 8; ++m) w[m] = cvtpk(s0[2*m], s0[2*m+1]);
        #pragma unroll
        for (int tl = 0; tl < 2; ++tl) {
            const int mb = 4 * tl, tk = tl;
            u32 send0 = hi ? w[mb]   : w[mb+2];
            u32 send1 = hi ? w[mb+1] : w[mb+3];
            u32 r0 = (u32)__shfl_xor((int)send0, 32, 64);
            u32 r1 = (u32)__shfl_xor((int)send1, 32, 64);
            union { u32 uw[4]; bf16x8 v; } pu;
            pu.uw[0] = hi ? r0 : w[mb];
            pu.uw[1] = hi ? r1 : w[mb+1];
            pu.uw[2] = hi ? w[mb+2] : r0;
            pu.uw[3] = hi ? w[mb+3] : r1;
            bf16x8 v0 = *(const bf16x8*)(Vt + ql * SPA + tk * 16 + hi * 8);
            bf16x8 v1 = *(const bf16x8*)(Vt + (32 + ql) * SPA + tk * 16 + hi * 8);
            o0 = MFMA32(pu.v, v0, o0);
            o1 = MFMA32(pu.v, v1, o1);
        }
        // ---- ksub 1: PV k-steps 2,3 ----
        #pragma unroll
        for (int r = 0; r < 16; ++r) { float p = exp2f(s1[r]); s1[r] = p; ls += p; }
        #pragma unroll
        for (int m = 0; m < 8; ++m) w[m] = cvtpk(s1[2*m], s1[2*m+1]);
        #pragma unroll
        for (int tl = 0; tl < 2; ++tl) {
            const int mb = 4 * tl, tk = 2 + tl;
            u32 send0 = hi ? w[mb]   : w[mb+2];
            u32 send1 = hi ? w[mb+1] : w[mb+3];
            u32 r0 = (u32)__shfl_xor((int)send0, 32, 64);
            u32 r1 = (u32)__shfl_xor((int)send1, 32, 64);
            union { u32 uw[4]; bf16x8 v; } pu;
            pu.uw[0] = hi ? r0 : w[mb];
            pu.uw[1] = hi ? r1 : w[mb+1];
            pu.uw[2] = hi ? w[mb+2] : r0;
            pu.uw[3] = hi ? w[mb+3] : r1;
            bf16x8 v0 = *(const bf16x8*)(Vt + ql * SPA + tk * 16 + hi * 8);
            bf16x8 v1 = *(const bf16x8*)(Vt + (32 + ql) * SPA + tk * 16 + hi * 8);
            o0 = MFMA32(pu.v, v0, o0);
            o1 = MFMA32(pu.v, v1, o1);
        }
        l_lane += ls;
    }
    // finalize: combine the two k-halves of l (lane <-> lane+32), store unnormalized O + l
    float l_tot = l_lane + __shfl_xor(l_lane, 32, 64);
    float* Op = split ? Op1 : Op0;
    const size_t ob = ((size_t)b * TSEQ) * MDIM + h * DHD;
    #pragma unroll
    for (int r = 0; r < 16; ++r) {
        int qr = q0 + wq * 32 + (r & 3) + 8 * (r >> 2) + 4 * hi;
        Op[ob + (size_t)qr * MDIM + ql]      = o0[r];
        Op[ob + (size_t)qr * MDIM + 32 + ql] = o1[r];
    }
    if (hi == 0)
        lp[(((size_t)split * NB + b) * NH + h) * TSEQ + q0 + wq * 32 + ql] = l_tot;
}

// ---------------- U: merge splits, normalize, mask-sum over h, bf16 split ----------------
__global__ __launch_bounds__(256)
void compute_U_split(const float* __restrict__ Op0, const float* __restrict__ Op1,
                     const float* __restrict__ lp, const unsigned* __restrict__ sel,
                     unsigned short* __restrict__ Uh, unsigned short* __restrict__ Ul)
{
    int idx = blockIdx.x * 256 + threadIdx.x;    // < MBT*512
    int bt = idx >> 9, ed = idx & 511, e = ed >> 6, d = ed & 63;
    int b = bt >> 11, t = bt & 2047;
    float sum = 0.f;
    const unsigned* sp = sel + bt * 16;
    #pragma unroll
    for (int h = 0; h < NH; ++h)
        if (sp[h] & (1u << (8 + e))) {
            size_t oi = (size_t)bt * MDIM + h * DHD + d;
            float o = Op0[oi] + Op1[oi];
            size_t li = (((size_t)b) * NH + h) * TSEQ + t;
            float l = lp[li] + lp[li + (size_t)NB * NH * TSEQ];
            sum += o / l;
        }
    unsigned short hi16 = f2bf(sum);
    Uh[idx] = hi16;
    Ul[idx] = f2bf(sum - bf2f(hi16));
}

extern "C" void kernel_launch(void* const* d_in, const int* in_sizes, int n_in,
                              void* d_out, int out_size, void* d_ws, size_t ws_size,
                              hipStream_t stream)
{
    const float* x  = (const float*)d_in[0];
    const float* Wq = (const float*)d_in[1];
    const float* Wk = (const float*)d_in[2];
    const float* Wv = (const float*)d_in[3];
    const float* Ws = (const float*)d_in[4];
    const float* Wd = (const float*)d_in[5];
    const float* Wo = (const float*)d_in[6];
    float* out = (float*)d_out;
    char* ws = (char*)d_ws;

    // region 0 (16.78 MB), time-multiplexed: [xb|Wqkvb] -> Gpart(f64) -> Op0(f32)
    unsigned short* xb    = (unsigned short*)(ws);
    unsigned short* Wqkvb = (unsigned short*)(ws + 8388608);
    double*         Gpart = (double*)(ws);                      // 2 x 8.39 MB
    float*          Op0   = (float*)(ws);                       // 16.78 MB
    unsigned short* QKVb  = (unsigned short*)(ws + 16777216);   // 20.97 MB
    unsigned short* Vtg   = (unsigned short*)(ws + 37748736);   // 8.39 MB
    float*          Op1   = (float*)(ws + 46137344);            // 16.78 MB
    float*          lp    = (float*)(ws + 62914560);            // 0.52 MB
    unsigned short* WoTh  = (unsigned short*)(ws + 63438848);   // 1.05 MB
    unsigned short* WoTl  = (unsigned short*)(ws + 64487424);   // 1.05 MB
    unsigned short* Uh    = (unsigned short*)(ws + 65536000);   // 4.19 MB
    unsigned short* Ul    = (unsigned short*)(ws + 69730304);   // 4.19 MB
    float2*         wvp   = (float2*)(ws + 73924608);           // 0.52 MB
    unsigned*       selp  = (unsigned*)(ws + 74448896);         // 0.26 MB
    float*          Wsd   = (float*)(ws + 74711040);            // 1.05 MB

    dim3 blk(256);
    prep<<<5632, blk, 0, stream>>>(x, Wq, Wk, Wv, Ws, Wd, Wo, xb, Wqkvb, Wsd, WoTh, WoTl);

    // fused QKV projection (Q pre-scaled): [4096,2560] = xb * Wqkv^T
    mfma_gemm<<<dim3(20, 32), blk, 0, stream>>>(xb, Wqkvb, QKVb, LDQKV, 1024);

    // gates: fp64 accumulation pins top-k ranking (overwrites dead xb/Wqkvb region)
    gemm_gate_sk<<<dim3(4, 64, 2), blk, 0, stream>>>(x, Wsd, Gpart);
    gate_topk<<<256, blk, 0, stream>>>(Gpart, wvp, selp);
    vtrans<<<2048, blk, 0, stream>>>(QKVb, wvp, selp, Vtg);

    attn_mfma<<<dim3(TSEQ / 128, NH, NB * 2), blk, 0, stream>>>(QKVb, Vtg, Op0, Op1, lp);

    compute_U_split<<<8192, blk, 0, stream>>>(Op0, Op1, lp, selp, Uh, Ul);
    mfma_gemm3<<<dim3(8, 32), blk, 0, stream>>>(Uh, Ul, WoTh, WoTl, out);
}

// Round 6
// 268.195 us; speedup vs baseline: 5.8808x; 1.1373x over previous
//
#include <hip/hip_runtime.h>
#include <math.h>

#define TSEQ 2048
#define NB   2
#define NH   16
#define NE   8
#define DHD  64
#define MDIM 1024
#define MBT  4096   // NB*TSEQ
#define LDQKV 2560  // Q(1024) | K(1024) | V-experts(512)
#define GTAU 1e-3f  // margin threshold for fp64 gate fix-up
#define MAXFLAG 16384

typedef __attribute__((ext_vector_type(8))) short bf16x8;
typedef __attribute__((ext_vector_type(4))) float f32x4;
typedef __attribute__((ext_vector_type(16))) float f32x16;
typedef unsigned int u32;

__device__ inline unsigned short f2bf(float f) {
    union { float f; unsigned u; } v; v.f = f;
    unsigned r = v.u + 0x7fff + ((v.u >> 16) & 1);
    return (unsigned short)(r >> 16);
}
__device__ inline float bf2f(unsigned short h) {
    union { unsigned u; float f; } v; v.u = ((unsigned)h) << 16;
    return v.f;
}
__device__ inline u32 cvtpk(float a, float b) {   // low16=bf16(a), high16=bf16(b)
    u32 r;
    asm("v_cvt_pk_bf16_f32 %0, %1, %2" : "=v"(r) : "v"(a), "v"(b));
    return r;
}

// async global->LDS, 16B per lane (dst wave-uniform base + lane*16)
__device__ inline void gload16(const void* g, void* l) {
    __builtin_amdgcn_global_load_lds((const __attribute__((address_space(1))) u32*)g,
                                     (__attribute__((address_space(3))) u32*)l, 16, 0, 0);
}

__device__ inline void cast8s(const float* __restrict__ in, unsigned short* __restrict__ out,
                              int i, float sc) {
    const float4* p = (const float4*)(in + (size_t)i * 8);
    float4 a = p[0], b = p[1];
    unsigned short o[8] = { f2bf(a.x*sc), f2bf(a.y*sc), f2bf(a.z*sc), f2bf(a.w*sc),
                            f2bf(b.x*sc), f2bf(b.y*sc), f2bf(b.z*sc), f2bf(b.w*sc) };
    *(uint4*)(out + (size_t)i * 8) = *(const uint4*)o;
}
__device__ inline void cast8hl(const float* __restrict__ in,
                               unsigned short* __restrict__ oh, unsigned short* __restrict__ ol,
                               int i) {
    const float4* p = (const float4*)(in + (size_t)i * 8);
    float4 a = p[0], b = p[1];
    float f[8] = { a.x, a.y, a.z, a.w, b.x, b.y, b.z, b.w };
    unsigned short h8[8], l8[8];
    #pragma unroll
    for (int j = 0; j < 8; ++j) {
        unsigned short hi = f2bf(f[j]);
        h8[j] = hi;
        l8[j] = f2bf(f[j] - bf2f(hi));
    }
    *(uint4*)(oh + (size_t)i * 8) = *(const uint4*)h8;
    *(uint4*)(ol + (size_t)i * 8) = *(const uint4*)l8;
}

// ---------------- fused prep ----------------
__global__ __launch_bounds__(256)
void prep(const float* __restrict__ x,  const float* __restrict__ Wq,
          const float* __restrict__ Wk, const float* __restrict__ Wv,
          const float* __restrict__ Ws, const float* __restrict__ Wd,
          const float* __restrict__ Wo,
          unsigned short* __restrict__ xb, unsigned short* __restrict__ xbl,
          unsigned short* __restrict__ Wqkvb,
          unsigned short* __restrict__ Wsdh, unsigned short* __restrict__ Wsdl,
          unsigned short* __restrict__ WoTh, unsigned short* __restrict__ WoTl,
          u32* __restrict__ flags)
{
    const float qsc = 0.125f * 1.4426950408889634f;  // fold scale*log2(e) into Q
    int b = blockIdx.x, tid = threadIdx.x;
    if (b == 0 && tid == 0) flags[0] = 0;
    if (b < 2048)      cast8hl(x, xb, xbl,          (b        ) * 256 + tid);
    else if (b < 2560) cast8s(Wq, Wqkvb,            (b - 2048) * 256 + tid, qsc);
    else if (b < 3072) cast8s(Wk, Wqkvb + 1048576,  (b - 2560) * 256 + tid, 1.f);
    else if (b < 3328) cast8s(Wv, Wqkvb + 2097152,  (b - 3072) * 256 + tid, 1.f);
    else if (b < 3456) {
        int i = (b - 3328) * 256 + tid;   // < 32768; 8 elems each of Ws|Wd
        const float* src = (i < 16384) ? Ws + (size_t)i * 8 : Wd + (size_t)(i - 16384) * 8;
        cast8hl(src, Wsdh + (size_t)(i & 16383) * 8 + (i < 16384 ? 0 : 131072) * 0, Wsdl, 0); // placeholder
    } else {
        int idx = (b - 3456) * 256 + tid;  // < 524288
        int f = idx >> 9, ed = idx & 511, e = ed >> 6, d = ed & 63;
        float v = Wo[(size_t)e * (MDIM * DHD) + (size_t)f * DHD + d];
        unsigned short hi = f2bf(v);
        WoTh[idx] = hi;
        WoTl[idx] = f2bf(v - bf2f(hi));
    }
}

// (real Wsd split — separated to keep addressing simple/correct)
__global__ __launch_bounds__(256)
void prep_wsd(const float* __restrict__ Ws, const float* __restrict__ Wd,
              unsigned short* __restrict__ Wsdh, unsigned short* __restrict__ Wsdl)
{
    int i = blockIdx.x * 256 + threadIdx.x;   // < 32768, 8 elems each
    const float* src = (i < 16384) ? Ws + (size_t)i * 8 : Wd + (size_t)(i - 16384) * 8;
    const float4* p = (const float4*)src;
    float4 a = p[0], bq = p[1];
    float f[8] = { a.x, a.y, a.z, a.w, bq.x, bq.y, bq.z, bq.w };
    unsigned short h8[8], l8[8];
    #pragma unroll
    for (int j = 0; j < 8; ++j) {
        unsigned short hi = f2bf(f[j]);
        h8[j] = hi;
        l8[j] = f2bf(f[j] - bf2f(hi));
    }
    *(uint4*)(Wsdh + (size_t)i * 8) = *(const uint4*)h8;
    *(uint4*)(Wsdl + (size_t)i * 8) = *(const uint4*)l8;
}

// ---------------- bf16 MFMA GEMM (global_load_lds staging): C[M,N]=A*B^T, bf16 out ----------------
__global__ __launch_bounds__(256)
void mfma_gemm(const unsigned short* __restrict__ A,
               const unsigned short* __restrict__ B,
               unsigned short* __restrict__ C, int N, int K)
{
    __shared__ __align__(16) unsigned short As[128 * 32];
    __shared__ __align__(16) unsigned short Bs[128 * 32];
    const int tid = threadIdx.x;
    const int lane = tid & 63, wave = tid >> 6;
    const int m0 = blockIdx.y * 128, n0 = blockIdx.x * 128;
    const int wm = (wave >> 1) * 64, wn = (wave & 1) * 64;
    const int fr = lane & 15, fg = lane >> 4;
    const int grow = lane >> 2, gcol = (lane & 3) * 8;

    f32x4 acc[4][4];
    #pragma unroll
    for (int i = 0; i < 4; ++i)
        #pragma unroll
        for (int j = 0; j < 4; ++j) acc[i][j] = (f32x4)0.f;

    for (int k0 = 0; k0 < K; k0 += 32) {
        __syncthreads();
        const unsigned short* gA = A + (size_t)(m0 + wave * 32 + grow) * K + k0 + gcol;
        gload16(gA,                 As + wave * 1024);
        gload16(gA + (size_t)16 * K, As + wave * 1024 + 512);
        const unsigned short* gB = B + (size_t)(n0 + wave * 32 + grow) * K + k0 + gcol;
        gload16(gB,                 Bs + wave * 1024);
        gload16(gB + (size_t)16 * K, Bs + wave * 1024 + 512);
        __syncthreads();
        bf16x8 af[4], bfr[4];
        #pragma unroll
        for (int t = 0; t < 4; ++t) {
            af[t]  = *(const bf16x8*)(As + (wm + t * 16 + fr) * 32 + fg * 8);
            bfr[t] = *(const bf16x8*)(Bs + (wn + t * 16 + fr) * 32 + fg * 8);
        }
        #pragma unroll
        for (int i = 0; i < 4; ++i)
            #pragma unroll
            for (int j = 0; j < 4; ++j)
                acc[i][j] = __builtin_amdgcn_mfma_f32_16x16x32_bf16(af[i], bfr[j], acc[i][j], 0, 0, 0);
    }
    #pragma unroll
    for (int i = 0; i < 4; ++i)
        #pragma unroll
        for (int j = 0; j < 4; ++j)
            #pragma unroll
            for (int rr = 0; rr < 4; ++rr) {
                int row = m0 + wm + i * 16 + fg * 4 + rr;
                int col = n0 + wn + j * 16 + fr;
                C[(size_t)row * N + col] = f2bf(acc[i][j][rr]);
            }
}

// ---------------- split-bf16 3-pass MFMA GEMM, fp32 out (final projection) ----------------
__global__ __launch_bounds__(256)
void mfma_gemm3(const unsigned short* __restrict__ Ah, const unsigned short* __restrict__ Al,
                const unsigned short* __restrict__ Bh, const unsigned short* __restrict__ Bl,
                float* __restrict__ C)
{
    const int Kc = 512, N = 1024;
    __shared__ __align__(16) unsigned short Ash[128 * 32];
    __shared__ __align__(16) unsigned short Asl[128 * 32];
    __shared__ __align__(16) unsigned short Bsh[128 * 32];
    __shared__ __align__(16) unsigned short Bsl[128 * 32];
    const int tid = threadIdx.x;
    const int lane = tid & 63, wave = tid >> 6;
    const int m0 = blockIdx.y * 128, n0 = blockIdx.x * 128;
    const int wm = (wave >> 1) * 64, wn = (wave & 1) * 64;
    const int fr = lane & 15, fg = lane >> 4;
    const int grow = lane >> 2, gcol = (lane & 3) * 8;

    f32x4 acc[4][4];
    #pragma unroll
    for (int i = 0; i < 4; ++i)
        #pragma unroll
        for (int j = 0; j < 4; ++j) acc[i][j] = (f32x4)0.f;

    for (int k0 = 0; k0 < Kc; k0 += 32) {
        __syncthreads();
        const size_t roff  = (size_t)(m0 + wave * 32 + grow) * Kc + k0 + gcol;
        const size_t roffB = (size_t)(n0 + wave * 32 + grow) * Kc + k0 + gcol;
        gload16(Ah + roff,             Ash + wave * 1024);
        gload16(Ah + roff + 16 * Kc,   Ash + wave * 1024 + 512);
        gload16(Al + roff,             Asl + wave * 1024);
        gload16(Al + roff + 16 * Kc,   Asl + wave * 1024 + 512);
        gload16(Bh + roffB,            Bsh + wave * 1024);
        gload16(Bh + roffB + 16 * Kc,  Bsh + wave * 1024 + 512);
        gload16(Bl + roffB,            Bsl + wave * 1024);
        gload16(Bl + roffB + 16 * Kc,  Bsl + wave * 1024 + 512);
        __syncthreads();
        bf16x8 ah[4], al[4], bh[4], bl[4];
        #pragma unroll
        for (int t = 0; t < 4; ++t) {
            ah[t] = *(const bf16x8*)(Ash + (wm + t * 16 + fr) * 32 + fg * 8);
            al[t] = *(const bf16x8*)(Asl + (wm + t * 16 + fr) * 32 + fg * 8);
            bh[t] = *(const bf16x8*)(Bsh + (wn + t * 16 + fr) * 32 + fg * 8);
            bl[t] = *(const bf16x8*)(Bsl + (wn + t * 16 + fr) * 32 + fg * 8);
        }
        #pragma unroll
        for (int i = 0; i < 4; ++i)
            #pragma unroll
            for (int j = 0; j < 4; ++j) {
                acc[i][j] = __builtin_amdgcn_mfma_f32_16x16x32_bf16(ah[i], bh[j], acc[i][j], 0, 0, 0);
                acc[i][j] = __builtin_amdgcn_mfma_f32_16x16x32_bf16(ah[i], bl[j], acc[i][j], 0, 0, 0);
                acc[i][j] = __builtin_amdgcn_mfma_f32_16x16x32_bf16(al[i], bh[j], acc[i][j], 0, 0, 0);
            }
    }
    #pragma unroll
    for (int i = 0; i < 4; ++i)
        #pragma unroll
        for (int j = 0; j < 4; ++j)
            #pragma unroll
            for (int rr = 0; rr < 4; ++rr) {
                int row = m0 + wm + i * 16 + fg * 4 + rr;
                int col = n0 + wn + j * 16 + fr;
                C[(size_t)row * N + col] = acc[i][j][rr];
            }
}

// ---------------- gate GEMM: split-bf16 3-pass, Gf[4096][256] fp32 ----------------
// tile 64x64, 4 waves of 32x32; grid (4, 64)
__global__ __launch_bounds__(256)
void gate_gemm(const unsigned short* __restrict__ Ah, const unsigned short* __restrict__ Al,
               const unsigned short* __restrict__ Bh, const unsigned short* __restrict__ Bl,
               float* __restrict__ C)
{
    const int K = 1024, N = 256;
    __shared__ __align__(16) unsigned short S[4][64 * 32];
    const int tid = threadIdx.x;
    const int lane = tid & 63, wave = tid >> 6;
    const int m0 = blockIdx.y * 64, n0 = blockIdx.x * 64;
    const int wm = (wave >> 1) * 32, wn = (wave & 1) * 32;
    const int fr = lane & 15, fg = lane >> 4;
    const int grow = lane >> 2, gcol = (lane & 3) * 8;

    const unsigned short* src = (wave == 0) ? Ah : (wave == 1) ? Al : (wave == 2) ? Bh : Bl;
    const int brow = (wave >= 2) ? n0 : m0;

    f32x4 acc[2][2];
    #pragma unroll
    for (int i = 0; i < 2; ++i)
        #pragma unroll
        for (int j = 0; j < 2; ++j) acc[i][j] = (f32x4)0.f;

    for (int k0 = 0; k0 < K; k0 += 32) {
        __syncthreads();
        #pragma unroll
        for (int i = 0; i < 4; ++i)
            gload16(src + (size_t)(brow + i * 16 + grow) * K + k0 + gcol, &S[wave][i * 512]);
        __syncthreads();
        bf16x8 ah[2], al[2], bh[2], bl[2];
        #pragma unroll
        for (int t = 0; t < 2; ++t) {
            ah[t] = *(const bf16x8*)(&S[0][(wm + t * 16 + fr) * 32 + fg * 8]);
            al[t] = *(const bf16x8*)(&S[1][(wm + t * 16 + fr) * 32 + fg * 8]);
            bh[t] = *(const bf16x8*)(&S[2][(wn + t * 16 + fr) * 32 + fg * 8]);
            bl[t] = *(const bf16x8*)(&S[3][(wn + t * 16 + fr) * 32 + fg * 8]);
        }
        #pragma unroll
        for (int i = 0; i < 2; ++i)
            #pragma unroll
            for (int j = 0; j < 2; ++j) {
                acc[i][j] = __builtin_amdgcn_mfma_f32_16x16x32_bf16(ah[i], bh[j], acc[i][j], 0, 0, 0);
                acc[i][j] = __builtin_amdgcn_mfma_f32_16x16x32_bf16(ah[i], bl[j], acc[i][j], 0, 0, 0);
                acc[i][j] = __builtin_amdgcn_mfma_f32_16x16x32_bf16(al[i], bh[j], acc[i][j], 0, 0, 0);
            }
    }
    #pragma unroll
    for (int i = 0; i < 2; ++i)
        #pragma unroll
        for (int j = 0; j < 2; ++j)
            #pragma unroll
            for (int rr = 0; rr < 4; ++rr) {
                int row = m0 + wm + i * 16 + fg * 4 + rr;
                int col = n0 + wn + j * 16 + fr;
                C[(size_t)row * N + col] = acc[i][j][rr];
            }
}

// ---------------- top-2 + margin flagging ----------------
__global__ __launch_bounds__(256)
void gate_topk2(const float* __restrict__ Gf,
                float2* __restrict__ wv, u32* __restrict__ selv, u32* __restrict__ selo,
                u32* __restrict__ flags)
{
    int item = blockIdx.x * 256 + threadIdx.x;   // < 65536
    int bt = item >> 4, h = item & 15;
    const float* g = Gf + (size_t)bt * 256 + h * NE;
    float b1 = -1e30f, b2 = -1e30f, b3 = -1e30f; int e1 = 0, e2 = 0;
    #pragma unroll
    for (int e = 0; e < NE; ++e) {
        float v = g[e];
        if (v > b1)      { b3 = b2; b2 = b1; e2 = e1; b1 = v; e1 = e; }
        else if (v > b2) { b3 = b2; b2 = v;  e2 = e; }
        else if (v > b3) { b3 = v; }
    }
    wv[item] = make_float2(1.f / (1.f + __expf(-b1)), 1.f / (1.f + __expf(-b2)));
    selv[item] = (u32)e1 | ((u32)e2 << 4);
    if (b2 - b3 < GTAU) {
        u32 p = atomicAdd(flags, 1u);
        if (p < MAXFLAG) flags[1 + p] = (u32)item;
    }
    const float* go = g + 128;
    float o1 = -1e30f, o2 = -1e30f, o3 = -1e30f; int f1 = 0, f2 = 0;
    #pragma unroll
    for (int e = 0; e < NE; ++e) {
        float v = go[e];
        if (v > o1)      { o3 = o2; o2 = o1; f2 = f1; o1 = v; f1 = e; }
        else if (v > o2) { o3 = o2; o2 = v;  f2 = e; }
        else if (v > o3) { o3 = v; }
    }
    selo[item] = (1u << f1) | (1u << f2);
    if (o2 - o3 < GTAU) {
        u32 p = atomicAdd(flags, 1u);
        if (p < MAXFLAG) flags[1 + p] = (u32)item | 0x10000u;
    }
}

// ---------------- fp64 fix-up for flagged near-tie items (one wave per record) ----------------
__global__ __launch_bounds__(256)
void gate_fix(const float* __restrict__ x, const float* __restrict__ Ws,
              const float* __restrict__ Wd, const u32* __restrict__ flags,
              float2* __restrict__ wv, u32* __restrict__ selv, u32* __restrict__ selo)
{
    u32 nf = flags[0]; if (nf > MAXFLAG) nf = MAXFLAG;
    int gw = (blockIdx.x * 256 + threadIdx.x) >> 6;
    int lane = threadIdx.x & 63;
    int nwaves = gridDim.x * 4;
    for (u32 w = gw; w < nf; w += nwaves) {
        u32 rec = flags[1 + w];
        int item = rec & 0xffff, which = rec >> 16;
        int bt = item >> 4, h = item & 15;
        const float* W = (which ? Wd : Ws) + (size_t)h * NE * MDIM + lane * 16;
        const float* xr = x + (size_t)bt * MDIM + lane * 16;
        double g[8];
        #pragma unroll
        for (int e = 0; e < 8; ++e) {
            double s = 0.0;
            #pragma unroll
            for (int c = 0; c < 16; ++c)
                s += (double)xr[c] * (double)W[(size_t)e * MDIM + c];
            g[e] = s;
        }
        #pragma unroll
        for (int off = 32; off; off >>= 1)
            #pragma unroll
            for (int e = 0; e < 8; ++e)
                g[e] += __shfl_xor(g[e], off, 64);
        if (lane == 0) {
            double b1 = -1e300, b2 = -1e300; int i1 = 0, i2 = 0;
            #pragma unroll
            for (int e = 0; e < 8; ++e) {
                double v = g[e];
                if (v > b1)      { b2 = b1; i2 = i1; b1 = v; i1 = e; }
                else if (v > b2) { b2 = v;  i2 = e; }
            }
            if (which == 0) {
                wv[item] = make_float2(1.f / (1.f + __expf(-(float)b1)),
                                       1.f / (1.f + __expf(-(float)b2)));
                selv[item] = (u32)i1 | ((u32)i2 << 4);
            } else {
                selo[item] = (1u << i1) | (1u << i2);
            }
        }
    }
}

// ---------------- V mix + transpose: Vtg[b][h][d][t] ----------------
__global__ __launch_bounds__(256)
void vtrans(const unsigned short* __restrict__ QKVb, const float2* __restrict__ wv,
            const u32* __restrict__ selv, unsigned short* __restrict__ Vtg)
{
    int idx = blockIdx.x * 256 + threadIdx.x;    // < 524288
    int tc = idx & 255;
    int d  = (idx >> 8) & 63;
    int h  = (idx >> 14) & 15;
    int b  = idx >> 18;
    unsigned short o[8];
    #pragma unroll
    for (int j = 0; j < 8; ++j) {
        int bt = b * TSEQ + tc * 8 + j;
        u32 s = selv[bt * 16 + h];
        float2 w = wv[bt * 16 + h];
        int e1 = s & 15, e2 = (s >> 4) & 15;
        const unsigned short* pv = QKVb + (size_t)bt * LDQKV + 2048;
        float v = w.x * bf2f(pv[e1 * 64 + d]) + w.y * bf2f(pv[e2 * 64 + d]);
        o[j] = f2bf(v);
    }
    *(uint4*)(Vtg + ((size_t)((b * NH + h) * DHD + d)) * TSEQ + tc * 8) = *(const uint4*)o;
}

// ---------------- attn: swapped-QK 32x32 MFMA, in-register P, fixed-max softmax ----------------
#define SPA 72   // LDS row stride (bf16) = 144 B
#define MFMA32(A,B,C) __builtin_amdgcn_mfma_f32_32x32x16_bf16(A, B, C, 0, 0, 0)
__global__ __launch_bounds__(256)
void attn_mfma(const unsigned short* __restrict__ QKVb,
               const unsigned short* __restrict__ Vtg,
               float* __restrict__ Op0, float* __restrict__ Op1,
               float* __restrict__ lp)
{
    __shared__ __align__(16) unsigned short Ks[64 * SPA];
    __shared__ __align__(16) unsigned short Vt[64 * SPA];   // V^T: rows=d, cols=key
    const int tid = threadIdx.x;
    const int lane = tid & 63, wq = tid >> 6;
    const int ql = lane & 31;
    const int hi = lane >> 5;
    const int q0 = blockIdx.x * 128;
    const int h = blockIdx.y;
    const int b = blockIdx.z >> 1, split = blockIdx.z & 1;
    const size_t base_q = ((size_t)b * TSEQ) * LDQKV + h * DHD;
    const size_t base_k = base_q + 1024;
    const size_t base_v = ((size_t)(b * NH + h) * DHD) * TSEQ;
    const int k00 = split * 1024;

    const int qrow = q0 + wq * 32 + ql;
    bf16x8 qa[4];
    #pragma unroll
    for (int t = 0; t < 4; ++t)
        qa[t] = *(const bf16x8*)(QKVb + base_q + (size_t)qrow * LDQKV + t * 16 + hi * 8);

    f32x16 o0 = (f32x16)0.f, o1 = (f32x16)0.f;
    float l_lane = 0.f;

    const int srow = tid >> 2, scol = (tid & 3) * 8;
    uint4 kr0 = *(const uint4*)(QKVb + base_k + (size_t)(k00 + srow) * LDQKV + scol);
    uint4 kr1 = *(const uint4*)(QKVb + base_k + (size_t)(k00 + srow) * LDQKV + scol + 32);
    uint4 vr0 = *(const uint4*)(Vtg + base_v + (size_t)srow * TSEQ + k00 + scol);
    uint4 vr1 = *(const uint4*)(Vtg + base_v + (size_t)srow * TSEQ + k00 + scol + 32);

    const int NT = 1024 / 64;
    for (int kb = 0; kb < NT; ++kb) {
        __syncthreads();
        *(uint4*)(Ks + srow * SPA + scol)      = kr0;
        *(uint4*)(Ks + srow * SPA + scol + 32) = kr1;
        *(uint4*)(Vt + srow * SPA + scol)      = vr0;
        *(uint4*)(Vt + srow * SPA + scol + 32) = vr1;
        __syncthreads();
        if (kb + 1 < NT) {
            const size_t gk = base_k + (size_t)(k00 + (kb + 1) * 64 + srow) * LDQKV + scol;
            const size_t gv = base_v + (size_t)srow * TSEQ + k00 + (kb + 1) * 64 + scol;
            kr0 = *(const uint4*)(QKVb + gk);
            kr1 = *(const uint4*)(QKVb + gk + 32);
            vr0 = *(const uint4*)(Vtg + gv);
            vr1 = *(const uint4*)(Vtg + gv + 32);
        }
        f32x16 s0 = (f32x16)0.f, s1 = (f32x16)0.f;
        #pragma unroll
        for (int t = 0; t < 4; ++t) {
            bf16x8 k0 = *(const bf16x8*)(Ks + ql * SPA + t * 16 + hi * 8);
            bf16x8 k1 = *(const bf16x8*)(Ks + (32 + ql) * SPA + t * 16 + hi * 8);
            s0 = MFMA32(k0, qa[t], s0);
            s1 = MFMA32(k1, qa[t], s1);
        }
        float ls = 0.f;
        u32 w[8];
        #pragma unroll
        for (int r = 0; r < 16; ++r) { float p = exp2f(s0[r]); s0[r] = p; ls += p; }
        #pragma unroll
        for (int m = 0; m < 8; ++m) w[m] = cvtpk(s0[2*m], s0[2*m+1]);
        #pragma unroll
        for (int tl = 0; tl < 2; ++tl) {
            const int mb = 4 * tl, tk = tl;
            u32 send0 = hi ? w[mb]   : w[mb+2];
            u32 send1 = hi ? w[mb+1] : w[mb+3];
            u32 r0 = (u32)__shfl_xor((int)send0, 32, 64);
            u32 r1 = (u32)__shfl_xor((int)send1, 32, 64);
            union { u32 uw[4]; bf16x8 v; } pu;
            pu.uw[0] = hi ? r0 : w[mb];
            pu.uw[1] = hi ? r1 : w[mb+1];
            pu.uw[2] = hi ? w[mb+2] : r0;
            pu.uw[3] = hi ? w[mb+3] : r1;
            bf16x8 v0 = *(const bf16x8*)(Vt + ql * SPA + tk * 16 + hi * 8);
            bf16x8 v1 = *(const bf16x8*)(Vt + (32 + ql) * SPA + tk * 16 + hi * 8);
            o0 = MFMA32(pu.v, v0, o0);
            o1 = MFMA32(pu.v, v1, o1);
        }
        #pragma unroll
        for (int r = 0; r < 16; ++r) { float p = exp2f(s1[r]); s1[r] = p; ls += p; }
        #pragma unroll
        for (int m = 0; m < 8; ++m) w[m] = cvtpk(s1[2*m], s1[2*m+1]);
        #pragma unroll
        for (int tl = 0; tl < 2; ++tl) {
            const int mb = 4 * tl, tk = 2 + tl;
            u32 send0 = hi ? w[mb]   : w[mb+2];
            u32 send1 = hi ? w[mb+1] : w[mb+3];
            u32 r0 = (u32)__shfl_xor((int)send0, 32, 64);
            u32 r1 = (u32)__shfl_xor((int)send1, 32, 64);
            union { u32 uw[4]; bf16x8 v; } pu;
            pu.uw[0] = hi ? r0 : w[mb];
            pu.uw[1] = hi ? r1 : w[mb+1];
            pu.uw[2] = hi ? w[mb+2] : r0;
            pu.uw[3] = hi ? w[mb+3] : r1;
            bf16x8 v0 = *(const bf16x8*)(Vt + ql * SPA + tk * 16 + hi * 8);
            bf16x8 v1 = *(const bf16x8*)(Vt + (32 + ql) * SPA + tk * 16 + hi * 8);
            o0 = MFMA32(pu.v, v0, o0);
            o1 = MFMA32(pu.v, v1, o1);
        }
        l_lane += ls;
    }
    float l_tot = l_lane + __shfl_xor(l_lane, 32, 64);
    float* Op = split ? Op1 : Op0;
    const size_t ob = ((size_t)b * TSEQ) * MDIM + h * DHD;
    #pragma unroll
    for (int r = 0; r < 16; ++r) {
        int qr = q0 + wq * 32 + (r & 3) + 8 * (r >> 2) + 4 * hi;
        Op[ob + (size_t)qr * MDIM + ql]      = o0[r];
        Op[ob + (size_t)qr * MDIM + 32 + ql] = o1[r];
    }
    if (hi == 0)
        lp[(((size_t)split * NB + b) * NH + h) * TSEQ + q0 + wq * 32 + ql] = l_tot;
}

// ---------------- U: merge splits, normalize, mask-sum over h, bf16 split ----------------
__global__ __launch_bounds__(256)
void compute_U_split(const float* __restrict__ Op0, const float* __restrict__ Op1,
                     const float* __restrict__ lp, const u32* __restrict__ selo,
                     unsigned short* __restrict__ Uh, unsigned short* __restrict__ Ul)
{
    int idx = blockIdx.x * 256 + threadIdx.x;    // < MBT*512
    int bt = idx >> 9, ed = idx & 511, e = ed >> 6, d = ed & 63;
    int b = bt >> 11, t = bt & 2047;
    float sum = 0.f;
    const u32* sp = selo + bt * 16;
    #pragma unroll
    for (int h = 0; h < NH; ++h)
        if (sp[h] & (1u << e)) {
            size_t oi = (size_t)bt * MDIM + h * DHD + d;
            float o = Op0[oi] + Op1[oi];
            size_t li = (((size_t)b) * NH + h) * TSEQ + t;
            float l = lp[li] + lp[li + (size_t)NB * NH * TSEQ];
            sum += o / l;
        }
    unsigned short hi16 = f2bf(sum);
    Uh[idx] = hi16;
    Ul[idx] = f2bf(sum - bf2f(hi16));
}

extern "C" void kernel_launch(void* const* d_in, const int* in_sizes, int n_in,
                              void* d_out, int out_size, void* d_ws, size_t ws_size,
                              hipStream_t stream)
{
    const float* x  = (const float*)d_in[0];
    const float* Wq = (const float*)d_in[1];
    const float* Wk = (const float*)d_in[2];
    const float* Wv = (const float*)d_in[3];
    const float* Ws = (const float*)d_in[4];
    const float* Wd = (const float*)d_in[5];
    const float* Wo = (const float*)d_in[6];
    float* out = (float*)d_out;
    char* ws = (char*)d_ws;

    // region 0 (16.78 MB): [xb|Wqkvb] -> Op0 ; region @46137344 (16.78 MB): xbl -> Op1
    unsigned short* xb    = (unsigned short*)(ws);
    unsigned short* Wqkvb = (unsigned short*)(ws + 8388608);
    float*          Op0   = (float*)(ws);
    unsigned short* QKVb  = (unsigned short*)(ws + 16777216);   // 20.97 MB
    unsigned short* Vtg   = (unsigned short*)(ws + 37748736);   // 8.39 MB
    unsigned short* xbl   = (unsigned short*)(ws + 46137344);   // 8.39 MB (dead before attn)
    float*          Op1   = (float*)(ws + 46137344);            // 16.78 MB
    float*          lp    = (float*)(ws + 62914560);            // 0.52 MB
    unsigned short* WoTh  = (unsigned short*)(ws + 63438848);   // 1.05 MB
    unsigned short* WoTl  = (unsigned short*)(ws + 64487424);   // 1.05 MB
    float*          Gf    = (float*)(ws + 65536000);            // 4.19 MB (dead before Uh)
    unsigned short* Uh    = (unsigned short*)(ws + 65536000);   // 4.19 MB
    u32*            flags = (u32*)(ws + 69730304);              // 64 KB (dead before Ul)
    unsigned short* Ul    = (unsigned short*)(ws + 69730304);   // 4.19 MB
    float2*         wvp   = (float2*)(ws + 73924608);           // 0.52 MB
    u32*            selv  = (u32*)(ws + 74448896);              // 0.26 MB
    u32*            selo  = (u32*)(ws + 74711040);              // 0.26 MB
    unsigned short* Wsdh  = (unsigned short*)(ws + 74973184);   // 0.52 MB
    unsigned short* Wsdl  = (unsigned short*)(ws + 75497472);   // 0.52 MB

    dim3 blk(256);
    prep<<<5504, blk, 0, stream>>>(x, Wq, Wk, Wv, Ws, Wd, Wo,
                                   xb, xbl, Wqkvb, Wsdh, Wsdl, WoTh, WoTl, flags);
    prep_wsd<<<128, blk, 0, stream>>>(Ws, Wd, Wsdh, Wsdl);

    // fused QKV projection (Q pre-scaled): [4096,2560] = xb * Wqkv^T
    mfma_gemm<<<dim3(20, 32), blk, 0, stream>>>(xb, Wqkvb, QKVb, LDQKV, 1024);

    // gates: split-bf16 MFMA + margin-gated fp64 fix-up
    gate_gemm<<<dim3(4, 64), blk, 0, stream>>>(xb, xbl, Wsdh, Wsdl, Gf);
    gate_topk2<<<256, blk, 0, stream>>>(Gf, wvp, selv, selo, flags);
    gate_fix<<<64, blk, 0, stream>>>(x, Ws, Wd, flags, wvp, selv, selo);

    vtrans<<<2048, blk, 0, stream>>>(QKVb, wvp, selv, Vtg);

    attn_mfma<<<dim3(TSEQ / 128, NH, NB * 2), blk, 0, stream>>>(QKVb, Vtg, Op0, Op1, lp);

    compute_U_split<<<8192, blk, 0, stream>>>(Op0, Op1, lp, selo, Uh, Ul);
    mfma_gemm3<<<dim3(8, 32), blk, 0, stream>>>(Uh, Ul, WoTh, WoTl, out);
}

// Round 7
// 262.844 us; speedup vs baseline: 6.0005x; 1.0204x over previous
//
#include <hip/hip_runtime.h>
#include <math.h>

#define TSEQ 2048
#define NB   2
#define NH   16
#define NE   8
#define DHD  64
#define MDIM 1024
#define MBT  4096   // NB*TSEQ
#define LDQKV 2560  // Q(1024) | K(1024) | V-experts(512)
#define GTAU 1e-3f  // margin threshold for fp64 gate fix-up
#define MAXFLAG 16384

typedef __attribute__((ext_vector_type(8))) short bf16x8;
typedef __attribute__((ext_vector_type(4))) float f32x4;
typedef __attribute__((ext_vector_type(16))) float f32x16;
typedef unsigned int u32;

__device__ inline unsigned short f2bf(float f) {
    union { float f; unsigned u; } v; v.f = f;
    unsigned r = v.u + 0x7fff + ((v.u >> 16) & 1);
    return (unsigned short)(r >> 16);
}
__device__ inline float bf2f(unsigned short h) {
    union { unsigned u; float f; } v; v.u = ((unsigned)h) << 16;
    return v.f;
}
__device__ inline u32 cvtpk(float a, float b) {   // low16=bf16(a), high16=bf16(b)
    u32 r;
    asm("v_cvt_pk_bf16_f32 %0, %1, %2" : "=v"(r) : "v"(a), "v"(b));
    return r;
}

// async global->LDS, 16B per lane (dst wave-uniform base + lane*16)
__device__ inline void gload16(const void* g, void* l) {
    __builtin_amdgcn_global_load_lds((const __attribute__((address_space(1))) u32*)g,
                                     (__attribute__((address_space(3))) u32*)l, 16, 0, 0);
}

__device__ inline void cast8s(const float* __restrict__ in, unsigned short* __restrict__ out,
                              int i, float sc) {
    const float4* p = (const float4*)(in + (size_t)i * 8);
    float4 a = p[0], b = p[1];
    unsigned short o[8] = { f2bf(a.x*sc), f2bf(a.y*sc), f2bf(a.z*sc), f2bf(a.w*sc),
                            f2bf(b.x*sc), f2bf(b.y*sc), f2bf(b.z*sc), f2bf(b.w*sc) };
    *(uint4*)(out + (size_t)i * 8) = *(const uint4*)o;
}
__device__ inline void cast8hl(const float* __restrict__ in,
                               unsigned short* __restrict__ oh, unsigned short* __restrict__ ol,
                               int i) {
    const float4* p = (const float4*)(in + (size_t)i * 8);
    float4 a = p[0], b = p[1];
    float f[8] = { a.x, a.y, a.z, a.w, b.x, b.y, b.z, b.w };
    unsigned short h8[8], l8[8];
    #pragma unroll
    for (int j = 0; j < 8; ++j) {
        unsigned short hi = f2bf(f[j]);
        h8[j] = hi;
        l8[j] = f2bf(f[j] - bf2f(hi));
    }
    *(uint4*)(oh + (size_t)i * 8) = *(const uint4*)h8;
    *(uint4*)(ol + (size_t)i * 8) = *(const uint4*)l8;
}

// ---------------- fused prep (casts + Wsd split + Wo repack/split + flag reset) ----------------
__global__ __launch_bounds__(256)
void prep(const float* __restrict__ x,  const float* __restrict__ Wq,
          const float* __restrict__ Wk, const float* __restrict__ Wv,
          const float* __restrict__ Ws, const float* __restrict__ Wd,
          const float* __restrict__ Wo,
          unsigned short* __restrict__ xb, unsigned short* __restrict__ xbl,
          unsigned short* __restrict__ Wqkvb,
          unsigned short* __restrict__ Wsdh, unsigned short* __restrict__ Wsdl,
          unsigned short* __restrict__ WoTh, unsigned short* __restrict__ WoTl,
          u32* __restrict__ flags)
{
    const float qsc = 0.125f * 1.4426950408889634f;  // fold scale*log2(e) into Q
    int b = blockIdx.x, tid = threadIdx.x;
    if (b == 0 && tid == 0) flags[0] = 0;
    if (b < 2048)      cast8hl(x, xb, xbl,          (b        ) * 256 + tid);
    else if (b < 2560) cast8s(Wq, Wqkvb,            (b - 2048) * 256 + tid, qsc);
    else if (b < 3072) cast8s(Wk, Wqkvb + 1048576,  (b - 2560) * 256 + tid, 1.f);
    else if (b < 3328) cast8s(Wv, Wqkvb + 2097152,  (b - 3072) * 256 + tid, 1.f);
    else if (b < 3456) {
        int i = (b - 3328) * 256 + tid;   // 0..32767; 8 elems each of Ws|Wd
        const float* src = (i < 16384) ? Ws + (size_t)i * 8 : Wd + (size_t)(i - 16384) * 8;
        const float4* p = (const float4*)src;
        float4 a = p[0], bq = p[1];
        float f8[8] = { a.x, a.y, a.z, a.w, bq.x, bq.y, bq.z, bq.w };
        unsigned short h8[8], l8[8];
        #pragma unroll
        for (int j = 0; j < 8; ++j) {
            unsigned short hi = f2bf(f8[j]);
            h8[j] = hi;
            l8[j] = f2bf(f8[j] - bf2f(hi));
        }
        *(uint4*)(Wsdh + (size_t)i * 8) = *(const uint4*)h8;
        *(uint4*)(Wsdl + (size_t)i * 8) = *(const uint4*)l8;
    } else {
        int idx = (b - 3456) * 256 + tid;  // < 524288
        int f = idx >> 9, ed = idx & 511, e = ed >> 6, d = ed & 63;
        float v = Wo[(size_t)e * (MDIM * DHD) + (size_t)f * DHD + d];
        unsigned short hi = f2bf(v);
        WoTh[idx] = hi;
        WoTl[idx] = f2bf(v - bf2f(hi));
    }
}

// ---------------- bf16 MFMA GEMM (gload_lds staging, XCD-swizzled): C[M,N]=A*B^T ----------------
// flat grid (nbx*nby), gridDim.x % 8 == 0
__global__ __launch_bounds__(256)
void mfma_gemm(const unsigned short* __restrict__ A,
               const unsigned short* __restrict__ B,
               unsigned short* __restrict__ C, int N, int K, int nbx)
{
    __shared__ __align__(16) unsigned short As[128 * 32];
    __shared__ __align__(16) unsigned short Bs[128 * 32];
    const int o = blockIdx.x;
    const int q8 = (int)gridDim.x >> 3;
    const int virt = (o & 7) * q8 + (o >> 3);      // bijective XCD-chunked remap
    const int bx = virt % nbx, by = virt / nbx;
    const int tid = threadIdx.x;
    const int lane = tid & 63, wave = tid >> 6;
    const int m0 = by * 128, n0 = bx * 128;
    const int wm = (wave >> 1) * 64, wn = (wave & 1) * 64;
    const int fr = lane & 15, fg = lane >> 4;
    const int grow = lane >> 2, gcol = (lane & 3) * 8;

    f32x4 acc[4][4];
    #pragma unroll
    for (int i = 0; i < 4; ++i)
        #pragma unroll
        for (int j = 0; j < 4; ++j) acc[i][j] = (f32x4)0.f;

    for (int k0 = 0; k0 < K; k0 += 32) {
        __syncthreads();
        const unsigned short* gA = A + (size_t)(m0 + wave * 32 + grow) * K + k0 + gcol;
        gload16(gA,                 As + wave * 1024);
        gload16(gA + (size_t)16 * K, As + wave * 1024 + 512);
        const unsigned short* gB = B + (size_t)(n0 + wave * 32 + grow) * K + k0 + gcol;
        gload16(gB,                 Bs + wave * 1024);
        gload16(gB + (size_t)16 * K, Bs + wave * 1024 + 512);
        __syncthreads();
        bf16x8 af[4], bfr[4];
        #pragma unroll
        for (int t = 0; t < 4; ++t) {
            af[t]  = *(const bf16x8*)(As + (wm + t * 16 + fr) * 32 + fg * 8);
            bfr[t] = *(const bf16x8*)(Bs + (wn + t * 16 + fr) * 32 + fg * 8);
        }
        #pragma unroll
        for (int i = 0; i < 4; ++i)
            #pragma unroll
            for (int j = 0; j < 4; ++j)
                acc[i][j] = __builtin_amdgcn_mfma_f32_16x16x32_bf16(af[i], bfr[j], acc[i][j], 0, 0, 0);
    }
    #pragma unroll
    for (int i = 0; i < 4; ++i)
        #pragma unroll
        for (int j = 0; j < 4; ++j)
            #pragma unroll
            for (int rr = 0; rr < 4; ++rr) {
                int row = m0 + wm + i * 16 + fg * 4 + rr;
                int col = n0 + wn + j * 16 + fr;
                C[(size_t)row * N + col] = f2bf(acc[i][j][rr]);
            }
}

// ---------------- split-bf16 3-pass MFMA GEMM, fp32 out (final projection, swizzled) ----------------
__global__ __launch_bounds__(256)
void mfma_gemm3(const unsigned short* __restrict__ Ah, const unsigned short* __restrict__ Al,
                const unsigned short* __restrict__ Bh, const unsigned short* __restrict__ Bl,
                float* __restrict__ C)
{
    const int Kc = 512, N = 1024;
    __shared__ __align__(16) unsigned short Ash[128 * 32];
    __shared__ __align__(16) unsigned short Asl[128 * 32];
    __shared__ __align__(16) unsigned short Bsh[128 * 32];
    __shared__ __align__(16) unsigned short Bsl[128 * 32];
    const int o = blockIdx.x;                       // 256 blocks
    const int virt = (o & 7) * 32 + (o >> 3);
    const int bx = virt & 7, by = virt >> 3;
    const int tid = threadIdx.x;
    const int lane = tid & 63, wave = tid >> 6;
    const int m0 = by * 128, n0 = bx * 128;
    const int wm = (wave >> 1) * 64, wn = (wave & 1) * 64;
    const int fr = lane & 15, fg = lane >> 4;
    const int grow = lane >> 2, gcol = (lane & 3) * 8;

    f32x4 acc[4][4];
    #pragma unroll
    for (int i = 0; i < 4; ++i)
        #pragma unroll
        for (int j = 0; j < 4; ++j) acc[i][j] = (f32x4)0.f;

    for (int k0 = 0; k0 < Kc; k0 += 32) {
        __syncthreads();
        const size_t roff  = (size_t)(m0 + wave * 32 + grow) * Kc + k0 + gcol;
        const size_t roffB = (size_t)(n0 + wave * 32 + grow) * Kc + k0 + gcol;
        gload16(Ah + roff,             Ash + wave * 1024);
        gload16(Ah + roff + 16 * Kc,   Ash + wave * 1024 + 512);
        gload16(Al + roff,             Asl + wave * 1024);
        gload16(Al + roff + 16 * Kc,   Asl + wave * 1024 + 512);
        gload16(Bh + roffB,            Bsh + wave * 1024);
        gload16(Bh + roffB + 16 * Kc,  Bsh + wave * 1024 + 512);
        gload16(Bl + roffB,            Bsl + wave * 1024);
        gload16(Bl + roffB + 16 * Kc,  Bsl + wave * 1024 + 512);
        __syncthreads();
        bf16x8 ah[4], al[4], bh[4], bl[4];
        #pragma unroll
        for (int t = 0; t < 4; ++t) {
            ah[t] = *(const bf16x8*)(Ash + (wm + t * 16 + fr) * 32 + fg * 8);
            al[t] = *(const bf16x8*)(Asl + (wm + t * 16 + fr) * 32 + fg * 8);
            bh[t] = *(const bf16x8*)(Bsh + (wn + t * 16 + fr) * 32 + fg * 8);
            bl[t] = *(const bf16x8*)(Bsl + (wn + t * 16 + fr) * 32 + fg * 8);
        }
        #pragma unroll
        for (int i = 0; i < 4; ++i)
            #pragma unroll
            for (int j = 0; j < 4; ++j) {
                acc[i][j] = __builtin_amdgcn_mfma_f32_16x16x32_bf16(ah[i], bh[j], acc[i][j], 0, 0, 0);
                acc[i][j] = __builtin_amdgcn_mfma_f32_16x16x32_bf16(ah[i], bl[j], acc[i][j], 0, 0, 0);
                acc[i][j] = __builtin_amdgcn_mfma_f32_16x16x32_bf16(al[i], bh[j], acc[i][j], 0, 0, 0);
            }
    }
    #pragma unroll
    for (int i = 0; i < 4; ++i)
        #pragma unroll
        for (int j = 0; j < 4; ++j)
            #pragma unroll
            for (int rr = 0; rr < 4; ++rr) {
                int row = m0 + wm + i * 16 + fg * 4 + rr;
                int col = n0 + wn + j * 16 + fr;
                C[(size_t)row * N + col] = acc[i][j][rr];
            }
}

// ---------------- gate GEMM: split-bf16 3-pass, Gf[4096][256] fp32 ----------------
__global__ __launch_bounds__(256)
void gate_gemm(const unsigned short* __restrict__ Ah, const unsigned short* __restrict__ Al,
               const unsigned short* __restrict__ Bh, const unsigned short* __restrict__ Bl,
               float* __restrict__ C)
{
    const int K = 1024, N = 256;
    __shared__ __align__(16) unsigned short S[4][64 * 32];
    const int tid = threadIdx.x;
    const int lane = tid & 63, wave = tid >> 6;
    const int m0 = blockIdx.y * 64, n0 = blockIdx.x * 64;
    const int wm = (wave >> 1) * 32, wn = (wave & 1) * 32;
    const int fr = lane & 15, fg = lane >> 4;
    const int grow = lane >> 2, gcol = (lane & 3) * 8;

    const unsigned short* src = (wave == 0) ? Ah : (wave == 1) ? Al : (wave == 2) ? Bh : Bl;
    const int brow = (wave >= 2) ? n0 : m0;

    f32x4 acc[2][2];
    #pragma unroll
    for (int i = 0; i < 2; ++i)
        #pragma unroll
        for (int j = 0; j < 2; ++j) acc[i][j] = (f32x4)0.f;

    for (int k0 = 0; k0 < K; k0 += 32) {
        __syncthreads();
        #pragma unroll
        for (int i = 0; i < 4; ++i)
            gload16(src + (size_t)(brow + i * 16 + grow) * K + k0 + gcol, &S[wave][i * 512]);
        __syncthreads();
        bf16x8 ah[2], al[2], bh[2], bl[2];
        #pragma unroll
        for (int t = 0; t < 2; ++t) {
            ah[t] = *(const bf16x8*)(&S[0][(wm + t * 16 + fr) * 32 + fg * 8]);
            al[t] = *(const bf16x8*)(&S[1][(wm + t * 16 + fr) * 32 + fg * 8]);
            bh[t] = *(const bf16x8*)(&S[2][(wn + t * 16 + fr) * 32 + fg * 8]);
            bl[t] = *(const bf16x8*)(&S[3][(wn + t * 16 + fr) * 32 + fg * 8]);
        }
        #pragma unroll
        for (int i = 0; i < 2; ++i)
            #pragma unroll
            for (int j = 0; j < 2; ++j) {
                acc[i][j] = __builtin_amdgcn_mfma_f32_16x16x32_bf16(ah[i], bh[j], acc[i][j], 0, 0, 0);
                acc[i][j] = __builtin_amdgcn_mfma_f32_16x16x32_bf16(ah[i], bl[j], acc[i][j], 0, 0, 0);
                acc[i][j] = __builtin_amdgcn_mfma_f32_16x16x32_bf16(al[i], bh[j], acc[i][j], 0, 0, 0);
            }
    }
    #pragma unroll
    for (int i = 0; i < 2; ++i)
        #pragma unroll
        for (int j = 0; j < 2; ++j)
            #pragma unroll
            for (int rr = 0; rr < 4; ++rr) {
                int row = m0 + wm + i * 16 + fg * 4 + rr;
                int col = n0 + wn + j * 16 + fr;
                C[(size_t)row * N + col] = acc[i][j][rr];
            }
}

// ---------------- top-2 + margin flagging ----------------
__global__ __launch_bounds__(256)
void gate_topk2(const float* __restrict__ Gf,
                float2* __restrict__ wv, u32* __restrict__ selv, u32* __restrict__ selo,
                u32* __restrict__ flags)
{
    int item = blockIdx.x * 256 + threadIdx.x;   // < 65536
    int bt = item >> 4, h = item & 15;
    const float* g = Gf + (size_t)bt * 256 + h * NE;
    float b1 = -1e30f, b2 = -1e30f, b3 = -1e30f; int e1 = 0, e2 = 0;
    #pragma unroll
    for (int e = 0; e < NE; ++e) {
        float v = g[e];
        if (v > b1)      { b3 = b2; b2 = b1; e2 = e1; b1 = v; e1 = e; }
        else if (v > b2) { b3 = b2; b2 = v;  e2 = e; }
        else if (v > b3) { b3 = v; }
    }
    wv[item] = make_float2(1.f / (1.f + __expf(-b1)), 1.f / (1.f + __expf(-b2)));
    selv[item] = (u32)e1 | ((u32)e2 << 4);
    if (b2 - b3 < GTAU) {
        u32 p = atomicAdd(flags, 1u);
        if (p < MAXFLAG) flags[1 + p] = (u32)item;
    }
    const float* go = g + 128;
    float o1 = -1e30f, o2 = -1e30f, o3 = -1e30f; int f1 = 0, f2 = 0;
    #pragma unroll
    for (int e = 0; e < NE; ++e) {
        float v = go[e];
        if (v > o1)      { o3 = o2; o2 = o1; f2 = f1; o1 = v; f1 = e; }
        else if (v > o2) { o3 = o2; o2 = v;  f2 = e; }
        else if (v > o3) { o3 = v; }
    }
    selo[item] = (1u << f1) | (1u << f2);
    if (o2 - o3 < GTAU) {
        u32 p = atomicAdd(flags, 1u);
        if (p < MAXFLAG) flags[1 + p] = (u32)item | 0x10000u;
    }
}

// ---------------- fp64 fix-up for flagged near-tie items (one wave per record) ----------------
__global__ __launch_bounds__(256)
void gate_fix(const float* __restrict__ x, const float* __restrict__ Ws,
              const float* __restrict__ Wd, const u32* __restrict__ flags,
              float2* __restrict__ wv, u32* __restrict__ selv, u32* __restrict__ selo)
{
    u32 nf = flags[0]; if (nf > MAXFLAG) nf = MAXFLAG;
    int gw = (blockIdx.x * 256 + threadIdx.x) >> 6;
    int lane = threadIdx.x & 63;
    int nwaves = gridDim.x * 4;
    for (u32 w = gw; w < nf; w += nwaves) {
        u32 rec = flags[1 + w];
        int item = rec & 0xffff, which = rec >> 16;
        int bt = item >> 4, h = item & 15;
        const float* W = (which ? Wd : Ws) + (size_t)h * NE * MDIM + lane * 16;
        const float* xr = x + (size_t)bt * MDIM + lane * 16;
        double g[8];
        #pragma unroll
        for (int e = 0; e < 8; ++e) {
            double s = 0.0;
            #pragma unroll
            for (int c = 0; c < 16; ++c)
                s += (double)xr[c] * (double)W[(size_t)e * MDIM + c];
            g[e] = s;
        }
        #pragma unroll
        for (int off = 32; off; off >>= 1)
            #pragma unroll
            for (int e = 0; e < 8; ++e)
                g[e] += __shfl_xor(g[e], off, 64);
        if (lane == 0) {
            double b1 = -1e300, b2 = -1e300; int i1 = 0, i2 = 0;
            #pragma unroll
            for (int e = 0; e < 8; ++e) {
                double v = g[e];
                if (v > b1)      { b2 = b1; i2 = i1; b1 = v; i1 = e; }
                else if (v > b2) { b2 = v;  i2 = e; }
            }
            if (which == 0) {
                wv[item] = make_float2(1.f / (1.f + __expf(-(float)b1)),
                                       1.f / (1.f + __expf(-(float)b2)));
                selv[item] = (u32)i1 | ((u32)i2 << 4);
            } else {
                selo[item] = (1u << i1) | (1u << i2);
            }
        }
    }
}

// ---------------- V mix + transpose: Vtg[b][h][d][t] ----------------
__global__ __launch_bounds__(256)
void vtrans(const unsigned short* __restrict__ QKVb, const float2* __restrict__ wv,
            const u32* __restrict__ selv, unsigned short* __restrict__ Vtg)
{
    int idx = blockIdx.x * 256 + threadIdx.x;    // < 524288
    int tc = idx & 255;
    int d  = (idx >> 8) & 63;
    int h  = (idx >> 14) & 15;
    int b  = idx >> 18;
    unsigned short o[8];
    #pragma unroll
    for (int j = 0; j < 8; ++j) {
        int bt = b * TSEQ + tc * 8 + j;
        u32 s = selv[bt * 16 + h];
        float2 w = wv[bt * 16 + h];
        int e1 = s & 15, e2 = (s >> 4) & 15;
        const unsigned short* pv = QKVb + (size_t)bt * LDQKV + 2048;
        float v = w.x * bf2f(pv[e1 * 64 + d]) + w.y * bf2f(pv[e2 * 64 + d]);
        o[j] = f2bf(v);
    }
    *(uint4*)(Vtg + ((size_t)((b * NH + h) * DHD + d)) * TSEQ + tc * 8) = *(const uint4*)o;
}

// ---------------- attn: swapped-QK 32x32 MFMA, in-register P, fixed-max softmax ----------------
// flat grid 1024, XCD-swizzled: each XCD owns 8 (b,h,split) groups x 16 q-blocks
#define SPA 72   // LDS row stride (bf16) = 144 B
#define MFMA32(A,B,C) __builtin_amdgcn_mfma_f32_32x32x16_bf16(A, B, C, 0, 0, 0)
__global__ __launch_bounds__(256)
void attn_mfma(const unsigned short* __restrict__ QKVb,
               const unsigned short* __restrict__ Vtg,
               float* __restrict__ Op0, float* __restrict__ Op1,
               float* __restrict__ lp)
{
    __shared__ __align__(16) unsigned short Ks[64 * SPA];
    __shared__ __align__(16) unsigned short Vt[64 * SPA];   // V^T: rows=d, cols=key
    const int vid = blockIdx.x;                  // 0..1023
    const int xcd = vid & 7, sl = vid >> 3;      // sl 0..127
    const int grp = xcd * 8 + (sl >> 4);         // 0..63 (b,h,split group)
    const int q0  = (sl & 15) * 128;
    const int h   = grp & 15;
    const int z   = grp >> 4;                    // 0..3
    const int b = z >> 1, split = z & 1;
    const int tid = threadIdx.x;
    const int lane = tid & 63, wq = tid >> 6;
    const int ql = lane & 31;
    const int hi = lane >> 5;
    const size_t base_q = ((size_t)b * TSEQ) * LDQKV + h * DHD;
    const size_t base_k = base_q + 1024;
    const size_t base_v = ((size_t)(b * NH + h) * DHD) * TSEQ;
    const int k00 = split * 1024;

    const int qrow = q0 + wq * 32 + ql;
    bf16x8 qa[4];
    #pragma unroll
    for (int t = 0; t < 4; ++t)
        qa[t] = *(const bf16x8*)(QKVb + base_q + (size_t)qrow * LDQKV + t * 16 + hi * 8);

    f32x16 o0 = (f32x16)0.f, o1 = (f32x16)0.f;
    float l_lane = 0.f;

    const int srow = tid >> 2, scol = (tid & 3) * 8;
    uint4 kr0 = *(const uint4*)(QKVb + base_k + (size_t)(k00 + srow) * LDQKV + scol);
    uint4 kr1 = *(const uint4*)(QKVb + base_k + (size_t)(k00 + srow) * LDQKV + scol + 32);
    uint4 vr0 = *(const uint4*)(Vtg + base_v + (size_t)srow * TSEQ + k00 + scol);
    uint4 vr1 = *(const uint4*)(Vtg + base_v + (size_t)srow * TSEQ + k00 + scol + 32);

    const int NT = 1024 / 64;
    for (int kb = 0; kb < NT; ++kb) {
        __syncthreads();
        *(uint4*)(Ks + srow * SPA + scol)      = kr0;
        *(uint4*)(Ks + srow * SPA + scol + 32) = kr1;
        *(uint4*)(Vt + srow * SPA + scol)      = vr0;
        *(uint4*)(Vt + srow * SPA + scol + 32) = vr1;
        __syncthreads();
        if (kb + 1 < NT) {
            const size_t gk = base_k + (size_t)(k00 + (kb + 1) * 64 + srow) * LDQKV + scol;
            const size_t gv = base_v + (size_t)srow * TSEQ + k00 + (kb + 1) * 64 + scol;
            kr0 = *(const uint4*)(QKVb + gk);
            kr1 = *(const uint4*)(QKVb + gk + 32);
            vr0 = *(const uint4*)(Vtg + gv);
            vr1 = *(const uint4*)(Vtg + gv + 32);
        }
        f32x16 s0 = (f32x16)0.f, s1 = (f32x16)0.f;
        #pragma unroll
        for (int t = 0; t < 4; ++t) {
            bf16x8 k0 = *(const bf16x8*)(Ks + ql * SPA + t * 16 + hi * 8);
            bf16x8 k1 = *(const bf16x8*)(Ks + (32 + ql) * SPA + t * 16 + hi * 8);
            s0 = MFMA32(k0, qa[t], s0);
            s1 = MFMA32(k1, qa[t], s1);
        }
        float ls = 0.f;
        u32 w[8];
        #pragma unroll
        for (int r = 0; r < 16; ++r) { float p = exp2f(s0[r]); s0[r] = p; ls += p; }
        #pragma unroll
        for (int m = 0; m < 8; ++m) w[m] = cvtpk(s0[2*m], s0[2*m+1]);
        #pragma unroll
        for (int tl = 0; tl < 2; ++tl) {
            const int mb = 4 * tl, tk = tl;
            u32 send0 = hi ? w[mb]   : w[mb+2];
            u32 send1 = hi ? w[mb+1] : w[mb+3];
            u32 r0 = (u32)__shfl_xor((int)send0, 32, 64);
            u32 r1 = (u32)__shfl_xor((int)send1, 32, 64);
            union { u32 uw[4]; bf16x8 v; } pu;
            pu.uw[0] = hi ? r0 : w[mb];
            pu.uw[1] = hi ? r1 : w[mb+1];
            pu.uw[2] = hi ? w[mb+2] : r0;
            pu.uw[3] = hi ? w[mb+3] : r1;
            bf16x8 v0 = *(const bf16x8*)(Vt + ql * SPA + tk * 16 + hi * 8);
            bf16x8 v1 = *(const bf16x8*)(Vt + (32 + ql) * SPA + tk * 16 + hi * 8);
            o0 = MFMA32(pu.v, v0, o0);
            o1 = MFMA32(pu.v, v1, o1);
        }
        #pragma unroll
        for (int r = 0; r < 16; ++r) { float p = exp2f(s1[r]); s1[r] = p; ls += p; }
        #pragma unroll
        for (int m = 0; m < 8; ++m) w[m] = cvtpk(s1[2*m], s1[2*m+1]);
        #pragma unroll
        for (int tl = 0; tl < 2; ++tl) {
            const int mb = 4 * tl, tk = 2 + tl;
            u32 send0 = hi ? w[mb]   : w[mb+2];
            u32 send1 = hi ? w[mb+1] : w[mb+3];
            u32 r0 = (u32)__shfl_xor((int)send0, 32, 64);
            u32 r1 = (u32)__shfl_xor((int)send1, 32, 64);
            union { u32 uw[4]; bf16x8 v; } pu;
            pu.uw[0] = hi ? r0 : w[mb];
            pu.uw[1] = hi ? r1 : w[mb+1];
            pu.uw[2] = hi ? w[mb+2] : r0;
            pu.uw[3] = hi ? w[mb+3] : r1;
            bf16x8 v0 = *(const bf16x8*)(Vt + ql * SPA + tk * 16 + hi * 8);
            bf16x8 v1 = *(const bf16x8*)(Vt + (32 + ql) * SPA + tk * 16 + hi * 8);
            o0 = MFMA32(pu.v, v0, o0);
            o1 = MFMA32(pu.v, v1, o1);
        }
        l_lane += ls;
    }
    float l_tot = l_lane + __shfl_xor(l_lane, 32, 64);
    float* Op = split ? Op1 : Op0;
    const size_t ob = ((size_t)b * TSEQ) * MDIM + h * DHD;
    #pragma unroll
    for (int r = 0; r < 16; ++r) {
        int qr = q0 + wq * 32 + (r & 3) + 8 * (r >> 2) + 4 * hi;
        Op[ob + (size_t)qr * MDIM + ql]      = o0[r];
        Op[ob + (size_t)qr * MDIM + 32 + ql] = o1[r];
    }
    if (hi == 0)
        lp[(((size_t)split * NB + b) * NH + h) * TSEQ + q0 + wq * 32 + ql] = l_tot;
}

// ---------------- U: merge splits, normalize, mask-sum over h, bf16 split ----------------
__global__ __launch_bounds__(256)
void compute_U_split(const float* __restrict__ Op0, const float* __restrict__ Op1,
                     const float* __restrict__ lp, const u32* __restrict__ selo,
                     unsigned short* __restrict__ Uh, unsigned short* __restrict__ Ul)
{
    int idx = blockIdx.x * 256 + threadIdx.x;    // < MBT*512
    int bt = idx >> 9, ed = idx & 511, e = ed >> 6, d = ed & 63;
    int b = bt >> 11, t = bt & 2047;
    float sum = 0.f;
    const u32* sp = selo + bt * 16;
    #pragma unroll
    for (int h = 0; h < NH; ++h)
        if (sp[h] & (1u << e)) {
            size_t oi = (size_t)bt * MDIM + h * DHD + d;
            float o = Op0[oi] + Op1[oi];
            size_t li = (((size_t)b) * NH + h) * TSEQ + t;
            float l = lp[li] + lp[li + (size_t)NB * NH * TSEQ];
            sum += o / l;
        }
    unsigned short hi16 = f2bf(sum);
    Uh[idx] = hi16;
    Ul[idx] = f2bf(sum - bf2f(hi16));
}

extern "C" void kernel_launch(void* const* d_in, const int* in_sizes, int n_in,
                              void* d_out, int out_size, void* d_ws, size_t ws_size,
                              hipStream_t stream)
{
    const float* x  = (const float*)d_in[0];
    const float* Wq = (const float*)d_in[1];
    const float* Wk = (const float*)d_in[2];
    const float* Wv = (const float*)d_in[3];
    const float* Ws = (const float*)d_in[4];
    const float* Wd = (const float*)d_in[5];
    const float* Wo = (const float*)d_in[6];
    float* out = (float*)d_out;
    char* ws = (char*)d_ws;

    // region 0 (16.78 MB): [xb|Wqkvb] -> Op0 ; region @46137344 (16.78 MB): xbl -> Op1
    unsigned short* xb    = (unsigned short*)(ws);
    unsigned short* Wqkvb = (unsigned short*)(ws + 8388608);
    float*          Op0   = (float*)(ws);
    unsigned short* QKVb  = (unsigned short*)(ws + 16777216);   // 20.97 MB
    unsigned short* Vtg   = (unsigned short*)(ws + 37748736);   // 8.39 MB
    unsigned short* xbl   = (unsigned short*)(ws + 46137344);   // 8.39 MB (dead before attn)
    float*          Op1   = (float*)(ws + 46137344);            // 16.78 MB
    float*          lp    = (float*)(ws + 62914560);            // 0.52 MB
    unsigned short* WoTh  = (unsigned short*)(ws + 63438848);   // 1.05 MB
    unsigned short* WoTl  = (unsigned short*)(ws + 64487424);   // 1.05 MB
    float*          Gf    = (float*)(ws + 65536000);            // 4.19 MB (dead before Uh)
    unsigned short* Uh    = (unsigned short*)(ws + 65536000);   // 4.19 MB
    u32*            flags = (u32*)(ws + 69730304);              // 64 KB (dead before Ul)
    unsigned short* Ul    = (unsigned short*)(ws + 69730304);   // 4.19 MB
    float2*         wvp   = (float2*)(ws + 73924608);           // 0.52 MB
    u32*            selv  = (u32*)(ws + 74448896);              // 0.26 MB
    u32*            selo  = (u32*)(ws + 74711040);              // 0.26 MB
    unsigned short* Wsdh  = (unsigned short*)(ws + 74973184);   // 0.52 MB
    unsigned short* Wsdl  = (unsigned short*)(ws + 75497472);   // 0.52 MB

    dim3 blk(256);
    prep<<<5504, blk, 0, stream>>>(x, Wq, Wk, Wv, Ws, Wd, Wo,
                                   xb, xbl, Wqkvb, Wsdh, Wsdl, WoTh, WoTl, flags);

    // fused QKV projection (Q pre-scaled): [4096,2560] = xb * Wqkv^T  (XCD-swizzled)
    mfma_gemm<<<640, blk, 0, stream>>>(xb, Wqkvb, QKVb, LDQKV, 1024, 20);

    // gates: split-bf16 MFMA + margin-gated fp64 fix-up
    gate_gemm<<<dim3(4, 64), blk, 0, stream>>>(xb, xbl, Wsdh, Wsdl, Gf);
    gate_topk2<<<256, blk, 0, stream>>>(Gf, wvp, selv, selo, flags);
    gate_fix<<<64, blk, 0, stream>>>(x, Ws, Wd, flags, wvp, selv, selo);

    vtrans<<<2048, blk, 0, stream>>>(QKVb, wvp, selv, Vtg);

    attn_mfma<<<1024, blk, 0, stream>>>(QKVb, Vtg, Op0, Op1, lp);

    compute_U_split<<<8192, blk, 0, stream>>>(Op0, Op1, lp, selo, Uh, Ul);
    mfma_gemm3<<<256, blk, 0, stream>>>(Uh, Ul, WoTh, WoTl, out);
}

// Round 9
// 245.410 us; speedup vs baseline: 6.4268x; 1.0710x over previous
//
#include <hip/hip_runtime.h>
#include <math.h>

#define TSEQ 2048
#define NB   2
#define NH   16
#define NE   8
#define DHD  64
#define MDIM 1024
#define MBT  4096   // NB*TSEQ
#define LDQKV 2560  // Q(1024) | K(1024) | V-experts(512)
#define GTAU 1e-3f  // margin threshold for fp64 gate fix-up
#define MAXFLAG 16384

typedef __attribute__((ext_vector_type(8))) short bf16x8;
typedef __attribute__((ext_vector_type(4))) float f32x4;
typedef __attribute__((ext_vector_type(16))) float f32x16;
typedef unsigned int u32;

__device__ inline unsigned short f2bf(float f) {
    union { float f; unsigned u; } v; v.f = f;
    unsigned r = v.u + 0x7fff + ((v.u >> 16) & 1);
    return (unsigned short)(r >> 16);
}
__device__ inline float bf2f(unsigned short h) {
    union { unsigned u; float f; } v; v.u = ((unsigned)h) << 16;
    return v.f;
}
__device__ inline u32 cvtpk(float a, float b) {   // low16=bf16(a), high16=bf16(b)
    u32 r;
    asm("v_cvt_pk_bf16_f32 %0, %1, %2" : "=v"(r) : "v"(a), "v"(b));
    return r;
}

// async global->LDS, 16B per lane (dst wave-uniform base + lane*16)
__device__ inline void gload16(const void* g, void* l) {
    __builtin_amdgcn_global_load_lds((const __attribute__((address_space(1))) u32*)g,
                                     (__attribute__((address_space(3))) u32*)l, 16, 0, 0);
}

__device__ inline void cast8s(const float* __restrict__ in, unsigned short* __restrict__ out,
                              int i, float sc) {
    const float4* p = (const float4*)(in + (size_t)i * 8);
    float4 a = p[0], b = p[1];
    unsigned short o[8] = { f2bf(a.x*sc), f2bf(a.y*sc), f2bf(a.z*sc), f2bf(a.w*sc),
                            f2bf(b.x*sc), f2bf(b.y*sc), f2bf(b.z*sc), f2bf(b.w*sc) };
    *(uint4*)(out + (size_t)i * 8) = *(const uint4*)o;
}
__device__ inline void cast8hl(const float* __restrict__ in,
                               unsigned short* __restrict__ oh, unsigned short* __restrict__ ol,
                               int i) {
    const float4* p = (const float4*)(in + (size_t)i * 8);
    float4 a = p[0], b = p[1];
    float f[8] = { a.x, a.y, a.z, a.w, b.x, b.y, b.z, b.w };
    unsigned short h8[8], l8[8];
    #pragma unroll
    for (int j = 0; j < 8; ++j) {
        unsigned short hi = f2bf(f[j]);
        h8[j] = hi;
        l8[j] = f2bf(f[j] - bf2f(hi));
    }
    *(uint4*)(oh + (size_t)i * 8) = *(const uint4*)h8;
    *(uint4*)(ol + (size_t)i * 8) = *(const uint4*)l8;
}

// ---------------- fused prep (casts + Wsd split + Wo repack/split + flag reset) ----------------
__global__ __launch_bounds__(256)
void prep(const float* __restrict__ x,  const float* __restrict__ Wq,
          const float* __restrict__ Wk, const float* __restrict__ Wv,
          const float* __restrict__ Ws, const float* __restrict__ Wd,
          const float* __restrict__ Wo,
          unsigned short* __restrict__ xb, unsigned short* __restrict__ xbl,
          unsigned short* __restrict__ Wqkvb,
          unsigned short* __restrict__ Wsdh, unsigned short* __restrict__ Wsdl,
          unsigned short* __restrict__ WoTh, unsigned short* __restrict__ WoTl,
          u32* __restrict__ flags)
{
    const float qsc = 0.125f * 1.4426950408889634f;  // fold scale*log2(e) into Q
    int b = blockIdx.x, tid = threadIdx.x;
    if (b == 0 && tid == 0) flags[0] = 0;
    if (b < 2048)      cast8hl(x, xb, xbl,          (b        ) * 256 + tid);
    else if (b < 2560) cast8s(Wq, Wqkvb,            (b - 2048) * 256 + tid, qsc);
    else if (b < 3072) cast8s(Wk, Wqkvb + 1048576,  (b - 2560) * 256 + tid, 1.f);
    else if (b < 3328) cast8s(Wv, Wqkvb + 2097152,  (b - 3072) * 256 + tid, 1.f);
    else if (b < 3456) {
        int i = (b - 3328) * 256 + tid;   // 0..32767; 8 elems each of Ws|Wd
        const float* src = (i < 16384) ? Ws + (size_t)i * 8 : Wd + (size_t)(i - 16384) * 8;
        const float4* p = (const float4*)src;
        float4 a = p[0], bq = p[1];
        float f8[8] = { a.x, a.y, a.z, a.w, bq.x, bq.y, bq.z, bq.w };
        unsigned short h8[8], l8[8];
        #pragma unroll
        for (int j = 0; j < 8; ++j) {
            unsigned short hi = f2bf(f8[j]);
            h8[j] = hi;
            l8[j] = f2bf(f8[j] - bf2f(hi));
        }
        *(uint4*)(Wsdh + (size_t)i * 8) = *(const uint4*)h8;
        *(uint4*)(Wsdl + (size_t)i * 8) = *(const uint4*)l8;
    } else {
        int idx = (b - 3456) * 256 + tid;  // < 524288
        int f = idx >> 9, ed = idx & 511, e = ed >> 6, d = ed & 63;
        float v = Wo[(size_t)e * (MDIM * DHD) + (size_t)f * DHD + d];
        unsigned short hi = f2bf(v);
        WoTh[idx] = hi;
        WoTl[idx] = f2bf(v - bf2f(hi));
    }
}

// ---------------- bf16 MFMA GEMM (gload_lds staging, XCD-swizzled): C[M,N]=A*B^T ----------------
__global__ __launch_bounds__(256)
void mfma_gemm(const unsigned short* __restrict__ A,
               const unsigned short* __restrict__ B,
               unsigned short* __restrict__ C, int N, int K, int nbx)
{
    __shared__ __align__(16) unsigned short As[128 * 32];
    __shared__ __align__(16) unsigned short Bs[128 * 32];
    const int o = blockIdx.x;
    const int q8 = (int)gridDim.x >> 3;
    const int virt = (o & 7) * q8 + (o >> 3);      // bijective XCD-chunked remap
    const int bx = virt % nbx, by = virt / nbx;
    const int tid = threadIdx.x;
    const int lane = tid & 63, wave = tid >> 6;
    const int m0 = by * 128, n0 = bx * 128;
    const int wm = (wave >> 1) * 64, wn = (wave & 1) * 64;
    const int fr = lane & 15, fg = lane >> 4;
    const int grow = lane >> 2, gcol = (lane & 3) * 8;

    f32x4 acc[4][4];
    #pragma unroll
    for (int i = 0; i < 4; ++i)
        #pragma unroll
        for (int j = 0; j < 4; ++j) acc[i][j] = (f32x4)0.f;

    for (int k0 = 0; k0 < K; k0 += 32) {
        __syncthreads();
        const unsigned short* gA = A + (size_t)(m0 + wave * 32 + grow) * K + k0 + gcol;
        gload16(gA,                 As + wave * 1024);
        gload16(gA + (size_t)16 * K, As + wave * 1024 + 512);
        const unsigned short* gB = B + (size_t)(n0 + wave * 32 + grow) * K + k0 + gcol;
        gload16(gB,                 Bs + wave * 1024);
        gload16(gB + (size_t)16 * K, Bs + wave * 1024 + 512);
        __syncthreads();
        bf16x8 af[4], bfr[4];
        #pragma unroll
        for (int t = 0; t < 4; ++t) {
            af[t]  = *(const bf16x8*)(As + (wm + t * 16 + fr) * 32 + fg * 8);
            bfr[t] = *(const bf16x8*)(Bs + (wn + t * 16 + fr) * 32 + fg * 8);
        }
        #pragma unroll
        for (int i = 0; i < 4; ++i)
            #pragma unroll
            for (int j = 0; j < 4; ++j)
                acc[i][j] = __builtin_amdgcn_mfma_f32_16x16x32_bf16(af[i], bfr[j], acc[i][j], 0, 0, 0);
    }
    #pragma unroll
    for (int i = 0; i < 4; ++i)
        #pragma unroll
        for (int j = 0; j < 4; ++j)
            #pragma unroll
            for (int rr = 0; rr < 4; ++rr) {
                int row = m0 + wm + i * 16 + fg * 4 + rr;
                int col = n0 + wn + j * 16 + fr;
                C[(size_t)row * N + col] = f2bf(acc[i][j][rr]);
            }
}

// ---------------- split-bf16 3-pass MFMA GEMM, fp32 out (final projection, swizzled) ----------------
__global__ __launch_bounds__(256)
void mfma_gemm3(const unsigned short* __restrict__ Ah, const unsigned short* __restrict__ Al,
                const unsigned short* __restrict__ Bh, const unsigned short* __restrict__ Bl,
                float* __restrict__ C)
{
    const int Kc = 512, N = 1024;
    __shared__ __align__(16) unsigned short Ash[128 * 32];
    __shared__ __align__(16) unsigned short Asl[128 * 32];
    __shared__ __align__(16) unsigned short Bsh[128 * 32];
    __shared__ __align__(16) unsigned short Bsl[128 * 32];
    const int o = blockIdx.x;                       // 256 blocks
    const int virt = (o & 7) * 32 + (o >> 3);
    const int bx = virt & 7, by = virt >> 3;
    const int tid = threadIdx.x;
    const int lane = tid & 63, wave = tid >> 6;
    const int m0 = by * 128, n0 = bx * 128;
    const int wm = (wave >> 1) * 64, wn = (wave & 1) * 64;
    const int fr = lane & 15, fg = lane >> 4;
    const int grow = lane >> 2, gcol = (lane & 3) * 8;

    f32x4 acc[4][4];
    #pragma unroll
    for (int i = 0; i < 4; ++i)
        #pragma unroll
        for (int j = 0; j < 4; ++j) acc[i][j] = (f32x4)0.f;

    for (int k0 = 0; k0 < Kc; k0 += 32) {
        __syncthreads();
        const size_t roff  = (size_t)(m0 + wave * 32 + grow) * Kc + k0 + gcol;
        const size_t roffB = (size_t)(n0 + wave * 32 + grow) * Kc + k0 + gcol;
        gload16(Ah + roff,             Ash + wave * 1024);
        gload16(Ah + roff + 16 * Kc,   Ash + wave * 1024 + 512);
        gload16(Al + roff,             Asl + wave * 1024);
        gload16(Al + roff + 16 * Kc,   Asl + wave * 1024 + 512);
        gload16(Bh + roffB,            Bsh + wave * 1024);
        gload16(Bh + roffB + 16 * Kc,  Bsh + wave * 1024 + 512);
        gload16(Bl + roffB,            Bsl + wave * 1024);
        gload16(Bl + roffB + 16 * Kc,  Bsl + wave * 1024 + 512);
        __syncthreads();
        bf16x8 ah[4], al[4], bh[4], bl[4];
        #pragma unroll
        for (int t = 0; t < 4; ++t) {
            ah[t] = *(const bf16x8*)(Ash + (wm + t * 16 + fr) * 32 + fg * 8);
            al[t] = *(const bf16x8*)(Asl + (wm + t * 16 + fr) * 32 + fg * 8);
            bh[t] = *(const bf16x8*)(Bsh + (wn + t * 16 + fr) * 32 + fg * 8);
            bl[t] = *(const bf16x8*)(Bsl + (wn + t * 16 + fr) * 32 + fg * 8);
        }
        #pragma unroll
        for (int i = 0; i < 4; ++i)
            #pragma unroll
            for (int j = 0; j < 4; ++j) {
                acc[i][j] = __builtin_amdgcn_mfma_f32_16x16x32_bf16(ah[i], bh[j], acc[i][j], 0, 0, 0);
                acc[i][j] = __builtin_amdgcn_mfma_f32_16x16x32_bf16(ah[i], bl[j], acc[i][j], 0, 0, 0);
                acc[i][j] = __builtin_amdgcn_mfma_f32_16x16x32_bf16(al[i], bh[j], acc[i][j], 0, 0, 0);
            }
    }
    #pragma unroll
    for (int i = 0; i < 4; ++i)
        #pragma unroll
        for (int j = 0; j < 4; ++j)
            #pragma unroll
            for (int rr = 0; rr < 4; ++rr) {
                int row = m0 + wm + i * 16 + fg * 4 + rr;
                int col = n0 + wn + j * 16 + fr;
                C[(size_t)row * N + col] = acc[i][j][rr];
            }
}

// ---------------- gate GEMM: split-bf16 3-pass, Gf[4096][256] fp32 ----------------
__global__ __launch_bounds__(256)
void gate_gemm(const unsigned short* __restrict__ Ah, const unsigned short* __restrict__ Al,
               const unsigned short* __restrict__ Bh, const unsigned short* __restrict__ Bl,
               float* __restrict__ C)
{
    const int K = 1024, N = 256;
    __shared__ __align__(16) unsigned short S[4][64 * 32];
    const int tid = threadIdx.x;
    const int lane = tid & 63, wave = tid >> 6;
    const int m0 = blockIdx.y * 64, n0 = blockIdx.x * 64;
    const int wm = (wave >> 1) * 32, wn = (wave & 1) * 32;
    const int fr = lane & 15, fg = lane >> 4;
    const int grow = lane >> 2, gcol = (lane & 3) * 8;

    const unsigned short* src = (wave == 0) ? Ah : (wave == 1) ? Al : (wave == 2) ? Bh : Bl;
    const int brow = (wave >= 2) ? n0 : m0;

    f32x4 acc[2][2];
    #pragma unroll
    for (int i = 0; i < 2; ++i)
        #pragma unroll
        for (int j = 0; j < 2; ++j) acc[i][j] = (f32x4)0.f;

    for (int k0 = 0; k0 < K; k0 += 32) {
        __syncthreads();
        #pragma unroll
        for (int i = 0; i < 4; ++i)
            gload16(src + (size_t)(brow + i * 16 + grow) * K + k0 + gcol, &S[wave][i * 512]);
        __syncthreads();
        bf16x8 ah[2], al[2], bh[2], bl[2];
        #pragma unroll
        for (int t = 0; t < 2; ++t) {
            ah[t] = *(const bf16x8*)(&S[0][(wm + t * 16 + fr) * 32 + fg * 8]);
            al[t] = *(const bf16x8*)(&S[1][(wm + t * 16 + fr) * 32 + fg * 8]);
            bh[t] = *(const bf16x8*)(&S[2][(wn + t * 16 + fr) * 32 + fg * 8]);
            bl[t] = *(const bf16x8*)(&S[3][(wn + t * 16 + fr) * 32 + fg * 8]);
        }
        #pragma unroll
        for (int i = 0; i < 2; ++i)
            #pragma unroll
            for (int j = 0; j < 2; ++j) {
                acc[i][j] = __builtin_amdgcn_mfma_f32_16x16x32_bf16(ah[i], bh[j], acc[i][j], 0, 0, 0);
                acc[i][j] = __builtin_amdgcn_mfma_f32_16x16x32_bf16(ah[i], bl[j], acc[i][j], 0, 0, 0);
                acc[i][j] = __builtin_amdgcn_mfma_f32_16x16x32_bf16(al[i], bh[j], acc[i][j], 0, 0, 0);
            }
    }
    #pragma unroll
    for (int i = 0; i < 2; ++i)
        #pragma unroll
        for (int j = 0; j < 2; ++j)
            #pragma unroll
            for (int rr = 0; rr < 4; ++rr) {
                int row = m0 + wm + i * 16 + fg * 4 + rr;
                int col = n0 + wn + j * 16 + fr;
                C[(size_t)row * N + col] = acc[i][j][rr];
            }
}

// ---------------- top-2 + margin flagging ----------------
__global__ __launch_bounds__(256)
void gate_topk2(const float* __restrict__ Gf,
                float2* __restrict__ wv, u32* __restrict__ selv, u32* __restrict__ selo,
                u32* __restrict__ flags)
{
    int item = blockIdx.x * 256 + threadIdx.x;   // < 65536
    int bt = item >> 4, h = item & 15;
    const float* g = Gf + (size_t)bt * 256 + h * NE;
    float b1 = -1e30f, b2 = -1e30f, b3 = -1e30f; int e1 = 0, e2 = 0;
    #pragma unroll
    for (int e = 0; e < NE; ++e) {
        float v = g[e];
        if (v > b1)      { b3 = b2; b2 = b1; e2 = e1; b1 = v; e1 = e; }
        else if (v > b2) { b3 = b2; b2 = v;  e2 = e; }
        else if (v > b3) { b3 = v; }
    }
    wv[item] = make_float2(1.f / (1.f + __expf(-b1)), 1.f / (1.f + __expf(-b2)));
    selv[item] = (u32)e1 | ((u32)e2 << 4);
    if (b2 - b3 < GTAU) {
        u32 p = atomicAdd(flags, 1u);
        if (p < MAXFLAG) flags[1 + p] = (u32)item;
    }
    const float* go = g + 128;
    float o1 = -1e30f, o2 = -1e30f, o3 = -1e30f; int f1 = 0, f2 = 0;
    #pragma unroll
    for (int e = 0; e < NE; ++e) {
        float v = go[e];
        if (v > o1)      { o3 = o2; o2 = o1; f2 = f1; o1 = v; f1 = e; }
        else if (v > o2) { o3 = o2; o2 = v;  f2 = e; }
        else if (v > o3) { o3 = v; }
    }
    selo[item] = (1u << f1) | (1u << f2);
    if (o2 - o3 < GTAU) {
        u32 p = atomicAdd(flags, 1u);
        if (p < MAXFLAG) flags[1 + p] = (u32)item | 0x10000u;
    }
}

// ---------------- fp64 fix-up for flagged near-tie items (one wave per record) ----------------
__global__ __launch_bounds__(256)
void gate_fix(const float* __restrict__ x, const float* __restrict__ Ws,
              const float* __restrict__ Wd, const u32* __restrict__ flags,
              float2* __restrict__ wv, u32* __restrict__ selv, u32* __restrict__ selo)
{
    u32 nf = flags[0]; if (nf > MAXFLAG) nf = MAXFLAG;
    int gw = (blockIdx.x * 256 + threadIdx.x) >> 6;
    int lane = threadIdx.x & 63;
    int nwaves = gridDim.x * 4;
    for (u32 w = gw; w < nf; w += nwaves) {
        u32 rec = flags[1 + w];
        int item = rec & 0xffff, which = rec >> 16;
        int bt = item >> 4, h = item & 15;
        const float* W = (which ? Wd : Ws) + (size_t)h * NE * MDIM + lane * 16;
        const float* xr = x + (size_t)bt * MDIM + lane * 16;
        double g[8];
        #pragma unroll
        for (int e = 0; e < 8; ++e) {
            double s = 0.0;
            #pragma unroll
            for (int c = 0; c < 16; ++c)
                s += (double)xr[c] * (double)W[(size_t)e * MDIM + c];
            g[e] = s;
        }
        #pragma unroll
        for (int off = 32; off; off >>= 1)
            #pragma unroll
            for (int e = 0; e < 8; ++e)
                g[e] += __shfl_xor(g[e], off, 64);
        if (lane == 0) {
            double b1 = -1e300, b2 = -1e300; int i1 = 0, i2 = 0;
            #pragma unroll
            for (int e = 0; e < 8; ++e) {
                double v = g[e];
                if (v > b1)      { b2 = b1; i2 = i1; b1 = v; i1 = e; }
                else if (v > b2) { b2 = v;  i2 = e; }
            }
            if (which == 0) {
                wv[item] = make_float2(1.f / (1.f + __expf(-(float)b1)),
                                       1.f / (1.f + __expf(-(float)b2)));
                selv[item] = (u32)i1 | ((u32)i2 << 4);
            } else {
                selo[item] = (1u << i1) | (1u << i2);
            }
        }
    }
}

// ---------------- V mix + transpose: Vtg[b][h][d][t] ----------------
__global__ __launch_bounds__(256)
void vtrans(const unsigned short* __restrict__ QKVb, const float2* __restrict__ wv,
            const u32* __restrict__ selv, unsigned short* __restrict__ Vtg)
{
    int idx = blockIdx.x * 256 + threadIdx.x;    // < 524288
    int tc = idx & 255;
    int d  = (idx >> 8) & 63;
    int h  = (idx >> 14) & 15;
    int b  = idx >> 18;
    unsigned short o[8];
    #pragma unroll
    for (int j = 0; j < 8; ++j) {
        int bt = b * TSEQ + tc * 8 + j;
        u32 s = selv[bt * 16 + h];
        float2 w = wv[bt * 16 + h];
        int e1 = s & 15, e2 = (s >> 4) & 15;
        const unsigned short* pv = QKVb + (size_t)bt * LDQKV + 2048;
        float v = w.x * bf2f(pv[e1 * 64 + d]) + w.y * bf2f(pv[e2 * 64 + d]);
        o[j] = f2bf(v);
    }
    *(uint4*)(Vtg + ((size_t)((b * NH + h) * DHD + d)) * TSEQ + tc * 8) = *(const uint4*)o;
}

// ---------------- attn: swapped-QK 32x32 MFMA, in-register P, fixed-max softmax ----------------
// flat grid 1024, XCD-swizzled: each XCD owns 8 (b,h,split) groups x 16 q-blocks
#define SPA 72   // LDS row stride (bf16) = 144 B
#define MFMA32(A,B,C) __builtin_amdgcn_mfma_f32_32x32x16_bf16(A, B, C, 0, 0, 0)
__global__ __launch_bounds__(256)
void attn_mfma(const unsigned short* __restrict__ QKVb,
               const unsigned short* __restrict__ Vtg,
               float* __restrict__ Op0, float* __restrict__ Op1,
               float* __restrict__ lp)
{
    __shared__ __align__(16) unsigned short Ks[64 * SPA];
    __shared__ __align__(16) unsigned short Vt[64 * SPA];   // V^T: rows=d, cols=key
    const int vid = blockIdx.x;                  // 0..1023
    const int xcd = vid & 7, sl = vid >> 3;      // sl 0..127
    const int grp = xcd * 8 + (sl >> 4);         // 0..63 (b,h,split group)
    const int q0  = (sl & 15) * 128;
    const int h   = grp & 15;
    const int z   = grp >> 4;                    // 0..3
    const int b = z >> 1, split = z & 1;
    const int tid = threadIdx.x;
    const int lane = tid & 63, wq = tid >> 6;
    const int ql = lane & 31;
    const int hi = lane >> 5;
    const size_t base_q = ((size_t)b * TSEQ) * LDQKV + h * DHD;
    const size_t base_k = base_q + 1024;
    const size_t base_v = ((size_t)(b * NH + h) * DHD) * TSEQ;
    const int k00 = split * 1024;

    const int qrow = q0 + wq * 32 + ql;
    bf16x8 qa[4];
    #pragma unroll
    for (int t = 0; t < 4; ++t)
        qa[t] = *(const bf16x8*)(QKVb + base_q + (size_t)qrow * LDQKV + t * 16 + hi * 8);

    f32x16 o0 = (f32x16)0.f, o1 = (f32x16)0.f;
    float l_lane = 0.f;

    const int srow = tid >> 2, scol = (tid & 3) * 8;
    uint4 kr0 = *(const uint4*)(QKVb + base_k + (size_t)(k00 + srow) * LDQKV + scol);
    uint4 kr1 = *(const uint4*)(QKVb + base_k + (size_t)(k00 + srow) * LDQKV + scol + 32);
    uint4 vr0 = *(const uint4*)(Vtg + base_v + (size_t)srow * TSEQ + k00 + scol);
    uint4 vr1 = *(const uint4*)(Vtg + base_v + (size_t)srow * TSEQ + k00 + scol + 32);

    const int NT = 1024 / 64;
    for (int kb = 0; kb < NT; ++kb) {
        __syncthreads();
        *(uint4*)(Ks + srow * SPA + scol)      = kr0;
        *(uint4*)(Ks + srow * SPA + scol + 32) = kr1;
        *(uint4*)(Vt + srow * SPA + scol)      = vr0;
        *(uint4*)(Vt + srow * SPA + scol + 32) = vr1;
        __syncthreads();
        if (kb + 1 < NT) {
            const size_t gk = base_k + (size_t)(k00 + (kb + 1) * 64 + srow) * LDQKV + scol;
            const size_t gv = base_v + (size_t)srow * TSEQ + k00 + (kb + 1) * 64 + scol;
            kr0 = *(const uint4*)(QKVb + gk);
            kr1 = *(const uint4*)(QKVb + gk + 32);
            vr0 = *(const uint4*)(Vtg + gv);
            vr1 = *(const uint4*)(Vtg + gv + 32);
        }
        f32x16 s0 = (f32x16)0.f, s1 = (f32x16)0.f;
        __builtin_amdgcn_s_setprio(1);
        #pragma unroll
        for (int t = 0; t < 4; ++t) {
            bf16x8 k0 = *(const bf16x8*)(Ks + ql * SPA + t * 16 + hi * 8);
            bf16x8 k1 = *(const bf16x8*)(Ks + (32 + ql) * SPA + t * 16 + hi * 8);
            s0 = MFMA32(k0, qa[t], s0);
            s1 = MFMA32(k1, qa[t], s1);
        }
        __builtin_amdgcn_s_setprio(0);
        float ls = 0.f;
        u32 w[8];
        #pragma unroll
        for (int r = 0; r < 16; ++r) { float p = exp2f(s0[r]); s0[r] = p; ls += p; }
        #pragma unroll
        for (int m = 0; m < 8; ++m) w[m] = cvtpk(s0[2*m], s0[2*m+1]);
        #pragma unroll
        for (int tl = 0; tl < 2; ++tl) {
            const int mb = 4 * tl, tk = tl;
            u32 send0 = hi ? w[mb]   : w[mb+2];
            u32 send1 = hi ? w[mb+1] : w[mb+3];
            u32 r0 = (u32)__shfl_xor((int)send0, 32, 64);
            u32 r1 = (u32)__shfl_xor((int)send1, 32, 64);
            union { u32 uw[4]; bf16x8 v; } pu;
            pu.uw[0] = hi ? r0 : w[mb];
            pu.uw[1] = hi ? r1 : w[mb+1];
            pu.uw[2] = hi ? w[mb+2] : r0;
            pu.uw[3] = hi ? w[mb+3] : r1;
            bf16x8 v0 = *(const bf16x8*)(Vt + ql * SPA + tk * 16 + hi * 8);
            bf16x8 v1 = *(const bf16x8*)(Vt + (32 + ql) * SPA + tk * 16 + hi * 8);
            __builtin_amdgcn_s_setprio(1);
            o0 = MFMA32(pu.v, v0, o0);
            o1 = MFMA32(pu.v, v1, o1);
            __builtin_amdgcn_s_setprio(0);
        }
        #pragma unroll
        for (int r = 0; r < 16; ++r) { float p = exp2f(s1[r]); s1[r] = p; ls += p; }
        #pragma unroll
        for (int m = 0; m < 8; ++m) w[m] = cvtpk(s1[2*m], s1[2*m+1]);
        #pragma unroll
        for (int tl = 0; tl < 2; ++tl) {
            const int mb = 4 * tl, tk = 2 + tl;
            u32 send0 = hi ? w[mb]   : w[mb+2];
            u32 send1 = hi ? w[mb+1] : w[mb+3];
            u32 r0 = (u32)__shfl_xor((int)send0, 32, 64);
            u32 r1 = (u32)__shfl_xor((int)send1, 32, 64);
            union { u32 uw[4]; bf16x8 v; } pu;
            pu.uw[0] = hi ? r0 : w[mb];
            pu.uw[1] = hi ? r1 : w[mb+1];
            pu.uw[2] = hi ? w[mb+2] : r0;
            pu.uw[3] = hi ? w[mb+3] : r1;
            bf16x8 v0 = *(const bf16x8*)(Vt + ql * SPA + tk * 16 + hi * 8);
            bf16x8 v1 = *(const bf16x8*)(Vt + (32 + ql) * SPA + tk * 16 + hi * 8);
            __builtin_amdgcn_s_setprio(1);
            o0 = MFMA32(pu.v, v0, o0);
            o1 = MFMA32(pu.v, v1, o1);
            __builtin_amdgcn_s_setprio(0);
        }
        l_lane += ls;
    }
    float l_tot = l_lane + __shfl_xor(l_lane, 32, 64);
    float* Op = split ? Op1 : Op0;
    const size_t ob = ((size_t)b * TSEQ) * MDIM + h * DHD;
    #pragma unroll
    for (int r = 0; r < 16; ++r) {
        int qr = q0 + wq * 32 + (r & 3) + 8 * (r >> 2) + 4 * hi;
        Op[ob + (size_t)qr * MDIM + ql]      = o0[r];
        Op[ob + (size_t)qr * MDIM + 32 + ql] = o1[r];
    }
    if (hi == 0)
        lp[(((size_t)split * NB + b) * NH + h) * TSEQ + q0 + wq * 32 + ql] = l_tot;
}

// ---------------- U: per-(bt,d) — att[h] once, distribute to 8 experts, bf16 split -------------
__global__ __launch_bounds__(256)
void compute_U2(const float* __restrict__ Op0, const float* __restrict__ Op1,
                const float* __restrict__ lp, const u32* __restrict__ selo,
                unsigned short* __restrict__ Uh, unsigned short* __restrict__ Ul)
{
    int t = blockIdx.x * 256 + threadIdx.x;      // < MBT*64 = 262144
    int bt = t >> 6, d = t & 63;
    int b = bt >> 11, ts = bt & 2047;
    float att[16];
    #pragma unroll
    for (int h = 0; h < NH; ++h) {
        size_t li = ((size_t)b * NH + h) * TSEQ + ts;
        float l = lp[li] + lp[li + (size_t)NB * NH * TSEQ];
        size_t oi = (size_t)bt * MDIM + h * DHD + d;
        att[h] = (Op0[oi] + Op1[oi]) / l;
    }
    const u32* sp = selo + bt * 16;
    u32 m[16];
    #pragma unroll
    for (int h = 0; h < NH; ++h) m[h] = sp[h];
    #pragma unroll
    for (int e = 0; e < NE; ++e) {
        float sum = 0.f;
        #pragma unroll
        for (int h = 0; h < NH; ++h)
            if (m[h] & (1u << e)) sum += att[h];
        int idx = bt * 512 + e * 64 + d;
        unsigned short hi16 = f2bf(sum);
        Uh[idx] = hi16;
        Ul[idx] = f2bf(sum - bf2f(hi16));
    }
}

extern "C" void kernel_launch(void* const* d_in, const int* in_sizes, int n_in,
                              void* d_out, int out_size, void* d_ws, size_t ws_size,
                              hipStream_t stream)
{
    const float* x  = (const float*)d_in[0];
    const float* Wq = (const float*)d_in[1];
    const float* Wk = (const float*)d_in[2];
    const float* Wv = (const float*)d_in[3];
    const float* Ws = (const float*)d_in[4];
    const float* Wd = (const float*)d_in[5];
    const float* Wo = (const float*)d_in[6];
    float* out = (float*)d_out;
    char* ws = (char*)d_ws;

    // region 0 (16.78 MB): [xb|Wqkvb] -> Op0 ; region @46137344 (16.78 MB): xbl -> Op1
    unsigned short* xb    = (unsigned short*)(ws);
    unsigned short* Wqkvb = (unsigned short*)(ws + 8388608);
    float*          Op0   = (float*)(ws);
    unsigned short* QKVb  = (unsigned short*)(ws + 16777216);   // 20.97 MB
    unsigned short* Vtg   = (unsigned short*)(ws + 37748736);   // 8.39 MB
    unsigned short* xbl   = (unsigned short*)(ws + 46137344);   // 8.39 MB (dead before attn)
    float*          Op1   = (float*)(ws + 46137344);            // 16.78 MB
    float*          lp    = (float*)(ws + 62914560);            // 0.52 MB
    unsigned short* WoTh  = (unsigned short*)(ws + 63438848);   // 1.05 MB
    unsigned short* WoTl  = (unsigned short*)(ws + 64487424);   // 1.05 MB
    float*          Gf    = (float*)(ws + 65536000);            // 4.19 MB (dead before Uh)
    unsigned short* Uh    = (unsigned short*)(ws + 65536000);   // 4.19 MB
    u32*            flags = (u32*)(ws + 69730304);              // 64 KB (dead before Ul)
    unsigned short* Ul    = (unsigned short*)(ws + 69730304);   // 4.19 MB
    float2*         wvp   = (float2*)(ws + 73924608);           // 0.52 MB
    u32*            selv  = (u32*)(ws + 74448896);              // 0.26 MB
    u32*            selo  = (u32*)(ws + 74711040);              // 0.26 MB
    unsigned short* Wsdh  = (unsigned short*)(ws + 74973184);   // 0.52 MB
    unsigned short* Wsdl  = (unsigned short*)(ws + 75497472);   // 0.52 MB

    dim3 blk(256);
    prep<<<5504, blk, 0, stream>>>(x, Wq, Wk, Wv, Ws, Wd, Wo,
                                   xb, xbl, Wqkvb, Wsdh, Wsdl, WoTh, WoTl, flags);

    // fused QKV projection (Q pre-scaled): [4096,2560] = xb * Wqkv^T  (XCD-swizzled)
    mfma_gemm<<<640, blk, 0, stream>>>(xb, Wqkvb, QKVb, LDQKV, 1024, 20);

    // gates: split-bf16 MFMA + margin-gated fp64 fix-up
    gate_gemm<<<dim3(4, 64), blk, 0, stream>>>(xb, xbl, Wsdh, Wsdl, Gf);
    gate_topk2<<<256, blk, 0, stream>>>(Gf, wvp, selv, selo, flags);
    gate_fix<<<64, blk, 0, stream>>>(x, Ws, Wd, flags, wvp, selv, selo);

    vtrans<<<2048, blk, 0, stream>>>(QKVb, wvp, selv, Vtg);

    attn_mfma<<<1024, blk, 0, stream>>>(QKVb, Vtg, Op0, Op1, lp);

    compute_U2<<<1024, blk, 0, stream>>>(Op0, Op1, lp, selo, Uh, Ul);
    mfma_gemm3<<<256, blk, 0, stream>>>(Uh, Ul, WoTh, WoTl, out);
}

// Round 10
// 233.090 us; speedup vs baseline: 6.7665x; 1.0529x over previous
//
#include <hip/hip_runtime.h>
#include <math.h>

#define TSEQ 2048
#define NB   2
#define NH   16
#define NE   8
#define DHD  64
#define MDIM 1024
#define MBT  4096   // NB*TSEQ
#define LDQKV 2560  // Q(1024) | K(1024) | V-experts(512)
#define GTAU 1e-3f  // margin threshold for fp64 gate fix-up
#define MAXFLAG 16384

typedef __attribute__((ext_vector_type(8))) short bf16x8;
typedef __attribute__((ext_vector_type(4))) float f32x4;
typedef __attribute__((ext_vector_type(16))) float f32x16;
typedef unsigned int u32;

__device__ inline unsigned short f2bf(float f) {
    union { float f; unsigned u; } v; v.f = f;
    unsigned r = v.u + 0x7fff + ((v.u >> 16) & 1);
    return (unsigned short)(r >> 16);
}
__device__ inline float bf2f(unsigned short h) {
    union { unsigned u; float f; } v; v.u = ((unsigned)h) << 16;
    return v.f;
}
__device__ inline u32 cvtpk(float a, float b) {   // low16=bf16(a), high16=bf16(b)
    u32 r;
    asm("v_cvt_pk_bf16_f32 %0, %1, %2" : "=v"(r) : "v"(a), "v"(b));
    return r;
}
// single-instruction exp2 (inputs bounded |x|<~8 here; no denorm/range handling needed)
__device__ inline float fexp2(float x) {
#if __has_builtin(__builtin_amdgcn_exp2f)
    return __builtin_amdgcn_exp2f(x);
#else
    float r; asm("v_exp_f32 %0, %1" : "=v"(r) : "v"(x)); return r;
#endif
}

// async global->LDS, 16B per lane (dst wave-uniform base + lane*16)
__device__ inline void gload16(const void* g, void* l) {
    __builtin_amdgcn_global_load_lds((const __attribute__((address_space(1))) u32*)g,
                                     (__attribute__((address_space(3))) u32*)l, 16, 0, 0);
}

__device__ inline void cast8s(const float* __restrict__ in, unsigned short* __restrict__ out,
                              int i, float sc) {
    const float4* p = (const float4*)(in + (size_t)i * 8);
    float4 a = p[0], b = p[1];
    unsigned short o[8] = { f2bf(a.x*sc), f2bf(a.y*sc), f2bf(a.z*sc), f2bf(a.w*sc),
                            f2bf(b.x*sc), f2bf(b.y*sc), f2bf(b.z*sc), f2bf(b.w*sc) };
    *(uint4*)(out + (size_t)i * 8) = *(const uint4*)o;
}
__device__ inline void cast8hl(const float* __restrict__ in,
                               unsigned short* __restrict__ oh, unsigned short* __restrict__ ol,
                               int i) {
    const float4* p = (const float4*)(in + (size_t)i * 8);
    float4 a = p[0], b = p[1];
    float f[8] = { a.x, a.y, a.z, a.w, b.x, b.y, b.z, b.w };
    unsigned short h8[8], l8[8];
    #pragma unroll
    for (int j = 0; j < 8; ++j) {
        unsigned short hi = f2bf(f[j]);
        h8[j] = hi;
        l8[j] = f2bf(f[j] - bf2f(hi));
    }
    *(uint4*)(oh + (size_t)i * 8) = *(const uint4*)h8;
    *(uint4*)(ol + (size_t)i * 8) = *(const uint4*)l8;
}

// ---------------- fused prep (casts + Wsd split + Wo repack/split + flag reset) ----------------
__global__ __launch_bounds__(256)
void prep(const float* __restrict__ x,  const float* __restrict__ Wq,
          const float* __restrict__ Wk, const float* __restrict__ Wv,
          const float* __restrict__ Ws, const float* __restrict__ Wd,
          const float* __restrict__ Wo,
          unsigned short* __restrict__ xb, unsigned short* __restrict__ xbl,
          unsigned short* __restrict__ Wqkvb,
          unsigned short* __restrict__ Wsdh, unsigned short* __restrict__ Wsdl,
          unsigned short* __restrict__ WoTh, unsigned short* __restrict__ WoTl,
          u32* __restrict__ flags)
{
    const float qsc = 0.125f * 1.4426950408889634f;  // fold scale*log2(e) into Q
    int b = blockIdx.x, tid = threadIdx.x;
    if (b == 0 && tid == 0) flags[0] = 0;
    if (b < 2048)      cast8hl(x, xb, xbl,          (b        ) * 256 + tid);
    else if (b < 2560) cast8s(Wq, Wqkvb,            (b - 2048) * 256 + tid, qsc);
    else if (b < 3072) cast8s(Wk, Wqkvb + 1048576,  (b - 2560) * 256 + tid, 1.f);
    else if (b < 3328) cast8s(Wv, Wqkvb + 2097152,  (b - 3072) * 256 + tid, 1.f);
    else if (b < 3456) {
        int i = (b - 3328) * 256 + tid;   // 0..32767; 8 elems each of Ws|Wd
        const float* src = (i < 16384) ? Ws + (size_t)i * 8 : Wd + (size_t)(i - 16384) * 8;
        const float4* p = (const float4*)src;
        float4 a = p[0], bq = p[1];
        float f8[8] = { a.x, a.y, a.z, a.w, bq.x, bq.y, bq.z, bq.w };
        unsigned short h8[8], l8[8];
        #pragma unroll
        for (int j = 0; j < 8; ++j) {
            unsigned short hi = f2bf(f8[j]);
            h8[j] = hi;
            l8[j] = f2bf(f8[j] - bf2f(hi));
        }
        *(uint4*)(Wsdh + (size_t)i * 8) = *(const uint4*)h8;
        *(uint4*)(Wsdl + (size_t)i * 8) = *(const uint4*)l8;
    } else {
        int idx = (b - 3456) * 256 + tid;  // < 524288
        int f = idx >> 9, ed = idx & 511, e = ed >> 6, d = ed & 63;
        float v = Wo[(size_t)e * (MDIM * DHD) + (size_t)f * DHD + d];
        unsigned short hi = f2bf(v);
        WoTh[idx] = hi;
        WoTl[idx] = f2bf(v - bf2f(hi));
    }
}

// ---------------- bf16 MFMA GEMM (gload_lds staging, XCD-swizzled): C[M,N]=A*B^T ----------------
__global__ __launch_bounds__(256)
void mfma_gemm(const unsigned short* __restrict__ A,
               const unsigned short* __restrict__ B,
               unsigned short* __restrict__ C, int N, int K, int nbx)
{
    __shared__ __align__(16) unsigned short As[128 * 32];
    __shared__ __align__(16) unsigned short Bs[128 * 32];
    const int o = blockIdx.x;
    const int q8 = (int)gridDim.x >> 3;
    const int virt = (o & 7) * q8 + (o >> 3);      // bijective XCD-chunked remap
    const int bx = virt % nbx, by = virt / nbx;
    const int tid = threadIdx.x;
    const int lane = tid & 63, wave = tid >> 6;
    const int m0 = by * 128, n0 = bx * 128;
    const int wm = (wave >> 1) * 64, wn = (wave & 1) * 64;
    const int fr = lane & 15, fg = lane >> 4;
    const int grow = lane >> 2, gcol = (lane & 3) * 8;

    f32x4 acc[4][4];
    #pragma unroll
    for (int i = 0; i < 4; ++i)
        #pragma unroll
        for (int j = 0; j < 4; ++j) acc[i][j] = (f32x4)0.f;

    for (int k0 = 0; k0 < K; k0 += 32) {
        __syncthreads();
        const unsigned short* gA = A + (size_t)(m0 + wave * 32 + grow) * K + k0 + gcol;
        gload16(gA,                 As + wave * 1024);
        gload16(gA + (size_t)16 * K, As + wave * 1024 + 512);
        const unsigned short* gB = B + (size_t)(n0 + wave * 32 + grow) * K + k0 + gcol;
        gload16(gB,                 Bs + wave * 1024);
        gload16(gB + (size_t)16 * K, Bs + wave * 1024 + 512);
        __syncthreads();
        bf16x8 af[4], bfr[4];
        #pragma unroll
        for (int t = 0; t < 4; ++t) {
            af[t]  = *(const bf16x8*)(As + (wm + t * 16 + fr) * 32 + fg * 8);
            bfr[t] = *(const bf16x8*)(Bs + (wn + t * 16 + fr) * 32 + fg * 8);
        }
        #pragma unroll
        for (int i = 0; i < 4; ++i)
            #pragma unroll
            for (int j = 0; j < 4; ++j)
                acc[i][j] = __builtin_amdgcn_mfma_f32_16x16x32_bf16(af[i], bfr[j], acc[i][j], 0, 0, 0);
    }
    #pragma unroll
    for (int i = 0; i < 4; ++i)
        #pragma unroll
        for (int j = 0; j < 4; ++j)
            #pragma unroll
            for (int rr = 0; rr < 4; ++rr) {
                int row = m0 + wm + i * 16 + fg * 4 + rr;
                int col = n0 + wn + j * 16 + fr;
                C[(size_t)row * N + col] = f2bf(acc[i][j][rr]);
            }
}

// ---------------- split-bf16 3-pass MFMA GEMM, fp32 out (final projection, swizzled) ----------------
__global__ __launch_bounds__(256)
void mfma_gemm3(const unsigned short* __restrict__ Ah, const unsigned short* __restrict__ Al,
                const unsigned short* __restrict__ Bh, const unsigned short* __restrict__ Bl,
                float* __restrict__ C)
{
    const int Kc = 512, N = 1024;
    __shared__ __align__(16) unsigned short Ash[128 * 32];
    __shared__ __align__(16) unsigned short Asl[128 * 32];
    __shared__ __align__(16) unsigned short Bsh[128 * 32];
    __shared__ __align__(16) unsigned short Bsl[128 * 32];
    const int o = blockIdx.x;                       // 256 blocks
    const int virt = (o & 7) * 32 + (o >> 3);
    const int bx = virt & 7, by = virt >> 3;
    const int tid = threadIdx.x;
    const int lane = tid & 63, wave = tid >> 6;
    const int m0 = by * 128, n0 = bx * 128;
    const int wm = (wave >> 1) * 64, wn = (wave & 1) * 64;
    const int fr = lane & 15, fg = lane >> 4;
    const int grow = lane >> 2, gcol = (lane & 3) * 8;

    f32x4 acc[4][4];
    #pragma unroll
    for (int i = 0; i < 4; ++i)
        #pragma unroll
        for (int j = 0; j < 4; ++j) acc[i][j] = (f32x4)0.f;

    for (int k0 = 0; k0 < Kc; k0 += 32) {
        __syncthreads();
        const size_t roff  = (size_t)(m0 + wave * 32 + grow) * Kc + k0 + gcol;
        const size_t roffB = (size_t)(n0 + wave * 32 + grow) * Kc + k0 + gcol;
        gload16(Ah + roff,             Ash + wave * 1024);
        gload16(Ah + roff + 16 * Kc,   Ash + wave * 1024 + 512);
        gload16(Al + roff,             Asl + wave * 1024);
        gload16(Al + roff + 16 * Kc,   Asl + wave * 1024 + 512);
        gload16(Bh + roffB,            Bsh + wave * 1024);
        gload16(Bh + roffB + 16 * Kc,  Bsh + wave * 1024 + 512);
        gload16(Bl + roffB,            Bsl + wave * 1024);
        gload16(Bl + roffB + 16 * Kc,  Bsl + wave * 1024 + 512);
        __syncthreads();
        bf16x8 ah[4], al[4], bh[4], bl[4];
        #pragma unroll
        for (int t = 0; t < 4; ++t) {
            ah[t] = *(const bf16x8*)(Ash + (wm + t * 16 + fr) * 32 + fg * 8);
            al[t] = *(const bf16x8*)(Asl + (wm + t * 16 + fr) * 32 + fg * 8);
            bh[t] = *(const bf16x8*)(Bsh + (wn + t * 16 + fr) * 32 + fg * 8);
            bl[t] = *(const bf16x8*)(Bsl + (wn + t * 16 + fr) * 32 + fg * 8);
        }
        #pragma unroll
        for (int i = 0; i < 4; ++i)
            #pragma unroll
            for (int j = 0; j < 4; ++j) {
                acc[i][j] = __builtin_amdgcn_mfma_f32_16x16x32_bf16(ah[i], bh[j], acc[i][j], 0, 0, 0);
                acc[i][j] = __builtin_amdgcn_mfma_f32_16x16x32_bf16(ah[i], bl[j], acc[i][j], 0, 0, 0);
                acc[i][j] = __builtin_amdgcn_mfma_f32_16x16x32_bf16(al[i], bh[j], acc[i][j], 0, 0, 0);
            }
    }
    #pragma unroll
    for (int i = 0; i < 4; ++i)
        #pragma unroll
        for (int j = 0; j < 4; ++j)
            #pragma unroll
            for (int rr = 0; rr < 4; ++rr) {
                int row = m0 + wm + i * 16 + fg * 4 + rr;
                int col = n0 + wn + j * 16 + fr;
                C[(size_t)row * N + col] = acc[i][j][rr];
            }
}

// ---------------- gate GEMM: split-bf16 3-pass, Gf[4096][256] fp32 ----------------
__global__ __launch_bounds__(256)
void gate_gemm(const unsigned short* __restrict__ Ah, const unsigned short* __restrict__ Al,
               const unsigned short* __restrict__ Bh, const unsigned short* __restrict__ Bl,
               float* __restrict__ C)
{
    const int K = 1024, N = 256;
    __shared__ __align__(16) unsigned short S[4][64 * 32];
    const int tid = threadIdx.x;
    const int lane = tid & 63, wave = tid >> 6;
    const int m0 = blockIdx.y * 64, n0 = blockIdx.x * 64;
    const int wm = (wave >> 1) * 32, wn = (wave & 1) * 32;
    const int fr = lane & 15, fg = lane >> 4;
    const int grow = lane >> 2, gcol = (lane & 3) * 8;

    const unsigned short* src = (wave == 0) ? Ah : (wave == 1) ? Al : (wave == 2) ? Bh : Bl;
    const int brow = (wave >= 2) ? n0 : m0;

    f32x4 acc[2][2];
    #pragma unroll
    for (int i = 0; i < 2; ++i)
        #pragma unroll
        for (int j = 0; j < 2; ++j) acc[i][j] = (f32x4)0.f;

    for (int k0 = 0; k0 < K; k0 += 32) {
        __syncthreads();
        #pragma unroll
        for (int i = 0; i < 4; ++i)
            gload16(src + (size_t)(brow + i * 16 + grow) * K + k0 + gcol, &S[wave][i * 512]);
        __syncthreads();
        bf16x8 ah[2], al[2], bh[2], bl[2];
        #pragma unroll
        for (int t = 0; t < 2; ++t) {
            ah[t] = *(const bf16x8*)(&S[0][(wm + t * 16 + fr) * 32 + fg * 8]);
            al[t] = *(const bf16x8*)(&S[1][(wm + t * 16 + fr) * 32 + fg * 8]);
            bh[t] = *(const bf16x8*)(&S[2][(wn + t * 16 + fr) * 32 + fg * 8]);
            bl[t] = *(const bf16x8*)(&S[3][(wn + t * 16 + fr) * 32 + fg * 8]);
        }
        #pragma unroll
        for (int i = 0; i < 2; ++i)
            #pragma unroll
            for (int j = 0; j < 2; ++j) {
                acc[i][j] = __builtin_amdgcn_mfma_f32_16x16x32_bf16(ah[i], bh[j], acc[i][j], 0, 0, 0);
                acc[i][j] = __builtin_amdgcn_mfma_f32_16x16x32_bf16(ah[i], bl[j], acc[i][j], 0, 0, 0);
                acc[i][j] = __builtin_amdgcn_mfma_f32_16x16x32_bf16(al[i], bh[j], acc[i][j], 0, 0, 0);
            }
    }
    #pragma unroll
    for (int i = 0; i < 2; ++i)
        #pragma unroll
        for (int j = 0; j < 2; ++j)
            #pragma unroll
            for (int rr = 0; rr < 4; ++rr) {
                int row = m0 + wm + i * 16 + fg * 4 + rr;
                int col = n0 + wn + j * 16 + fr;
                C[(size_t)row * N + col] = acc[i][j][rr];
            }
}

// ---------------- top-2 + margin flagging ----------------
__global__ __launch_bounds__(256)
void gate_topk2(const float* __restrict__ Gf,
                float2* __restrict__ wv, u32* __restrict__ selv, u32* __restrict__ selo,
                u32* __restrict__ flags)
{
    int item = blockIdx.x * 256 + threadIdx.x;   // < 65536
    int bt = item >> 4, h = item & 15;
    const float* g = Gf + (size_t)bt * 256 + h * NE;
    float b1 = -1e30f, b2 = -1e30f, b3 = -1e30f; int e1 = 0, e2 = 0;
    #pragma unroll
    for (int e = 0; e < NE; ++e) {
        float v = g[e];
        if (v > b1)      { b3 = b2; b2 = b1; e2 = e1; b1 = v; e1 = e; }
        else if (v > b2) { b3 = b2; b2 = v;  e2 = e; }
        else if (v > b3) { b3 = v; }
    }
    wv[item] = make_float2(1.f / (1.f + __expf(-b1)), 1.f / (1.f + __expf(-b2)));
    selv[item] = (u32)e1 | ((u32)e2 << 4);
    if (b2 - b3 < GTAU) {
        u32 p = atomicAdd(flags, 1u);
        if (p < MAXFLAG) flags[1 + p] = (u32)item;
    }
    const float* go = g + 128;
    float o1 = -1e30f, o2 = -1e30f, o3 = -1e30f; int f1 = 0, f2 = 0;
    #pragma unroll
    for (int e = 0; e < NE; ++e) {
        float v = go[e];
        if (v > o1)      { o3 = o2; o2 = o1; f2 = f1; o1 = v; f1 = e; }
        else if (v > o2) { o3 = o2; o2 = v;  f2 = e; }
        else if (v > o3) { o3 = v; }
    }
    selo[item] = (1u << f1) | (1u << f2);
    if (o2 - o3 < GTAU) {
        u32 p = atomicAdd(flags, 1u);
        if (p < MAXFLAG) flags[1 + p] = (u32)item | 0x10000u;
    }
}

// ---------------- fp64 fix-up for flagged near-tie items (one wave per record) ----------------
__global__ __launch_bounds__(256)
void gate_fix(const float* __restrict__ x, const float* __restrict__ Ws,
              const float* __restrict__ Wd, const u32* __restrict__ flags,
              float2* __restrict__ wv, u32* __restrict__ selv, u32* __restrict__ selo)
{
    u32 nf = flags[0]; if (nf > MAXFLAG) nf = MAXFLAG;
    int gw = (blockIdx.x * 256 + threadIdx.x) >> 6;
    int lane = threadIdx.x & 63;
    int nwaves = gridDim.x * 4;
    for (u32 w = gw; w < nf; w += nwaves) {
        u32 rec = flags[1 + w];
        int item = rec & 0xffff, which = rec >> 16;
        int bt = item >> 4, h = item & 15;
        const float* W = (which ? Wd : Ws) + (size_t)h * NE * MDIM + lane * 16;
        const float* xr = x + (size_t)bt * MDIM + lane * 16;
        double g[8];
        #pragma unroll
        for (int e = 0; e < 8; ++e) {
            double s = 0.0;
            #pragma unroll
            for (int c = 0; c < 16; ++c)
                s += (double)xr[c] * (double)W[(size_t)e * MDIM + c];
            g[e] = s;
        }
        #pragma unroll
        for (int off = 32; off; off >>= 1)
            #pragma unroll
            for (int e = 0; e < 8; ++e)
                g[e] += __shfl_xor(g[e], off, 64);
        if (lane == 0) {
            double b1 = -1e300, b2 = -1e300; int i1 = 0, i2 = 0;
            #pragma unroll
            for (int e = 0; e < 8; ++e) {
                double v = g[e];
                if (v > b1)      { b2 = b1; i2 = i1; b1 = v; i1 = e; }
                else if (v > b2) { b2 = v;  i2 = e; }
            }
            if (which == 0) {
                wv[item] = make_float2(1.f / (1.f + __expf(-(float)b1)),
                                       1.f / (1.f + __expf(-(float)b2)));
                selv[item] = (u32)i1 | ((u32)i2 << 4);
            } else {
                selo[item] = (1u << i1) | (1u << i2);
            }
        }
    }
}

// ---------------- V mix + transpose: Vtg[b][h][d][t] ----------------
__global__ __launch_bounds__(256)
void vtrans(const unsigned short* __restrict__ QKVb, const float2* __restrict__ wv,
            const u32* __restrict__ selv, unsigned short* __restrict__ Vtg)
{
    int idx = blockIdx.x * 256 + threadIdx.x;    // < 524288
    int tc = idx & 255;
    int d  = (idx >> 8) & 63;
    int h  = (idx >> 14) & 15;
    int b  = idx >> 18;
    unsigned short o[8];
    #pragma unroll
    for (int j = 0; j < 8; ++j) {
        int bt = b * TSEQ + tc * 8 + j;
        u32 s = selv[bt * 16 + h];
        float2 w = wv[bt * 16 + h];
        int e1 = s & 15, e2 = (s >> 4) & 15;
        const unsigned short* pv = QKVb + (size_t)bt * LDQKV + 2048;
        float v = w.x * bf2f(pv[e1 * 64 + d]) + w.y * bf2f(pv[e2 * 64 + d]);
        o[j] = f2bf(v);
    }
    *(uint4*)(Vtg + ((size_t)((b * NH + h) * DHD + d)) * TSEQ + tc * 8) = *(const uint4*)o;
}

// ---------------- attn: swapped-QK 32x32 MFMA, in-register P, fixed-max softmax ----------------
// flat grid 1024, XCD-swizzled: each XCD owns 8 (b,h,split) groups x 16 q-blocks
#define SPA 72   // LDS row stride (bf16) = 144 B
#define MFMA32(A,B,C) __builtin_amdgcn_mfma_f32_32x32x16_bf16(A, B, C, 0, 0, 0)
__global__ __launch_bounds__(256)
void attn_mfma(const unsigned short* __restrict__ QKVb,
               const unsigned short* __restrict__ Vtg,
               float* __restrict__ Op0, float* __restrict__ Op1,
               float* __restrict__ lp)
{
    __shared__ __align__(16) unsigned short Ks[64 * SPA];
    __shared__ __align__(16) unsigned short Vt[64 * SPA];   // V^T: rows=d, cols=key
    const int vid = blockIdx.x;                  // 0..1023
    const int xcd = vid & 7, sl = vid >> 3;      // sl 0..127
    const int grp = xcd * 8 + (sl >> 4);         // 0..63 (b,h,split group)
    const int q0  = (sl & 15) * 128;
    const int h   = grp & 15;
    const int z   = grp >> 4;                    // 0..3
    const int b = z >> 1, split = z & 1;
    const int tid = threadIdx.x;
    const int lane = tid & 63, wq = tid >> 6;
    const int ql = lane & 31;
    const int hi = lane >> 5;
    const size_t base_q = ((size_t)b * TSEQ) * LDQKV + h * DHD;
    const size_t base_k = base_q + 1024;
    const size_t base_v = ((size_t)(b * NH + h) * DHD) * TSEQ;
    const int k00 = split * 1024;

    const int qrow = q0 + wq * 32 + ql;
    bf16x8 qa[4];
    #pragma unroll
    for (int t = 0; t < 4; ++t)
        qa[t] = *(const bf16x8*)(QKVb + base_q + (size_t)qrow * LDQKV + t * 16 + hi * 8);

    f32x16 o0 = (f32x16)0.f, o1 = (f32x16)0.f;
    float l_lane = 0.f;

    const int srow = tid >> 2, scol = (tid & 3) * 8;
    uint4 kr0 = *(const uint4*)(QKVb + base_k + (size_t)(k00 + srow) * LDQKV + scol);
    uint4 kr1 = *(const uint4*)(QKVb + base_k + (size_t)(k00 + srow) * LDQKV + scol + 32);
    uint4 vr0 = *(const uint4*)(Vtg + base_v + (size_t)srow * TSEQ + k00 + scol);
    uint4 vr1 = *(const uint4*)(Vtg + base_v + (size_t)srow * TSEQ + k00 + scol + 32);

    const int NT = 1024 / 64;
    for (int kb = 0; kb < NT; ++kb) {
        __syncthreads();
        *(uint4*)(Ks + srow * SPA + scol)      = kr0;
        *(uint4*)(Ks + srow * SPA + scol + 32) = kr1;
        *(uint4*)(Vt + srow * SPA + scol)      = vr0;
        *(uint4*)(Vt + srow * SPA + scol + 32) = vr1;
        __syncthreads();
        if (kb + 1 < NT) {
            const size_t gk = base_k + (size_t)(k00 + (kb + 1) * 64 + srow) * LDQKV + scol;
            const size_t gv = base_v + (size_t)srow * TSEQ + k00 + (kb + 1) * 64 + scol;
            kr0 = *(const uint4*)(QKVb + gk);
            kr1 = *(const uint4*)(QKVb + gk + 32);
            vr0 = *(const uint4*)(Vtg + gv);
            vr1 = *(const uint4*)(Vtg + gv + 32);
        }
        f32x16 s0 = (f32x16)0.f, s1 = (f32x16)0.f;
        #pragma unroll
        for (int t = 0; t < 4; ++t) {
            bf16x8 k0 = *(const bf16x8*)(Ks + ql * SPA + t * 16 + hi * 8);
            bf16x8 k1 = *(const bf16x8*)(Ks + (32 + ql) * SPA + t * 16 + hi * 8);
            s0 = MFMA32(k0, qa[t], s0);
            s1 = MFMA32(k1, qa[t], s1);
        }
        float ls0 = 0.f, ls1 = 0.f;
        u32 w[8];
        #pragma unroll
        for (int r = 0; r < 16; r += 2) {
            float pa = fexp2(s0[r]), pb = fexp2(s0[r + 1]);
            s0[r] = pa; s0[r + 1] = pb;
            ls0 += pa; ls1 += pb;
        }
        #pragma unroll
        for (int m = 0; m < 8; ++m) w[m] = cvtpk(s0[2*m], s0[2*m+1]);
        #pragma unroll
        for (int tl = 0; tl < 2; ++tl) {
            const int mb = 4 * tl, tk = tl;
            u32 send0 = hi ? w[mb]   : w[mb+2];
            u32 send1 = hi ? w[mb+1] : w[mb+3];
            u32 r0 = (u32)__shfl_xor((int)send0, 32, 64);
            u32 r1 = (u32)__shfl_xor((int)send1, 32, 64);
            union { u32 uw[4]; bf16x8 v; } pu;
            pu.uw[0] = hi ? r0 : w[mb];
            pu.uw[1] = hi ? r1 : w[mb+1];
            pu.uw[2] = hi ? w[mb+2] : r0;
            pu.uw[3] = hi ? w[mb+3] : r1;
            bf16x8 v0 = *(const bf16x8*)(Vt + ql * SPA + tk * 16 + hi * 8);
            bf16x8 v1 = *(const bf16x8*)(Vt + (32 + ql) * SPA + tk * 16 + hi * 8);
            o0 = MFMA32(pu.v, v0, o0);
            o1 = MFMA32(pu.v, v1, o1);
        }
        #pragma unroll
        for (int r = 0; r < 16; r += 2) {
            float pa = fexp2(s1[r]), pb = fexp2(s1[r + 1]);
            s1[r] = pa; s1[r + 1] = pb;
            ls0 += pa; ls1 += pb;
        }
        #pragma unroll
        for (int m = 0; m < 8; ++m) w[m] = cvtpk(s1[2*m], s1[2*m+1]);
        #pragma unroll
        for (int tl = 0; tl < 2; ++tl) {
            const int mb = 4 * tl, tk = 2 + tl;
            u32 send0 = hi ? w[mb]   : w[mb+2];
            u32 send1 = hi ? w[mb+1] : w[mb+3];
            u32 r0 = (u32)__shfl_xor((int)send0, 32, 64);
            u32 r1 = (u32)__shfl_xor((int)send1, 32, 64);
            union { u32 uw[4]; bf16x8 v; } pu;
            pu.uw[0] = hi ? r0 : w[mb];
            pu.uw[1] = hi ? r1 : w[mb+1];
            pu.uw[2] = hi ? w[mb+2] : r0;
            pu.uw[3] = hi ? w[mb+3] : r1;
            bf16x8 v0 = *(const bf16x8*)(Vt + ql * SPA + tk * 16 + hi * 8);
            bf16x8 v1 = *(const bf16x8*)(Vt + (32 + ql) * SPA + tk * 16 + hi * 8);
            o0 = MFMA32(pu.v, v0, o0);
            o1 = MFMA32(pu.v, v1, o1);
        }
        l_lane += ls0 + ls1;
    }
    float l_tot = l_lane + __shfl_xor(l_lane, 32, 64);
    float* Op = split ? Op1 : Op0;
    const size_t ob = ((size_t)b * TSEQ) * MDIM + h * DHD;
    #pragma unroll
    for (int r = 0; r < 16; ++r) {
        int qr = q0 + wq * 32 + (r & 3) + 8 * (r >> 2) + 4 * hi;
        Op[ob + (size_t)qr * MDIM + ql]      = o0[r];
        Op[ob + (size_t)qr * MDIM + 32 + ql] = o1[r];
    }
    if (hi == 0)
        lp[(((size_t)split * NB + b) * NH + h) * TSEQ + q0 + wq * 32 + ql] = l_tot;
}

// ---------------- U: per-(bt,d) — att[h] once, distribute to 8 experts, bf16 split -------------
__global__ __launch_bounds__(256)
void compute_U2(const float* __restrict__ Op0, const float* __restrict__ Op1,
                const float* __restrict__ lp, const u32* __restrict__ selo,
                unsigned short* __restrict__ Uh, unsigned short* __restrict__ Ul)
{
    int t = blockIdx.x * 256 + threadIdx.x;      // < MBT*64 = 262144
    int bt = t >> 6, d = t & 63;
    int b = bt >> 11, ts = bt & 2047;
    float att[16];
    #pragma unroll
    for (int h = 0; h < NH; ++h) {
        size_t li = ((size_t)b * NH + h) * TSEQ + ts;
        float l = lp[li] + lp[li + (size_t)NB * NH * TSEQ];
        size_t oi = (size_t)bt * MDIM + h * DHD + d;
        att[h] = (Op0[oi] + Op1[oi]) / l;
    }
    const u32* sp = selo + bt * 16;
    u32 m[16];
    #pragma unroll
    for (int h = 0; h < NH; ++h) m[h] = sp[h];
    #pragma unroll
    for (int e = 0; e < NE; ++e) {
        float sum = 0.f;
        #pragma unroll
        for (int h = 0; h < NH; ++h)
            if (m[h] & (1u << e)) sum += att[h];
        int idx = bt * 512 + e * 64 + d;
        unsigned short hi16 = f2bf(sum);
        Uh[idx] = hi16;
        Ul[idx] = f2bf(sum - bf2f(hi16));
    }
}

extern "C" void kernel_launch(void* const* d_in, const int* in_sizes, int n_in,
                              void* d_out, int out_size, void* d_ws, size_t ws_size,
                              hipStream_t stream)
{
    const float* x  = (const float*)d_in[0];
    const float* Wq = (const float*)d_in[1];
    const float* Wk = (const float*)d_in[2];
    const float* Wv = (const float*)d_in[3];
    const float* Ws = (const float*)d_in[4];
    const float* Wd = (const float*)d_in[5];
    const float* Wo = (const float*)d_in[6];
    float* out = (float*)d_out;
    char* ws = (char*)d_ws;

    // region 0 (16.78 MB): [xb|Wqkvb] -> Op0 ; region @46137344 (16.78 MB): xbl -> Op1
    unsigned short* xb    = (unsigned short*)(ws);
    unsigned short* Wqkvb = (unsigned short*)(ws + 8388608);
    float*          Op0   = (float*)(ws);
    unsigned short* QKVb  = (unsigned short*)(ws + 16777216);   // 20.97 MB
    unsigned short* Vtg   = (unsigned short*)(ws + 37748736);   // 8.39 MB
    unsigned short* xbl   = (unsigned short*)(ws + 46137344);   // 8.39 MB (dead before attn)
    float*          Op1   = (float*)(ws + 46137344);            // 16.78 MB
    float*          lp    = (float*)(ws + 62914560);            // 0.52 MB
    unsigned short* WoTh  = (unsigned short*)(ws + 63438848);   // 1.05 MB
    unsigned short* WoTl  = (unsigned short*)(ws + 64487424);   // 1.05 MB
    float*          Gf    = (float*)(ws + 65536000);            // 4.19 MB (dead before Uh)
    unsigned short* Uh    = (unsigned short*)(ws + 65536000);   // 4.19 MB
    u32*            flags = (u32*)(ws + 69730304);              // 64 KB (dead before Ul)
    unsigned short* Ul    = (unsigned short*)(ws + 69730304);   // 4.19 MB
    float2*         wvp   = (float2*)(ws + 73924608);           // 0.52 MB
    u32*            selv  = (u32*)(ws + 74448896);              // 0.26 MB
    u32*            selo  = (u32*)(ws + 74711040);              // 0.26 MB
    unsigned short* Wsdh  = (unsigned short*)(ws + 74973184);   // 0.52 MB
    unsigned short* Wsdl  = (unsigned short*)(ws + 75497472);   // 0.52 MB

    dim3 blk(256);
    prep<<<5504, blk, 0, stream>>>(x, Wq, Wk, Wv, Ws, Wd, Wo,
                                   xb, xbl, Wqkvb, Wsdh, Wsdl, WoTh, WoTl, flags);

    // fused QKV projection (Q pre-scaled): [4096,2560] = xb * Wqkv^T  (XCD-swizzled)
    mfma_gemm<<<640, blk, 0, stream>>>(xb, Wqkvb, QKVb, LDQKV, 1024, 20);

    // gates: split-bf16 MFMA + margin-gated fp64 fix-up
    gate_gemm<<<dim3(4, 64), blk, 0, stream>>>(xb, xbl, Wsdh, Wsdl, Gf);
    gate_topk2<<<256, blk, 0, stream>>>(Gf, wvp, selv, selo, flags);
    gate_fix<<<64, blk, 0, stream>>>(x, Ws, Wd, flags, wvp, selv, selo);

    vtrans<<<2048, blk, 0, stream>>>(QKVb, wvp, selv, Vtg);

    attn_mfma<<<1024, blk, 0, stream>>>(QKVb, Vtg, Op0, Op1, lp);

    compute_U2<<<1024, blk, 0, stream>>>(Op0, Op1, lp, selo, Uh, Ul);
    mfma_gemm3<<<256, blk, 0, stream>>>(Uh, Ul, WoTh, WoTl, out);
}

// Round 11
// 178.574 us; speedup vs baseline: 8.8322x; 1.3053x over previous
//
#include <hip/hip_runtime.h>
#include <math.h>

#define TSEQ 2048
#define NB   2
#define NH   16
#define NE   8
#define DHD  64
#define MDIM 1024
#define MBT  4096   // NB*TSEQ
#define LDQKV 2560  // Q(1024) | K(1024) | V-experts(512)
#define GTAU 1e-3f  // margin threshold for fp64 gate fix-up
#define MAXFLAG 16384

typedef __attribute__((ext_vector_type(8))) short bf16x8;
typedef __attribute__((ext_vector_type(4))) float f32x4;
typedef __attribute__((ext_vector_type(16))) float f32x16;
typedef unsigned int u32;

__device__ inline unsigned short f2bf(float f) {
    union { float f; unsigned u; } v; v.f = f;
    unsigned r = v.u + 0x7fff + ((v.u >> 16) & 1);
    return (unsigned short)(r >> 16);
}
__device__ inline float bf2f(unsigned short h) {
    union { unsigned u; float f; } v; v.u = ((unsigned)h) << 16;
    return v.f;
}
__device__ inline u32 cvtpk(float a, float b) {   // low16=bf16(a), high16=bf16(b)
    u32 r;
    asm("v_cvt_pk_bf16_f32 %0, %1, %2" : "=v"(r) : "v"(a), "v"(b));
    return r;
}
// single-instruction exp2 (inputs bounded |x|<~8 here; no denorm/range handling needed)
__device__ inline float fexp2(float x) {
#if __has_builtin(__builtin_amdgcn_exp2f)
    return __builtin_amdgcn_exp2f(x);
#else
    float r; asm("v_exp_f32 %0, %1" : "=v"(r) : "v"(x)); return r;
#endif
}

// async global->LDS, 16B per lane (dst wave-uniform base + lane*16)
__device__ inline void gload16(const void* g, void* l) {
    __builtin_amdgcn_global_load_lds((const __attribute__((address_space(1))) u32*)g,
                                     (__attribute__((address_space(3))) u32*)l, 16, 0, 0);
}

__device__ inline void cast8s(const float* __restrict__ in, unsigned short* __restrict__ out,
                              int i, float sc) {
    const float4* p = (const float4*)(in + (size_t)i * 8);
    float4 a = p[0], b = p[1];
    unsigned short o[8] = { f2bf(a.x*sc), f2bf(a.y*sc), f2bf(a.z*sc), f2bf(a.w*sc),
                            f2bf(b.x*sc), f2bf(b.y*sc), f2bf(b.z*sc), f2bf(b.w*sc) };
    *(uint4*)(out + (size_t)i * 8) = *(const uint4*)o;
}
__device__ inline void cast8hl(const float* __restrict__ in,
                               unsigned short* __restrict__ oh, unsigned short* __restrict__ ol,
                               int i) {
    const float4* p = (const float4*)(in + (size_t)i * 8);
    float4 a = p[0], b = p[1];
    float f[8] = { a.x, a.y, a.z, a.w, b.x, b.y, b.z, b.w };
    unsigned short h8[8], l8[8];
    #pragma unroll
    for (int j = 0; j < 8; ++j) {
        unsigned short hi = f2bf(f[j]);
        h8[j] = hi;
        l8[j] = f2bf(f[j] - bf2f(hi));
    }
    *(uint4*)(oh + (size_t)i * 8) = *(const uint4*)h8;
    *(uint4*)(ol + (size_t)i * 8) = *(const uint4*)l8;
}

// ---------------- fused prep (casts + Wsd split + Wo repack/split + flag reset) ----------------
__global__ __launch_bounds__(256)
void prep(const float* __restrict__ x,  const float* __restrict__ Wq,
          const float* __restrict__ Wk, const float* __restrict__ Wv,
          const float* __restrict__ Ws, const float* __restrict__ Wd,
          const float* __restrict__ Wo,
          unsigned short* __restrict__ xb, unsigned short* __restrict__ xbl,
          unsigned short* __restrict__ Wqkvb,
          unsigned short* __restrict__ Wsdh, unsigned short* __restrict__ Wsdl,
          unsigned short* __restrict__ WoTh, unsigned short* __restrict__ WoTl,
          u32* __restrict__ flags)
{
    const float qsc = 0.125f * 1.4426950408889634f;  // fold scale*log2(e) into Q
    int b = blockIdx.x, tid = threadIdx.x;
    if (b == 0 && tid == 0) flags[0] = 0;
    if (b < 2048)      cast8hl(x, xb, xbl,          (b        ) * 256 + tid);
    else if (b < 2560) cast8s(Wq, Wqkvb,            (b - 2048) * 256 + tid, qsc);
    else if (b < 3072) cast8s(Wk, Wqkvb + 1048576,  (b - 2560) * 256 + tid, 1.f);
    else if (b < 3328) cast8s(Wv, Wqkvb + 2097152,  (b - 3072) * 256 + tid, 1.f);
    else if (b < 3456) {
        int i = (b - 3328) * 256 + tid;   // 0..32767; 8 elems each of Ws|Wd
        const float* src = (i < 16384) ? Ws + (size_t)i * 8 : Wd + (size_t)(i - 16384) * 8;
        const float4* p = (const float4*)src;
        float4 a = p[0], bq = p[1];
        float f8[8] = { a.x, a.y, a.z, a.w, bq.x, bq.y, bq.z, bq.w };
        unsigned short h8[8], l8[8];
        #pragma unroll
        for (int j = 0; j < 8; ++j) {
            unsigned short hi = f2bf(f8[j]);
            h8[j] = hi;
            l8[j] = f2bf(f8[j] - bf2f(hi));
        }
        *(uint4*)(Wsdh + (size_t)i * 8) = *(const uint4*)h8;
        *(uint4*)(Wsdl + (size_t)i * 8) = *(const uint4*)l8;
    } else {
        int idx = (b - 3456) * 256 + tid;  // < 524288
        int f = idx >> 9, ed = idx & 511, e = ed >> 6, d = ed & 63;
        float v = Wo[(size_t)e * (MDIM * DHD) + (size_t)f * DHD + d];
        unsigned short hi = f2bf(v);
        WoTh[idx] = hi;
        WoTl[idx] = f2bf(v - bf2f(hi));
    }
}

// ---------------- bf16 MFMA GEMM (gload_lds staging, XCD-swizzled): C[M,N]=A*B^T ----------------
__global__ __launch_bounds__(256)
void mfma_gemm(const unsigned short* __restrict__ A,
               const unsigned short* __restrict__ B,
               unsigned short* __restrict__ C, int N, int K, int nbx)
{
    __shared__ __align__(16) unsigned short As[128 * 32];
    __shared__ __align__(16) unsigned short Bs[128 * 32];
    const int o = blockIdx.x;
    const int q8 = (int)gridDim.x >> 3;
    const int virt = (o & 7) * q8 + (o >> 3);      // bijective XCD-chunked remap
    const int bx = virt % nbx, by = virt / nbx;
    const int tid = threadIdx.x;
    const int lane = tid & 63, wave = tid >> 6;
    const int m0 = by * 128, n0 = bx * 128;
    const int wm = (wave >> 1) * 64, wn = (wave & 1) * 64;
    const int fr = lane & 15, fg = lane >> 4;
    const int grow = lane >> 2, gcol = (lane & 3) * 8;

    f32x4 acc[4][4];
    #pragma unroll
    for (int i = 0; i < 4; ++i)
        #pragma unroll
        for (int j = 0; j < 4; ++j) acc[i][j] = (f32x4)0.f;

    for (int k0 = 0; k0 < K; k0 += 32) {
        __syncthreads();
        const unsigned short* gA = A + (size_t)(m0 + wave * 32 + grow) * K + k0 + gcol;
        gload16(gA,                 As + wave * 1024);
        gload16(gA + (size_t)16 * K, As + wave * 1024 + 512);
        const unsigned short* gB = B + (size_t)(n0 + wave * 32 + grow) * K + k0 + gcol;
        gload16(gB,                 Bs + wave * 1024);
        gload16(gB + (size_t)16 * K, Bs + wave * 1024 + 512);
        __syncthreads();
        bf16x8 af[4], bfr[4];
        #pragma unroll
        for (int t = 0; t < 4; ++t) {
            af[t]  = *(const bf16x8*)(As + (wm + t * 16 + fr) * 32 + fg * 8);
            bfr[t] = *(const bf16x8*)(Bs + (wn + t * 16 + fr) * 32 + fg * 8);
        }
        #pragma unroll
        for (int i = 0; i < 4; ++i)
            #pragma unroll
            for (int j = 0; j < 4; ++j)
                acc[i][j] = __builtin_amdgcn_mfma_f32_16x16x32_bf16(af[i], bfr[j], acc[i][j], 0, 0, 0);
    }
    #pragma unroll
    for (int i = 0; i < 4; ++i)
        #pragma unroll
        for (int j = 0; j < 4; ++j)
            #pragma unroll
            for (int rr = 0; rr < 4; ++rr) {
                int row = m0 + wm + i * 16 + fg * 4 + rr;
                int col = n0 + wn + j * 16 + fr;
                C[(size_t)row * N + col] = f2bf(acc[i][j][rr]);
            }
}

// ---------------- split-bf16 3-pass MFMA GEMM, fp32 out (final projection, swizzled) ----------------
__global__ __launch_bounds__(256)
void mfma_gemm3(const unsigned short* __restrict__ Ah, const unsigned short* __restrict__ Al,
                const unsigned short* __restrict__ Bh, const unsigned short* __restrict__ Bl,
                float* __restrict__ C)
{
    const int Kc = 512, N = 1024;
    __shared__ __align__(16) unsigned short Ash[128 * 32];
    __shared__ __align__(16) unsigned short Asl[128 * 32];
    __shared__ __align__(16) unsigned short Bsh[128 * 32];
    __shared__ __align__(16) unsigned short Bsl[128 * 32];
    const int o = blockIdx.x;                       // 256 blocks
    const int virt = (o & 7) * 32 + (o >> 3);
    const int bx = virt & 7, by = virt >> 3;
    const int tid = threadIdx.x;
    const int lane = tid & 63, wave = tid >> 6;
    const int m0 = by * 128, n0 = bx * 128;
    const int wm = (wave >> 1) * 64, wn = (wave & 1) * 64;
    const int fr = lane & 15, fg = lane >> 4;
    const int grow = lane >> 2, gcol = (lane & 3) * 8;

    f32x4 acc[4][4];
    #pragma unroll
    for (int i = 0; i < 4; ++i)
        #pragma unroll
        for (int j = 0; j < 4; ++j) acc[i][j] = (f32x4)0.f;

    for (int k0 = 0; k0 < Kc; k0 += 32) {
        __syncthreads();
        const size_t roff  = (size_t)(m0 + wave * 32 + grow) * Kc + k0 + gcol;
        const size_t roffB = (size_t)(n0 + wave * 32 + grow) * Kc + k0 + gcol;
        gload16(Ah + roff,             Ash + wave * 1024);
        gload16(Ah + roff + 16 * Kc,   Ash + wave * 1024 + 512);
        gload16(Al + roff,             Asl + wave * 1024);
        gload16(Al + roff + 16 * Kc,   Asl + wave * 1024 + 512);
        gload16(Bh + roffB,            Bsh + wave * 1024);
        gload16(Bh + roffB + 16 * Kc,  Bsh + wave * 1024 + 512);
        gload16(Bl + roffB,            Bsl + wave * 1024);
        gload16(Bl + roffB + 16 * Kc,  Bsl + wave * 1024 + 512);
        __syncthreads();
        bf16x8 ah[4], al[4], bh[4], bl[4];
        #pragma unroll
        for (int t = 0; t < 4; ++t) {
            ah[t] = *(const bf16x8*)(Ash + (wm + t * 16 + fr) * 32 + fg * 8);
            al[t] = *(const bf16x8*)(Asl + (wm + t * 16 + fr) * 32 + fg * 8);
            bh[t] = *(const bf16x8*)(Bsh + (wn + t * 16 + fr) * 32 + fg * 8);
            bl[t] = *(const bf16x8*)(Bsl + (wn + t * 16 + fr) * 32 + fg * 8);
        }
        #pragma unroll
        for (int i = 0; i < 4; ++i)
            #pragma unroll
            for (int j = 0; j < 4; ++j) {
                acc[i][j] = __builtin_amdgcn_mfma_f32_16x16x32_bf16(ah[i], bh[j], acc[i][j], 0, 0, 0);
                acc[i][j] = __builtin_amdgcn_mfma_f32_16x16x32_bf16(ah[i], bl[j], acc[i][j], 0, 0, 0);
                acc[i][j] = __builtin_amdgcn_mfma_f32_16x16x32_bf16(al[i], bh[j], acc[i][j], 0, 0, 0);
            }
    }
    #pragma unroll
    for (int i = 0; i < 4; ++i)
        #pragma unroll
        for (int j = 0; j < 4; ++j)
            #pragma unroll
            for (int rr = 0; rr < 4; ++rr) {
                int row = m0 + wm + i * 16 + fg * 4 + rr;
                int col = n0 + wn + j * 16 + fr;
                C[(size_t)row * N + col] = acc[i][j][rr];
            }
}

// ---------------- gate GEMM: split-bf16 3-pass, Gf[4096][256] fp32 ----------------
__global__ __launch_bounds__(256)
void gate_gemm(const unsigned short* __restrict__ Ah, const unsigned short* __restrict__ Al,
               const unsigned short* __restrict__ Bh, const unsigned short* __restrict__ Bl,
               float* __restrict__ C)
{
    const int K = 1024, N = 256;
    __shared__ __align__(16) unsigned short S[4][64 * 32];
    const int tid = threadIdx.x;
    const int lane = tid & 63, wave = tid >> 6;
    const int m0 = blockIdx.y * 64, n0 = blockIdx.x * 64;
    const int wm = (wave >> 1) * 32, wn = (wave & 1) * 32;
    const int fr = lane & 15, fg = lane >> 4;
    const int grow = lane >> 2, gcol = (lane & 3) * 8;

    const unsigned short* src = (wave == 0) ? Ah : (wave == 1) ? Al : (wave == 2) ? Bh : Bl;
    const int brow = (wave >= 2) ? n0 : m0;

    f32x4 acc[2][2];
    #pragma unroll
    for (int i = 0; i < 2; ++i)
        #pragma unroll
        for (int j = 0; j < 2; ++j) acc[i][j] = (f32x4)0.f;

    for (int k0 = 0; k0 < K; k0 += 32) {
        __syncthreads();
        #pragma unroll
        for (int i = 0; i < 4; ++i)
            gload16(src + (size_t)(brow + i * 16 + grow) * K + k0 + gcol, &S[wave][i * 512]);
        __syncthreads();
        bf16x8 ah[2], al[2], bh[2], bl[2];
        #pragma unroll
        for (int t = 0; t < 2; ++t) {
            ah[t] = *(const bf16x8*)(&S[0][(wm + t * 16 + fr) * 32 + fg * 8]);
            al[t] = *(const bf16x8*)(&S[1][(wm + t * 16 + fr) * 32 + fg * 8]);
            bh[t] = *(const bf16x8*)(&S[2][(wn + t * 16 + fr) * 32 + fg * 8]);
            bl[t] = *(const bf16x8*)(&S[3][(wn + t * 16 + fr) * 32 + fg * 8]);
        }
        #pragma unroll
        for (int i = 0; i < 2; ++i)
            #pragma unroll
            for (int j = 0; j < 2; ++j) {
                acc[i][j] = __builtin_amdgcn_mfma_f32_16x16x32_bf16(ah[i], bh[j], acc[i][j], 0, 0, 0);
                acc[i][j] = __builtin_amdgcn_mfma_f32_16x16x32_bf16(ah[i], bl[j], acc[i][j], 0, 0, 0);
                acc[i][j] = __builtin_amdgcn_mfma_f32_16x16x32_bf16(al[i], bh[j], acc[i][j], 0, 0, 0);
            }
    }
    #pragma unroll
    for (int i = 0; i < 2; ++i)
        #pragma unroll
        for (int j = 0; j < 2; ++j)
            #pragma unroll
            for (int rr = 0; rr < 4; ++rr) {
                int row = m0 + wm + i * 16 + fg * 4 + rr;
                int col = n0 + wn + j * 16 + fr;
                C[(size_t)row * N + col] = acc[i][j][rr];
            }
}

// ---------------- top-2 + margin flagging ----------------
__global__ __launch_bounds__(256)
void gate_topk2(const float* __restrict__ Gf,
                float2* __restrict__ wv, u32* __restrict__ selv, u32* __restrict__ selo,
                u32* __restrict__ flags)
{
    int item = blockIdx.x * 256 + threadIdx.x;   // < 65536
    int bt = item >> 4, h = item & 15;
    const float* g = Gf + (size_t)bt * 256 + h * NE;
    float b1 = -1e30f, b2 = -1e30f, b3 = -1e30f; int e1 = 0, e2 = 0;
    #pragma unroll
    for (int e = 0; e < NE; ++e) {
        float v = g[e];
        if (v > b1)      { b3 = b2; b2 = b1; e2 = e1; b1 = v; e1 = e; }
        else if (v > b2) { b3 = b2; b2 = v;  e2 = e; }
        else if (v > b3) { b3 = v; }
    }
    wv[item] = make_float2(1.f / (1.f + __expf(-b1)), 1.f / (1.f + __expf(-b2)));
    selv[item] = (u32)e1 | ((u32)e2 << 4);
    if (b2 - b3 < GTAU) {
        u32 p = atomicAdd(flags, 1u);
        if (p < MAXFLAG) flags[1 + p] = (u32)item;
    }
    const float* go = g + 128;
    float o1 = -1e30f, o2 = -1e30f, o3 = -1e30f; int f1 = 0, f2 = 0;
    #pragma unroll
    for (int e = 0; e < NE; ++e) {
        float v = go[e];
        if (v > o1)      { o3 = o2; o2 = o1; f2 = f1; o1 = v; f1 = e; }
        else if (v > o2) { o3 = o2; o2 = v;  f2 = e; }
        else if (v > o3) { o3 = v; }
    }
    selo[item] = (1u << f1) | (1u << f2);
    if (o2 - o3 < GTAU) {
        u32 p = atomicAdd(flags, 1u);
        if (p < MAXFLAG) flags[1 + p] = (u32)item | 0x10000u;
    }
}

// ---------------- fp64 fix-up for flagged near-tie items (one wave per record) ----------------
__global__ __launch_bounds__(256)
void gate_fix(const float* __restrict__ x, const float* __restrict__ Ws,
              const float* __restrict__ Wd, const u32* __restrict__ flags,
              float2* __restrict__ wv, u32* __restrict__ selv, u32* __restrict__ selo)
{
    u32 nf = flags[0]; if (nf > MAXFLAG) nf = MAXFLAG;
    int gw = (blockIdx.x * 256 + threadIdx.x) >> 6;
    int lane = threadIdx.x & 63;
    int nwaves = gridDim.x * 4;
    for (u32 w = gw; w < nf; w += nwaves) {
        u32 rec = flags[1 + w];
        int item = rec & 0xffff, which = rec >> 16;
        int bt = item >> 4, h = item & 15;
        const float* W = (which ? Wd : Ws) + (size_t)h * NE * MDIM + lane * 16;
        const float* xr = x + (size_t)bt * MDIM + lane * 16;
        double g[8];
        #pragma unroll
        for (int e = 0; e < 8; ++e) {
            double s = 0.0;
            #pragma unroll
            for (int c = 0; c < 16; ++c)
                s += (double)xr[c] * (double)W[(size_t)e * MDIM + c];
            g[e] = s;
        }
        #pragma unroll
        for (int off = 32; off; off >>= 1)
            #pragma unroll
            for (int e = 0; e < 8; ++e)
                g[e] += __shfl_xor(g[e], off, 64);
        if (lane == 0) {
            double b1 = -1e300, b2 = -1e300; int i1 = 0, i2 = 0;
            #pragma unroll
            for (int e = 0; e < 8; ++e) {
                double v = g[e];
                if (v > b1)      { b2 = b1; i2 = i1; b1 = v; i1 = e; }
                else if (v > b2) { b2 = v;  i2 = e; }
            }
            if (which == 0) {
                wv[item] = make_float2(1.f / (1.f + __expf(-(float)b1)),
                                       1.f / (1.f + __expf(-(float)b2)));
                selv[item] = (u32)i1 | ((u32)i2 << 4);
            } else {
                selo[item] = (1u << i1) | (1u << i2);
            }
        }
    }
}

// ---------------- V mix + transpose, LDS-staged: Vtg[b][h][d][t] ----------------
// One block per (b,h,tblk of 256 t). Phase 1: vectorized expert mix -> LDS [t][d].
// Phase 2: conflict-free column reads (lane=d, wave-uniform chunk) -> contiguous Vtg writes.
#define VTP 72   // LDS row stride (bf16 elems), 144 B, 16B-aligned
__global__ __launch_bounds__(256)
void vtrans(const unsigned short* __restrict__ QKVb, const float2* __restrict__ wv,
            const u32* __restrict__ selv, unsigned short* __restrict__ Vtg)
{
    __shared__ __align__(16) unsigned short Ls[256 * VTP];
    const int vid = blockIdx.x;              // 0..255
    const int xcd = vid & 7, local = vid >> 3;
    const int virt = xcd * 32 + local;       // bijective XCD-chunked remap
    const int b = virt >> 7, rem = virt & 127;
    const int tblk = rem >> 4, h = rem & 15;
    const int tid = threadIdx.x;

    // phase 1: one thread per t — mix the 2 selected experts, vector loads
    {
        const int bt = b * TSEQ + tblk * 256 + tid;
        u32 s = selv[bt * 16 + h];
        float2 w = wv[bt * 16 + h];
        int e1 = s & 15, e2 = (s >> 4) & 15;
        const unsigned short* pv = QKVb + (size_t)bt * LDQKV + 2048;
        #pragma unroll
        for (int c = 0; c < 8; ++c) {
            uint4 a  = *(const uint4*)(pv + e1 * 64 + c * 8);
            uint4 bb = *(const uint4*)(pv + e2 * 64 + c * 8);
            unsigned short ea[8], eb[8], eo[8];
            *(uint4*)ea = a; *(uint4*)eb = bb;
            #pragma unroll
            for (int j = 0; j < 8; ++j)
                eo[j] = f2bf(w.x * bf2f(ea[j]) + w.y * bf2f(eb[j]));
            *(uint4*)(Ls + tid * VTP + c * 8) = *(const uint4*)eo;
        }
    }
    __syncthreads();
    // phase 2: transpose out of LDS — lane = d (conflict-free broadcast pairs)
    {
        const int d = tid & 63, outer = tid >> 6;
        const size_t vrow = ((size_t)((b * NH + h) * DHD + d)) * TSEQ + tblk * 256;
        #pragma unroll
        for (int c8 = 0; c8 < 8; ++c8) {
            int t0 = (outer * 8 + c8) * 8;
            unsigned short o[8];
            #pragma unroll
            for (int j = 0; j < 8; ++j)
                o[j] = Ls[(t0 + j) * VTP + d];
            *(uint4*)(Vtg + vrow + t0) = *(const uint4*)o;
        }
    }
}

// ---------------- attn: swapped-QK 32x32 MFMA, in-register P, fixed-max softmax ----------------
// flat grid 1024, XCD-swizzled: each XCD owns 8 (b,h,split) groups x 16 q-blocks
#define SPA 72   // LDS row stride (bf16) = 144 B
#define MFMA32(A,B,C) __builtin_amdgcn_mfma_f32_32x32x16_bf16(A, B, C, 0, 0, 0)
__global__ __launch_bounds__(256)
void attn_mfma(const unsigned short* __restrict__ QKVb,
               const unsigned short* __restrict__ Vtg,
               float* __restrict__ Op0, float* __restrict__ Op1,
               float* __restrict__ lp)
{
    __shared__ __align__(16) unsigned short Ks[64 * SPA];
    __shared__ __align__(16) unsigned short Vt[64 * SPA];   // V^T: rows=d, cols=key
    const int vid = blockIdx.x;                  // 0..1023
    const int xcd = vid & 7, sl = vid >> 3;      // sl 0..127
    const int grp = xcd * 8 + (sl >> 4);         // 0..63 (b,h,split group)
    const int q0  = (sl & 15) * 128;
    const int h   = grp & 15;
    const int z   = grp >> 4;                    // 0..3
    const int b = z >> 1, split = z & 1;
    const int tid = threadIdx.x;
    const int lane = tid & 63, wq = tid >> 6;
    const int ql = lane & 31;
    const int hi = lane >> 5;
    const size_t base_q = ((size_t)b * TSEQ) * LDQKV + h * DHD;
    const size_t base_k = base_q + 1024;
    const size_t base_v = ((size_t)(b * NH + h) * DHD) * TSEQ;
    const int k00 = split * 1024;

    const int qrow = q0 + wq * 32 + ql;
    bf16x8 qa[4];
    #pragma unroll
    for (int t = 0; t < 4; ++t)
        qa[t] = *(const bf16x8*)(QKVb + base_q + (size_t)qrow * LDQKV + t * 16 + hi * 8);

    f32x16 o0 = (f32x16)0.f, o1 = (f32x16)0.f;
    float l_lane = 0.f;

    const int srow = tid >> 2, scol = (tid & 3) * 8;
    uint4 kr0 = *(const uint4*)(QKVb + base_k + (size_t)(k00 + srow) * LDQKV + scol);
    uint4 kr1 = *(const uint4*)(QKVb + base_k + (size_t)(k00 + srow) * LDQKV + scol + 32);
    uint4 vr0 = *(const uint4*)(Vtg + base_v + (size_t)srow * TSEQ + k00 + scol);
    uint4 vr1 = *(const uint4*)(Vtg + base_v + (size_t)srow * TSEQ + k00 + scol + 32);

    const int NT = 1024 / 64;
    for (int kb = 0; kb < NT; ++kb) {
        __syncthreads();
        *(uint4*)(Ks + srow * SPA + scol)      = kr0;
        *(uint4*)(Ks + srow * SPA + scol + 32) = kr1;
        *(uint4*)(Vt + srow * SPA + scol)      = vr0;
        *(uint4*)(Vt + srow * SPA + scol + 32) = vr1;
        __syncthreads();
        if (kb + 1 < NT) {
            const size_t gk = base_k + (size_t)(k00 + (kb + 1) * 64 + srow) * LDQKV + scol;
            const size_t gv = base_v + (size_t)srow * TSEQ + k00 + (kb + 1) * 64 + scol;
            kr0 = *(const uint4*)(QKVb + gk);
            kr1 = *(const uint4*)(QKVb + gk + 32);
            vr0 = *(const uint4*)(Vtg + gv);
            vr1 = *(const uint4*)(Vtg + gv + 32);
        }
        f32x16 s0 = (f32x16)0.f, s1 = (f32x16)0.f;
        #pragma unroll
        for (int t = 0; t < 4; ++t) {
            bf16x8 k0 = *(const bf16x8*)(Ks + ql * SPA + t * 16 + hi * 8);
            bf16x8 k1 = *(const bf16x8*)(Ks + (32 + ql) * SPA + t * 16 + hi * 8);
            s0 = MFMA32(k0, qa[t], s0);
            s1 = MFMA32(k1, qa[t], s1);
        }
        float ls0 = 0.f, ls1 = 0.f;
        u32 w[8];
        #pragma unroll
        for (int r = 0; r < 16; r += 2) {
            float pa = fexp2(s0[r]), pb = fexp2(s0[r + 1]);
            s0[r] = pa; s0[r + 1] = pb;
            ls0 += pa; ls1 += pb;
        }
        #pragma unroll
        for (int m = 0; m < 8; ++m) w[m] = cvtpk(s0[2*m], s0[2*m+1]);
        #pragma unroll
        for (int tl = 0; tl < 2; ++tl) {
            const int mb = 4 * tl, tk = tl;
            u32 send0 = hi ? w[mb]   : w[mb+2];
            u32 send1 = hi ? w[mb+1] : w[mb+3];
            u32 r0 = (u32)__shfl_xor((int)send0, 32, 64);
            u32 r1 = (u32)__shfl_xor((int)send1, 32, 64);
            union { u32 uw[4]; bf16x8 v; } pu;
            pu.uw[0] = hi ? r0 : w[mb];
            pu.uw[1] = hi ? r1 : w[mb+1];
            pu.uw[2] = hi ? w[mb+2] : r0;
            pu.uw[3] = hi ? w[mb+3] : r1;
            bf16x8 v0 = *(const bf16x8*)(Vt + ql * SPA + tk * 16 + hi * 8);
            bf16x8 v1 = *(const bf16x8*)(Vt + (32 + ql) * SPA + tk * 16 + hi * 8);
            o0 = MFMA32(pu.v, v0, o0);
            o1 = MFMA32(pu.v, v1, o1);
        }
        #pragma unroll
        for (int r = 0; r < 16; r += 2) {
            float pa = fexp2(s1[r]), pb = fexp2(s1[r + 1]);
            s1[r] = pa; s1[r + 1] = pb;
            ls0 += pa; ls1 += pb;
        }
        #pragma unroll
        for (int m = 0; m < 8; ++m) w[m] = cvtpk(s1[2*m], s1[2*m+1]);
        #pragma unroll
        for (int tl = 0; tl < 2; ++tl) {
            const int mb = 4 * tl, tk = 2 + tl;
            u32 send0 = hi ? w[mb]   : w[mb+2];
            u32 send1 = hi ? w[mb+1] : w[mb+3];
            u32 r0 = (u32)__shfl_xor((int)send0, 32, 64);
            u32 r1 = (u32)__shfl_xor((int)send1, 32, 64);
            union { u32 uw[4]; bf16x8 v; } pu;
            pu.uw[0] = hi ? r0 : w[mb];
            pu.uw[1] = hi ? r1 : w[mb+1];
            pu.uw[2] = hi ? w[mb+2] : r0;
            pu.uw[3] = hi ? w[mb+3] : r1;
            bf16x8 v0 = *(const bf16x8*)(Vt + ql * SPA + tk * 16 + hi * 8);
            bf16x8 v1 = *(const bf16x8*)(Vt + (32 + ql) * SPA + tk * 16 + hi * 8);
            o0 = MFMA32(pu.v, v0, o0);
            o1 = MFMA32(pu.v, v1, o1);
        }
        l_lane += ls0 + ls1;
    }
    float l_tot = l_lane + __shfl_xor(l_lane, 32, 64);
    float* Op = split ? Op1 : Op0;
    const size_t ob = ((size_t)b * TSEQ) * MDIM + h * DHD;
    #pragma unroll
    for (int r = 0; r < 16; ++r) {
        int qr = q0 + wq * 32 + (r & 3) + 8 * (r >> 2) + 4 * hi;
        Op[ob + (size_t)qr * MDIM + ql]      = o0[r];
        Op[ob + (size_t)qr * MDIM + 32 + ql] = o1[r];
    }
    if (hi == 0)
        lp[(((size_t)split * NB + b) * NH + h) * TSEQ + q0 + wq * 32 + ql] = l_tot;
}

// ---------------- U: per-(bt,d) — att[h] once, distribute to 8 experts, bf16 split -------------
__global__ __launch_bounds__(256)
void compute_U2(const float* __restrict__ Op0, const float* __restrict__ Op1,
                const float* __restrict__ lp, const u32* __restrict__ selo,
                unsigned short* __restrict__ Uh, unsigned short* __restrict__ Ul)
{
    int t = blockIdx.x * 256 + threadIdx.x;      // < MBT*64 = 262144
    int bt = t >> 6, d = t & 63;
    int b = bt >> 11, ts = bt & 2047;
    float att[16];
    #pragma unroll
    for (int h = 0; h < NH; ++h) {
        size_t li = ((size_t)b * NH + h) * TSEQ + ts;
        float l = lp[li] + lp[li + (size_t)NB * NH * TSEQ];
        size_t oi = (size_t)bt * MDIM + h * DHD + d;
        att[h] = (Op0[oi] + Op1[oi]) / l;
    }
    const u32* sp = selo + bt * 16;
    u32 m[16];
    #pragma unroll
    for (int h = 0; h < NH; ++h) m[h] = sp[h];
    #pragma unroll
    for (int e = 0; e < NE; ++e) {
        float sum = 0.f;
        #pragma unroll
        for (int h = 0; h < NH; ++h)
            if (m[h] & (1u << e)) sum += att[h];
        int idx = bt * 512 + e * 64 + d;
        unsigned short hi16 = f2bf(sum);
        Uh[idx] = hi16;
        Ul[idx] = f2bf(sum - bf2f(hi16));
    }
}

extern "C" void kernel_launch(void* const* d_in, const int* in_sizes, int n_in,
                              void* d_out, int out_size, void* d_ws, size_t ws_size,
                              hipStream_t stream)
{
    const float* x  = (const float*)d_in[0];
    const float* Wq = (const float*)d_in[1];
    const float* Wk = (const float*)d_in[2];
    const float* Wv = (const float*)d_in[3];
    const float* Ws = (const float*)d_in[4];
    const float* Wd = (const float*)d_in[5];
    const float* Wo = (const float*)d_in[6];
    float* out = (float*)d_out;
    char* ws = (char*)d_ws;

    // region 0 (16.78 MB): [xb|Wqkvb] -> Op0 ; region @46137344 (16.78 MB): xbl -> Op1
    unsigned short* xb    = (unsigned short*)(ws);
    unsigned short* Wqkvb = (unsigned short*)(ws + 8388608);
    float*          Op0   = (float*)(ws);
    unsigned short* QKVb  = (unsigned short*)(ws + 16777216);   // 20.97 MB
    unsigned short* Vtg   = (unsigned short*)(ws + 37748736);   // 8.39 MB
    unsigned short* xbl   = (unsigned short*)(ws + 46137344);   // 8.39 MB (dead before attn)
    float*          Op1   = (float*)(ws + 46137344);            // 16.78 MB
    float*          lp    = (float*)(ws + 62914560);            // 0.52 MB
    unsigned short* WoTh  = (unsigned short*)(ws + 63438848);   // 1.05 MB
    unsigned short* WoTl  = (unsigned short*)(ws + 64487424);   // 1.05 MB
    float*          Gf    = (float*)(ws + 65536000);            // 4.19 MB (dead before Uh)
    unsigned short* Uh    = (unsigned short*)(ws + 65536000);   // 4.19 MB
    u32*            flags = (u32*)(ws + 69730304);              // 64 KB (dead before Ul)
    unsigned short* Ul    = (unsigned short*)(ws + 69730304);   // 4.19 MB
    float2*         wvp   = (float2*)(ws + 73924608);           // 0.52 MB
    u32*            selv  = (u32*)(ws + 74448896);              // 0.26 MB
    u32*            selo  = (u32*)(ws + 74711040);              // 0.26 MB
    unsigned short* Wsdh  = (unsigned short*)(ws + 74973184);   // 0.52 MB
    unsigned short* Wsdl  = (unsigned short*)(ws + 75497472);   // 0.52 MB

    dim3 blk(256);
    prep<<<5504, blk, 0, stream>>>(x, Wq, Wk, Wv, Ws, Wd, Wo,
                                   xb, xbl, Wqkvb, Wsdh, Wsdl, WoTh, WoTl, flags);

    // fused QKV projection (Q pre-scaled): [4096,2560] = xb * Wqkv^T  (XCD-swizzled)
    mfma_gemm<<<640, blk, 0, stream>>>(xb, Wqkvb, QKVb, LDQKV, 1024, 20);

    // gates: split-bf16 MFMA + margin-gated fp64 fix-up
    gate_gemm<<<dim3(4, 64), blk, 0, stream>>>(xb, xbl, Wsdh, Wsdl, Gf);
    gate_topk2<<<256, blk, 0, stream>>>(Gf, wvp, selv, selo, flags);
    gate_fix<<<64, blk, 0, stream>>>(x, Ws, Wd, flags, wvp, selv, selo);

    vtrans<<<256, blk, 0, stream>>>(QKVb, wvp, selv, Vtg);

    attn_mfma<<<1024, blk, 0, stream>>>(QKVb, Vtg, Op0, Op1, lp);

    compute_U2<<<1024, blk, 0, stream>>>(Op0, Op1, lp, selo, Uh, Ul);
    mfma_gemm3<<<256, blk, 0, stream>>>(Uh, Ul, WoTh, WoTl, out);
}